// Round 2
// baseline (4670.853 us; speedup 1.0000x reference)
//
#include <hip/hip_runtime.h>
#include <math.h>

#define BATCHN 256
#define SEQ 200
#define DMODEL 256
#define DINNER 512
#define NH 32
#define HD 16
#define DSTATE 64
#define DINPROJ 1184
#define XBCLD 672
#define BL (BATCHN*SEQ)   // 51200
#define NF 101
#define NJ 202

// ---------------- DFT matrix init ----------------
__global__ void init_dft_kernel(float* __restrict__ EF, float* __restrict__ EI)
{
    const float ang = 6.28318530717958647692f / 200.0f;
    int idx = blockIdx.x * 256 + threadIdx.x;
    if (idx < NJ * SEQ) {
        int f = idx / SEQ, t = idx - f * SEQ;
        float v;
        if (f <= 100) {
            int ph = (f * t) % 200;
            v = cosf(ang * (float)ph);
        } else {
            int ff = f - 101;
            int ph = (ff * t) % 200;
            v = -sinf(ang * (float)ph);
        }
        EF[idx] = v;
    } else if (idx < 2 * NJ * SEQ) {
        int j2 = idx - NJ * SEQ;
        int t = j2 / NJ, j = j2 - t * NJ;
        float v;
        if (j == 0) v = 1.0f / 200.0f;
        else if (j == 100) v = ((t & 1) ? -1.0f : 1.0f) / 200.0f;
        else if (j < 100) { int ph = (j * t) % 200; v = 2.0f * cosf(ang * (float)ph) / 200.0f; }
        else if (j == 101 || j == 201) v = 0.0f;
        else { int f = j - 101; int ph = (f * t) % 200; v = -2.0f * sinf(ang * (float)ph) / 200.0f; }
        EI[j2] = v;
    }
}

// ---------------- generic fp32 tiled GEMM ----------------
// ACT: 0 = none(+bias), 1 = bias+GELU, 2 = accumulate into C (no bias)
template<int ACT>
__global__ __launch_bounds__(256) void gemm_kernel(
    const float* __restrict__ A, const float* __restrict__ B, float* __restrict__ C,
    const float* __restrict__ bias,
    int M, int N, int K, int lda, int ldb, int ldc,
    long long sA, long long sB, long long sC)
{
    __shared__ float As[16][64];
    __shared__ float Bs[16][64];
    A += (long long)blockIdx.z * sA;
    B += (long long)blockIdx.z * sB;
    C += (long long)blockIdx.z * sC;
    int m0 = blockIdx.y * 64, n0 = blockIdx.x * 64;
    int tid = threadIdx.x;
    int tm = tid >> 4, tn = tid & 15;
    int am = tid >> 2, ak = (tid & 3) * 4;
    int bk = tid >> 4, bn = (tid & 15) * 4;
    float acc[4][4];
#pragma unroll
    for (int i = 0; i < 4; i++)
#pragma unroll
        for (int j = 0; j < 4; j++) acc[i][j] = 0.f;

    for (int k0 = 0; k0 < K; k0 += 16) {
        int gm = m0 + am;
#pragma unroll
        for (int i = 0; i < 4; i++) {
            int gk = k0 + ak + i;
            As[ak + i][am] = (gm < M && gk < K) ? A[(long long)gm * lda + gk] : 0.f;
        }
        int gk = k0 + bk;
#pragma unroll
        for (int i = 0; i < 4; i++) {
            int gn = n0 + bn + i;
            Bs[bk][bn + i] = (gk < K && gn < N) ? B[(long long)gk * ldb + gn] : 0.f;
        }
        __syncthreads();
#pragma unroll
        for (int kk = 0; kk < 16; kk++) {
            float a[4], bb[4];
#pragma unroll
            for (int i = 0; i < 4; i++) { a[i] = As[kk][tm * 4 + i]; bb[i] = Bs[kk][tn * 4 + i]; }
#pragma unroll
            for (int i = 0; i < 4; i++)
#pragma unroll
                for (int j = 0; j < 4; j++)
                    acc[i][j] = fmaf(a[i], bb[j], acc[i][j]);
        }
        __syncthreads();
    }
#pragma unroll
    for (int i = 0; i < 4; i++) {
        int gm = m0 + tm * 4 + i;
        if (gm >= M) continue;
#pragma unroll
        for (int j = 0; j < 4; j++) {
            int gn = n0 + tn * 4 + j;
            if (gn >= N) continue;
            float v = acc[i][j];
            long long ci = (long long)gm * ldc + gn;
            if (ACT == 2) {
                C[ci] += v;
            } else {
                if (bias) v += bias[gn];
                if (ACT == 1) v = 0.5f * v * (1.f + erff(v * 0.70710678118654752f));
                C[ci] = v;
            }
        }
    }
}

// ---------------- conv+silu for B/C channels, dt/dA ----------------
__global__ void convbc_kernel(const float* __restrict__ XBC, const float* __restrict__ conv_w,
                              const float* __restrict__ conv_b, const float* __restrict__ dt_bias,
                              const float* __restrict__ A_log,
                              float* __restrict__ BCb, float* __restrict__ DTb, float* __restrict__ DAb)
{
    int row = blockIdx.x;
    int b = row / SEQ, l = row - b * SEQ;
    int tid = threadIdx.x;
    if (tid < 128) {
        int ch = 512 + tid;                     // conv channel == local XBC col
        float acc = conv_b[ch];
#pragma unroll
        for (int k = 0; k < 4; k++) {
            int lt = l + k - 3;
            if (lt >= 0)
                acc = fmaf(conv_w[ch * 4 + k], XBC[(long long)(b * SEQ + lt) * XBCLD + ch], acc);
        }
        BCb[(long long)row * 128 + tid] = acc / (1.f + expf(-acc));
    } else if (tid < 160) {
        int h = tid - 128;
        float draw = XBC[(long long)row * XBCLD + 640 + h] + dt_bias[h];
        float dtv = (draw > 20.f) ? draw : log1pf(expf(draw));
        DTb[(long long)row * NH + h] = dtv;
        DAb[(long long)row * NH + h] = expf(-expf(A_log[h]) * dtv);
    }
}

// ---------------- selective scan with fused x-channel conv; y in-place ----------------
__global__ __launch_bounds__(256) void scan2_kernel(
    const float* __restrict__ DTb, const float* __restrict__ DAb,
    float* __restrict__ XBC, const float* __restrict__ BCb,
    const float* __restrict__ Dsk,
    const float* __restrict__ conv_w, const float* __restrict__ conv_b)
{
    int wid = blockIdx.x * 4 + (threadIdx.x >> 6);
    int lane = threadIdx.x & 63;
    int b = wid >> 5, h = wid & 31;
    float cw0 = 0.f, cw1 = 0.f, cw2 = 0.f, cw3 = 0.f, cb = 0.f;
    if (lane < HD) {
        int ch = h * HD + lane;
        cw0 = conv_w[ch * 4 + 0]; cw1 = conv_w[ch * 4 + 1];
        cw2 = conv_w[ch * 4 + 2]; cw3 = conv_w[ch * 4 + 3];
        cb = conv_b[ch];
    }
    float ds = Dsk[h];
    float wA = 0.f, wB = 0.f, wC = 0.f;
    float st[16];
#pragma unroll
    for (int p = 0; p < 16; p++) st[p] = 0.f;
    long long rowbase = (long long)b * SEQ;
    for (int t = 0; t < SEQ; t++) {
        long long row = rowbase + t;
        float da = DAb[row * NH + h];
        float dtv = DTb[row * NH + h];
        float bv = BCb[row * 128 + lane];
        float cv = BCb[row * 128 + 64 + lane];
        float xhv = 0.f;
        if (lane < HD) {
            float raw = XBC[row * XBCLD + h * HD + lane];
            float cvv = cb + cw0 * wA + cw1 * wB + cw2 * wC + cw3 * raw;
            xhv = cvv / (1.f + expf(-cvv));
            wA = wB; wB = wC; wC = raw;
        }
        float xv = dtv * xhv;
        float part[16];
#pragma unroll
        for (int p = 0; p < 16; p++) {
            float d = __shfl(xv, p);
            st[p] = fmaf(da, st[p], d * bv);
            part[p] = st[p] * cv;
        }
#pragma unroll
        for (int m = 1; m < 64; m <<= 1) {
#pragma unroll
            for (int p = 0; p < 16; p++) part[p] += __shfl_xor(part[p], m);
        }
        float ov = 0.f;
#pragma unroll
        for (int p = 0; p < 16; p++) ov = (lane == p) ? part[p] : ov;
        if (lane < HD) XBC[row * XBCLD + h * HD + lane] = ov + ds * xhv;
    }
}

// ---------------- fused z-GEMV + silu gate + RMSNorm (in-place on XBC y-cols) ----------------
__global__ __launch_bounds__(256) void zgate_kernel(
    const float* __restrict__ X, const float* __restrict__ Wip,
    float* __restrict__ XBC, const float* __restrict__ rms_w)
{
    __shared__ float xs[16][DMODEL];
    __shared__ float red[16][4];
    int row0 = blockIdx.x * 16;
    int tid = threadIdx.x;
#pragma unroll
    for (int r = 0; r < 16; r++)
        xs[r][tid] = X[(long long)(row0 + r) * DMODEL + tid];
    __syncthreads();
    float z0[16], z1[16];
#pragma unroll
    for (int r = 0; r < 16; r++) { z0[r] = 0.f; z1[r] = 0.f; }
    for (int k = 0; k < DMODEL; k++) {
        float w0 = Wip[(long long)k * DINPROJ + tid];
        float w1 = Wip[(long long)k * DINPROJ + 256 + tid];
#pragma unroll
        for (int r = 0; r < 16; r++) {
            float xv = xs[r][k];
            z0[r] = fmaf(xv, w0, z0[r]);
            z1[r] = fmaf(xv, w1, z1[r]);
        }
    }
    int wv = tid >> 6, lane = tid & 63;
    float g0[16], g1[16];
#pragma unroll
    for (int r = 0; r < 16; r++) {
        long long row = row0 + r;
        float y0 = XBC[row * XBCLD + tid];
        float y1 = XBC[row * XBCLD + 256 + tid];
        float zz0 = z0[r], zz1 = z1[r];
        float a0 = y0 * (zz0 / (1.f + expf(-zz0)));
        float a1 = y1 * (zz1 / (1.f + expf(-zz1)));
        g0[r] = a0; g1[r] = a1;
        float val = fmaf(a0, a0, a1 * a1);
#pragma unroll
        for (int m = 1; m < 64; m <<= 1) val += __shfl_xor(val, m);
        if (lane == 0) red[r][wv] = val;
    }
    __syncthreads();
#pragma unroll
    for (int r = 0; r < 16; r++) {
        long long row = row0 + r;
        float ss = red[r][0] + red[r][1] + red[r][2] + red[r][3];
        float sc = rsqrtf(ss * (1.f / 512.f) + 1e-5f);
        XBC[row * XBCLD + tid]       = g0[r] * sc * rms_w[tid];
        XBC[row * XBCLD + 256 + tid] = g1[r] * sc * rms_w[256 + tid];
    }
}

// ---------------- LayerNorm(a+b)*g+be ----------------
__global__ void lnadd_kernel(const float* __restrict__ A, const float* __restrict__ Bb,
                             const float* __restrict__ g, const float* __restrict__ be,
                             float* __restrict__ O)
{
    int row = blockIdx.x * 4 + (threadIdx.x >> 6);
    int lane = threadIdx.x & 63;
    long long base = (long long)row * DMODEL + lane * 4;
    float v[4]; float s1 = 0.f;
#pragma unroll
    for (int i = 0; i < 4; i++) { float a = A[base + i] + Bb[base + i]; v[i] = a; s1 += a; }
#pragma unroll
    for (int m = 1; m < 64; m <<= 1) s1 += __shfl_xor(s1, m);
    float mean = s1 * (1.f / 256.f);
    float s2 = 0.f;
#pragma unroll
    for (int i = 0; i < 4; i++) { float d = v[i] - mean; s2 = fmaf(d, d, s2); }
#pragma unroll
    for (int m = 1; m < 64; m <<= 1) s2 += __shfl_xor(s2, m);
    float r = rsqrtf(s2 * (1.f / 256.f) + 1e-12f);
#pragma unroll
    for (int i = 0; i < 4; i++)
        O[base + i] = (v[i] - mean) * r * g[lane * 4 + i] + be[lane * 4 + i];
}

// ---------------- combine: H = alpha*h1 + beta*LN(xi+x)  (in-place on H1) ----------------
__global__ void combine_kernel(const float* __restrict__ XI, const float* __restrict__ X,
                               float* __restrict__ H1,
                               const float* __restrict__ fg, const float* __restrict__ fb,
                               const float* __restrict__ al, const float* __restrict__ bt)
{
    int row = blockIdx.x * 4 + (threadIdx.x >> 6);
    int lane = threadIdx.x & 63;
    long long base = (long long)row * DMODEL + lane * 4;
    float v[4]; float s1 = 0.f;
#pragma unroll
    for (int i = 0; i < 4; i++) { float a = XI[base + i] + X[base + i]; v[i] = a; s1 += a; }
#pragma unroll
    for (int m = 1; m < 64; m <<= 1) s1 += __shfl_xor(s1, m);
    float mean = s1 * (1.f / 256.f);
    float s2 = 0.f;
#pragma unroll
    for (int i = 0; i < 4; i++) { float d = v[i] - mean; s2 = fmaf(d, d, s2); }
#pragma unroll
    for (int m = 1; m < 64; m <<= 1) s2 += __shfl_xor(s2, m);
    float r = rsqrtf(s2 * (1.f / 256.f) + 1e-12f);
#pragma unroll
    for (int i = 0; i < 4; i++) {
        float h2 = (v[i] - mean) * r * fg[lane * 4 + i] + fb[lane * 4 + i];
        H1[base + i] = al[lane * 4 + i] * H1[base + i] + bt[lane * 4 + i] * h2;
    }
}

// ---------------- pointwise spectral filter (in place) ----------------
__global__ void filt_kernel(float* __restrict__ XF, const float* __restrict__ W)
{
    long long idx = (long long)blockIdx.x * 256 + threadIdx.x;
    if (idx >= (long long)BATCHN * NF * DMODEL) return;
    int d = (int)(idx % DMODEL);
    int f = (int)((idx / DMODEL) % NF);
    int b = (int)(idx / ((long long)DMODEL * NF));
    long long re_i = ((long long)b * NJ + f) * DMODEL + d;
    long long im_i = ((long long)b * NJ + 101 + f) * DMODEL + d;
    float re = XF[re_i], im = XF[im_i];
    float wr = W[((long long)f * DMODEL + d) * 2];
    float wi = W[((long long)f * DMODEL + d) * 2 + 1];
    XF[re_i] = re * wr - im * wi;
    XF[im_i] = re * wi + im * wr;
}

extern "C" void kernel_launch(void* const* d_in, const int* in_sizes, int n_in,
                              void* d_out, int out_size, void* d_ws, size_t ws_size,
                              hipStream_t stream)
{
    const float* x          = (const float*)d_in[0];
    const float* in_proj_w  = (const float*)d_in[1];
    const float* conv_w     = (const float*)d_in[2];
    const float* conv_b     = (const float*)d_in[3];
    const float* dt_bias    = (const float*)d_in[4];
    const float* A_log      = (const float*)d_in[5];
    const float* D_skip     = (const float*)d_in[6];
    const float* rms_w      = (const float*)d_in[7];
    const float* out_proj_w = (const float*)d_in[8];
    const float* ln_g       = (const float*)d_in[9];
    const float* ln_b       = (const float*)d_in[10];
    const float* filt_w     = (const float*)d_in[11];
    const float* filt_ln_g  = (const float*)d_in[12];
    const float* filt_ln_b  = (const float*)d_in[13];
    const float* alpha      = (const float*)d_in[14];
    const float* beta       = (const float*)d_in[15];
    const float* ffn_w1     = (const float*)d_in[16];
    const float* ffn_b1     = (const float*)d_in[17];
    const float* ffn_w2     = (const float*)d_in[18];
    const float* ffn_b2     = (const float*)d_in[19];
    const float* ffn_ln_g   = (const float*)d_in[20];
    const float* ffn_ln_b   = (const float*)d_in[21];
    float* out = (float*)d_out;
    float* ws = (float*)d_ws;

    // workspace layout (floats), peak ~219 MiB
    float* E_FWD = ws;                                   // 40400
    float* E_INV = ws + 40400;                           // 40400 (pad to 81920)
    float* XBC   = ws + 81920;                           // BL*672  (xBC raw | y | G | later XF/XI/HID/FFO)
    float* BCb   = XBC + (long long)BL * XBCLD;          // BL*128
    float* DTb   = BCb + (long long)BL * 128;            // BL*32
    float* DAb   = DTb + (long long)BL * NH;             // BL*32
    float* MO    = DAb + (long long)BL * NH;             // BL*256  (h1 / H)
    // post-scan reuse of XBC region:
    float* XF  = XBC;                                    // 256*202*256 = 13,238,272
    float* XI  = XBC + (long long)BATCHN * NJ * DMODEL;  // BL*256
    float* HID = XBC;                                    // BL*256 (per K-quarter)
    float* FFO = XBC + (long long)BL * DMODEL;           // BL*256

    // 1. DFT matrices
    init_dft_kernel<<<dim3((2 * NJ * SEQ + 255) / 256), dim3(256), 0, stream>>>(E_FWD, E_INV);

    // 2. in_proj partial GEMM (xBC + dt cols only): [BL,256]@[256,672] -> XBC
    gemm_kernel<0><<<dim3(11, BL / 64, 1), dim3(256), 0, stream>>>(
        x, in_proj_w + 512, XBC, nullptr, BL, XBCLD, DMODEL, DMODEL, DINPROJ, XBCLD, 0, 0, 0);

    // 3. conv+silu for B/C channels; dt -> DT/DA
    convbc_kernel<<<dim3(BL), dim3(192), 0, stream>>>(XBC, conv_w, conv_b, dt_bias, A_log,
                                                      BCb, DTb, DAb);

    // 4. scan (fused x-channel conv + silu + D_skip), y written in-place into XBC cols 0..511
    scan2_kernel<<<dim3(BATCHN * NH / 4), dim3(256), 0, stream>>>(DTb, DAb, XBC, BCb, D_skip,
                                                                  conv_w, conv_b);

    // 5. fused z-GEMV + gate + RMSNorm (in-place: XBC cols 0..511 become G)
    zgate_kernel<<<dim3(BL / 16), dim3(256), 0, stream>>>(x, in_proj_w, XBC, rms_w);

    // 6. out_proj GEMM: [BL,512(stride 672)]@[512,256] -> MO
    gemm_kernel<0><<<dim3(4, BL / 64, 1), dim3(256), 0, stream>>>(
        XBC, out_proj_w, MO, nullptr, BL, DMODEL, DINNER, XBCLD, DMODEL, DMODEL, 0, 0, 0);

    // 7. h1 = LN(MO + x) in place
    lnadd_kernel<<<dim3(BL / 4), dim3(256), 0, stream>>>(MO, x, ln_g, ln_b, MO);

    // 8. FFT forward: per-b GEMM E_FWD[202,200] @ x_b[200,256] -> XF (XBC region now dead)
    gemm_kernel<0><<<dim3(4, 4, BATCHN), dim3(256), 0, stream>>>(
        E_FWD, x, XF, nullptr, NJ, DMODEL, SEQ, SEQ, DMODEL, DMODEL,
        0, (long long)SEQ * DMODEL, (long long)NJ * DMODEL);

    // 9. pointwise complex filter (in place)
    filt_kernel<<<dim3((BATCHN * NF * DMODEL + 255) / 256), dim3(256), 0, stream>>>(XF, filt_w);

    // 10. FFT inverse: per-b GEMM E_INV[200,202] @ XF_b[202,256] -> XI
    gemm_kernel<0><<<dim3(4, 4, BATCHN), dim3(256), 0, stream>>>(
        E_INV, XF, XI, nullptr, SEQ, DMODEL, NJ, NJ, DMODEL, DMODEL,
        0, (long long)NJ * DMODEL, (long long)SEQ * DMODEL);

    // 11. combine: MO = alpha*h1 + beta*LN(XI + x)   (in place on MO)
    combine_kernel<<<dim3(BL / 4), dim3(256), 0, stream>>>(XI, x, MO, filt_ln_g, filt_ln_b,
                                                           alpha, beta);

    // 12/13. FFN in K-quarters: HID_q = GELU(H@W1_q + b1_q); FFO (+)= HID_q @ W2_q
    for (int q = 0; q < 4; q++) {
        gemm_kernel<1><<<dim3(4, BL / 64, 1), dim3(256), 0, stream>>>(
            MO, ffn_w1 + q * 256, HID, ffn_b1 + q * 256, BL, 256, DMODEL, DMODEL, 1024, 256, 0, 0, 0);
        if (q == 0)
            gemm_kernel<0><<<dim3(4, BL / 64, 1), dim3(256), 0, stream>>>(
                HID, ffn_w2 + q * 256 * DMODEL, FFO, ffn_b2, BL, DMODEL, 256, 256, DMODEL, DMODEL, 0, 0, 0);
        else
            gemm_kernel<2><<<dim3(4, BL / 64, 1), dim3(256), 0, stream>>>(
                HID, ffn_w2 + q * 256 * DMODEL, FFO, nullptr, BL, DMODEL, 256, 256, DMODEL, DMODEL, 0, 0, 0);
    }

    // 14. out = LN(FFO + H)
    lnadd_kernel<<<dim3(BL / 4), dim3(256), 0, stream>>>(FFO, MO, ffn_ln_g, ffn_ln_b, out);
}

// Round 3
// 3300.753 us; speedup vs baseline: 1.4151x; 1.4151x over previous
//
#include <hip/hip_runtime.h>
#include <math.h>

#define BATCHN 256
#define SEQ 200
#define DMODEL 256
#define DINNER 512
#define NH 32
#define HD 16
#define DSTATE 64
#define DINPROJ 1184
#define XBCLD 672
#define BL (BATCHN*SEQ)   // 51200
#define NF 101
#define NJ 202

// ---------------- DFT matrix init ----------------
__global__ void init_dft_kernel(float* __restrict__ EF, float* __restrict__ EI)
{
    const float ang = 6.28318530717958647692f / 200.0f;
    int idx = blockIdx.x * 256 + threadIdx.x;
    if (idx < NJ * SEQ) {
        int f = idx / SEQ, t = idx - f * SEQ;
        float v;
        if (f <= 100) {
            int ph = (f * t) % 200;
            v = cosf(ang * (float)ph);
        } else {
            int ff = f - 101;
            int ph = (ff * t) % 200;
            v = -sinf(ang * (float)ph);
        }
        EF[idx] = v;
    } else if (idx < 2 * NJ * SEQ) {
        int j2 = idx - NJ * SEQ;
        int t = j2 / NJ, j = j2 - t * NJ;
        float v;
        if (j == 0) v = 1.0f / 200.0f;
        else if (j == 100) v = ((t & 1) ? -1.0f : 1.0f) / 200.0f;
        else if (j < 100) { int ph = (j * t) % 200; v = 2.0f * cosf(ang * (float)ph) / 200.0f; }
        else if (j == 101 || j == 201) v = 0.0f;
        else { int f = j - 101; int ph = (f * t) % 200; v = -2.0f * sinf(ang * (float)ph) / 200.0f; }
        EI[j2] = v;
    }
}

// ---------------- generic fp32 tiled GEMM ----------------
// ACT: 0 = none(+bias), 1 = bias+GELU, 2 = accumulate into C (no bias)
template<int ACT>
__global__ __launch_bounds__(256) void gemm_kernel(
    const float* __restrict__ A, const float* __restrict__ B, float* __restrict__ C,
    const float* __restrict__ bias,
    int M, int N, int K, int lda, int ldb, int ldc,
    long long sA, long long sB, long long sC)
{
    __shared__ float As[16][64];
    __shared__ float Bs[16][64];
    A += (long long)blockIdx.z * sA;
    B += (long long)blockIdx.z * sB;
    C += (long long)blockIdx.z * sC;
    int m0 = blockIdx.y * 64, n0 = blockIdx.x * 64;
    int tid = threadIdx.x;
    int tm = tid >> 4, tn = tid & 15;
    int am = tid >> 2, ak = (tid & 3) * 4;
    int bk = tid >> 4, bn = (tid & 15) * 4;
    float acc[4][4];
#pragma unroll
    for (int i = 0; i < 4; i++)
#pragma unroll
        for (int j = 0; j < 4; j++) acc[i][j] = 0.f;

    for (int k0 = 0; k0 < K; k0 += 16) {
        int gm = m0 + am;
#pragma unroll
        for (int i = 0; i < 4; i++) {
            int gk = k0 + ak + i;
            As[ak + i][am] = (gm < M && gk < K) ? A[(long long)gm * lda + gk] : 0.f;
        }
        int gk = k0 + bk;
#pragma unroll
        for (int i = 0; i < 4; i++) {
            int gn = n0 + bn + i;
            Bs[bk][bn + i] = (gk < K && gn < N) ? B[(long long)gk * ldb + gn] : 0.f;
        }
        __syncthreads();
#pragma unroll
        for (int kk = 0; kk < 16; kk++) {
            float a[4], bb[4];
#pragma unroll
            for (int i = 0; i < 4; i++) { a[i] = As[kk][tm * 4 + i]; bb[i] = Bs[kk][tn * 4 + i]; }
#pragma unroll
            for (int i = 0; i < 4; i++)
#pragma unroll
                for (int j = 0; j < 4; j++)
                    acc[i][j] = fmaf(a[i], bb[j], acc[i][j]);
        }
        __syncthreads();
    }
#pragma unroll
    for (int i = 0; i < 4; i++) {
        int gm = m0 + tm * 4 + i;
        if (gm >= M) continue;
#pragma unroll
        for (int j = 0; j < 4; j++) {
            int gn = n0 + tn * 4 + j;
            if (gn >= N) continue;
            float v = acc[i][j];
            long long ci = (long long)gm * ldc + gn;
            if (ACT == 2) {
                C[ci] += v;
            } else {
                if (bias) v += bias[gn];
                if (ACT == 1) v = 0.5f * v * (1.f + erff(v * 0.70710678118654752f));
                C[ci] = v;
            }
        }
    }
}

// ---------------- conv+silu for B/C channels, dt/dA ----------------
__global__ void convbc_kernel(const float* __restrict__ XBC, const float* __restrict__ conv_w,
                              const float* __restrict__ conv_b, const float* __restrict__ dt_bias,
                              const float* __restrict__ A_log,
                              float* __restrict__ BCb, float* __restrict__ DTb, float* __restrict__ DAb)
{
    int row = blockIdx.x;
    int b = row / SEQ, l = row - b * SEQ;
    int tid = threadIdx.x;
    if (tid < 128) {
        int ch = 512 + tid;                     // conv channel == local XBC col
        float acc = conv_b[ch];
#pragma unroll
        for (int k = 0; k < 4; k++) {
            int lt = l + k - 3;
            if (lt >= 0)
                acc = fmaf(conv_w[ch * 4 + k], XBC[(long long)(b * SEQ + lt) * XBCLD + ch], acc);
        }
        BCb[(long long)row * 128 + tid] = acc / (1.f + expf(-acc));
    } else if (tid < 160) {
        int h = tid - 128;
        float draw = XBC[(long long)row * XBCLD + 640 + h] + dt_bias[h];
        float dtv = (draw > 20.f) ? draw : log1pf(expf(draw));
        DTb[(long long)row * NH + h] = dtv;
        DAb[(long long)row * NH + h] = expf(-expf(A_log[h]) * dtv);
    }
}

// ---------------- selective scan v3: lane=(g,p), n spread over 16 regs ----------------
// p = lane&15 : head-dim channel (conv+silu computed redundantly per lane, no shfl)
// g = lane>>4 : state-col quarter, n = g*16+r
// y[p] = sum_r st[r]*cv[r] reduced in-register, then 2 shfl_xor across groups.
__global__ __launch_bounds__(256) void scan3_kernel(
    const float* __restrict__ DTb, const float* __restrict__ DAb,
    float* __restrict__ XBC, const float* __restrict__ BCb,
    const float* __restrict__ Dsk,
    const float* __restrict__ conv_w, const float* __restrict__ conv_b)
{
    int wid = blockIdx.x * 4 + (threadIdx.x >> 6);
    int lane = threadIdx.x & 63;
    int b = wid >> 5, h = wid & 31;
    int p = lane & 15;
    int g = lane >> 4;
    int ch = h * HD + p;
    float cw0 = conv_w[ch * 4 + 0], cw1 = conv_w[ch * 4 + 1];
    float cw2 = conv_w[ch * 4 + 2], cw3 = conv_w[ch * 4 + 3];
    float cb = conv_b[ch];
    float ds = Dsk[h];
    float wA = 0.f, wB = 0.f, wC = 0.f;
    float st[16];
#pragma unroll
    for (int r = 0; r < 16; r++) st[r] = 0.f;
    long long rowbase = (long long)b * SEQ;
    for (int t = 0; t < SEQ; t++) {
        long long row = rowbase + t;
        float da = DAb[row * NH + h];
        float dtv = DTb[row * NH + h];
        float raw = XBC[row * XBCLD + h * HD + p];
        const float4* bq = (const float4*)(BCb + row * 128 + g * 16);
        const float4* cq = (const float4*)(BCb + row * 128 + 64 + g * 16);
        float4 b0 = bq[0], b1 = bq[1], b2 = bq[2], b3 = bq[3];
        float4 c0 = cq[0], c1 = cq[1], c2 = cq[2], c3 = cq[3];
        float cvv = cb + cw0 * wA + cw1 * wB + cw2 * wC + cw3 * raw;
        float xhv = cvv / (1.f + expf(-cvv));
        wA = wB; wB = wC; wC = raw;
        float xv = dtv * xhv;
        float part = 0.f;
        st[0]  = fmaf(da, st[0],  xv * b0.x); part = fmaf(st[0],  c0.x, part);
        st[1]  = fmaf(da, st[1],  xv * b0.y); part = fmaf(st[1],  c0.y, part);
        st[2]  = fmaf(da, st[2],  xv * b0.z); part = fmaf(st[2],  c0.z, part);
        st[3]  = fmaf(da, st[3],  xv * b0.w); part = fmaf(st[3],  c0.w, part);
        st[4]  = fmaf(da, st[4],  xv * b1.x); part = fmaf(st[4],  c1.x, part);
        st[5]  = fmaf(da, st[5],  xv * b1.y); part = fmaf(st[5],  c1.y, part);
        st[6]  = fmaf(da, st[6],  xv * b1.z); part = fmaf(st[6],  c1.z, part);
        st[7]  = fmaf(da, st[7],  xv * b1.w); part = fmaf(st[7],  c1.w, part);
        st[8]  = fmaf(da, st[8],  xv * b2.x); part = fmaf(st[8],  c2.x, part);
        st[9]  = fmaf(da, st[9],  xv * b2.y); part = fmaf(st[9],  c2.y, part);
        st[10] = fmaf(da, st[10], xv * b2.z); part = fmaf(st[10], c2.z, part);
        st[11] = fmaf(da, st[11], xv * b2.w); part = fmaf(st[11], c2.w, part);
        st[12] = fmaf(da, st[12], xv * b3.x); part = fmaf(st[12], c3.x, part);
        st[13] = fmaf(da, st[13], xv * b3.y); part = fmaf(st[13], c3.y, part);
        st[14] = fmaf(da, st[14], xv * b3.z); part = fmaf(st[14], c3.z, part);
        st[15] = fmaf(da, st[15], xv * b3.w); part = fmaf(st[15], c3.w, part);
        part += __shfl_xor(part, 16);
        part += __shfl_xor(part, 32);
        if (lane < HD)
            XBC[row * XBCLD + h * HD + p] = part + ds * xhv;
    }
}

// ---------------- fused z-GEMV + silu gate + RMSNorm (in-place on XBC y-cols) ----------------
__global__ __launch_bounds__(256) void zgate_kernel(
    const float* __restrict__ X, const float* __restrict__ Wip,
    float* __restrict__ XBC, const float* __restrict__ rms_w)
{
    __shared__ float xs[16][DMODEL];
    __shared__ float red[16][4];
    int row0 = blockIdx.x * 16;
    int tid = threadIdx.x;
#pragma unroll
    for (int r = 0; r < 16; r++)
        xs[r][tid] = X[(long long)(row0 + r) * DMODEL + tid];
    __syncthreads();
    float z0[16], z1[16];
#pragma unroll
    for (int r = 0; r < 16; r++) { z0[r] = 0.f; z1[r] = 0.f; }
    for (int k = 0; k < DMODEL; k++) {
        float w0 = Wip[(long long)k * DINPROJ + tid];
        float w1 = Wip[(long long)k * DINPROJ + 256 + tid];
#pragma unroll
        for (int r = 0; r < 16; r++) {
            float xv = xs[r][k];
            z0[r] = fmaf(xv, w0, z0[r]);
            z1[r] = fmaf(xv, w1, z1[r]);
        }
    }
    int wv = tid >> 6, lane = tid & 63;
    float g0[16], g1[16];
#pragma unroll
    for (int r = 0; r < 16; r++) {
        long long row = row0 + r;
        float y0 = XBC[row * XBCLD + tid];
        float y1 = XBC[row * XBCLD + 256 + tid];
        float zz0 = z0[r], zz1 = z1[r];
        float a0 = y0 * (zz0 / (1.f + expf(-zz0)));
        float a1 = y1 * (zz1 / (1.f + expf(-zz1)));
        g0[r] = a0; g1[r] = a1;
        float val = fmaf(a0, a0, a1 * a1);
#pragma unroll
        for (int m = 1; m < 64; m <<= 1) val += __shfl_xor(val, m);
        if (lane == 0) red[r][wv] = val;
    }
    __syncthreads();
#pragma unroll
    for (int r = 0; r < 16; r++) {
        long long row = row0 + r;
        float ss = red[r][0] + red[r][1] + red[r][2] + red[r][3];
        float sc = rsqrtf(ss * (1.f / 512.f) + 1e-5f);
        XBC[row * XBCLD + tid]       = g0[r] * sc * rms_w[tid];
        XBC[row * XBCLD + 256 + tid] = g1[r] * sc * rms_w[256 + tid];
    }
}

// ---------------- LayerNorm(a+b)*g+be ----------------
__global__ void lnadd_kernel(const float* __restrict__ A, const float* __restrict__ Bb,
                             const float* __restrict__ g, const float* __restrict__ be,
                             float* __restrict__ O)
{
    int row = blockIdx.x * 4 + (threadIdx.x >> 6);
    int lane = threadIdx.x & 63;
    long long base = (long long)row * DMODEL + lane * 4;
    float v[4]; float s1 = 0.f;
#pragma unroll
    for (int i = 0; i < 4; i++) { float a = A[base + i] + Bb[base + i]; v[i] = a; s1 += a; }
#pragma unroll
    for (int m = 1; m < 64; m <<= 1) s1 += __shfl_xor(s1, m);
    float mean = s1 * (1.f / 256.f);
    float s2 = 0.f;
#pragma unroll
    for (int i = 0; i < 4; i++) { float d = v[i] - mean; s2 = fmaf(d, d, s2); }
#pragma unroll
    for (int m = 1; m < 64; m <<= 1) s2 += __shfl_xor(s2, m);
    float r = rsqrtf(s2 * (1.f / 256.f) + 1e-12f);
#pragma unroll
    for (int i = 0; i < 4; i++)
        O[base + i] = (v[i] - mean) * r * g[lane * 4 + i] + be[lane * 4 + i];
}

// ---------------- combine: H = alpha*h1 + beta*LN(xi+x)  (in-place on H1) ----------------
__global__ void combine_kernel(const float* __restrict__ XI, const float* __restrict__ X,
                               float* __restrict__ H1,
                               const float* __restrict__ fg, const float* __restrict__ fb,
                               const float* __restrict__ al, const float* __restrict__ bt)
{
    int row = blockIdx.x * 4 + (threadIdx.x >> 6);
    int lane = threadIdx.x & 63;
    long long base = (long long)row * DMODEL + lane * 4;
    float v[4]; float s1 = 0.f;
#pragma unroll
    for (int i = 0; i < 4; i++) { float a = XI[base + i] + X[base + i]; v[i] = a; s1 += a; }
#pragma unroll
    for (int m = 1; m < 64; m <<= 1) s1 += __shfl_xor(s1, m);
    float mean = s1 * (1.f / 256.f);
    float s2 = 0.f;
#pragma unroll
    for (int i = 0; i < 4; i++) { float d = v[i] - mean; s2 = fmaf(d, d, s2); }
#pragma unroll
    for (int m = 1; m < 64; m <<= 1) s2 += __shfl_xor(s2, m);
    float r = rsqrtf(s2 * (1.f / 256.f) + 1e-12f);
#pragma unroll
    for (int i = 0; i < 4; i++) {
        float h2 = (v[i] - mean) * r * fg[lane * 4 + i] + fb[lane * 4 + i];
        H1[base + i] = al[lane * 4 + i] * H1[base + i] + bt[lane * 4 + i] * h2;
    }
}

// ---------------- pointwise spectral filter (in place) ----------------
__global__ void filt_kernel(float* __restrict__ XF, const float* __restrict__ W)
{
    long long idx = (long long)blockIdx.x * 256 + threadIdx.x;
    if (idx >= (long long)BATCHN * NF * DMODEL) return;
    int d = (int)(idx % DMODEL);
    int f = (int)((idx / DMODEL) % NF);
    int b = (int)(idx / ((long long)DMODEL * NF));
    long long re_i = ((long long)b * NJ + f) * DMODEL + d;
    long long im_i = ((long long)b * NJ + 101 + f) * DMODEL + d;
    float re = XF[re_i], im = XF[im_i];
    float wr = W[((long long)f * DMODEL + d) * 2];
    float wi = W[((long long)f * DMODEL + d) * 2 + 1];
    XF[re_i] = re * wr - im * wi;
    XF[im_i] = re * wi + im * wr;
}

extern "C" void kernel_launch(void* const* d_in, const int* in_sizes, int n_in,
                              void* d_out, int out_size, void* d_ws, size_t ws_size,
                              hipStream_t stream)
{
    const float* x          = (const float*)d_in[0];
    const float* in_proj_w  = (const float*)d_in[1];
    const float* conv_w     = (const float*)d_in[2];
    const float* conv_b     = (const float*)d_in[3];
    const float* dt_bias    = (const float*)d_in[4];
    const float* A_log      = (const float*)d_in[5];
    const float* D_skip     = (const float*)d_in[6];
    const float* rms_w      = (const float*)d_in[7];
    const float* out_proj_w = (const float*)d_in[8];
    const float* ln_g       = (const float*)d_in[9];
    const float* ln_b       = (const float*)d_in[10];
    const float* filt_w     = (const float*)d_in[11];
    const float* filt_ln_g  = (const float*)d_in[12];
    const float* filt_ln_b  = (const float*)d_in[13];
    const float* alpha      = (const float*)d_in[14];
    const float* beta       = (const float*)d_in[15];
    const float* ffn_w1     = (const float*)d_in[16];
    const float* ffn_b1     = (const float*)d_in[17];
    const float* ffn_w2     = (const float*)d_in[18];
    const float* ffn_b2     = (const float*)d_in[19];
    const float* ffn_ln_g   = (const float*)d_in[20];
    const float* ffn_ln_b   = (const float*)d_in[21];
    float* out = (float*)d_out;
    float* ws = (float*)d_ws;

    // workspace layout (floats), peak ~219 MiB
    float* E_FWD = ws;                                   // 40400
    float* E_INV = ws + 40400;                           // 40400 (pad to 81920)
    float* XBC   = ws + 81920;                           // BL*672  (xBC raw | y | G | later XF/XI/HID/FFO)
    float* BCb   = XBC + (long long)BL * XBCLD;          // BL*128
    float* DTb   = BCb + (long long)BL * 128;            // BL*32
    float* DAb   = DTb + (long long)BL * NH;             // BL*32
    float* MO    = DAb + (long long)BL * NH;             // BL*256  (h1 / H)
    // post-scan reuse of XBC region:
    float* XF  = XBC;                                    // 256*202*256 = 13,238,272
    float* XI  = XBC + (long long)BATCHN * NJ * DMODEL;  // BL*256
    float* HID = XBC;                                    // BL*256 (per K-quarter)
    float* FFO = XBC + (long long)BL * DMODEL;           // BL*256

    // 1. DFT matrices
    init_dft_kernel<<<dim3((2 * NJ * SEQ + 255) / 256), dim3(256), 0, stream>>>(E_FWD, E_INV);

    // 2. in_proj partial GEMM (xBC + dt cols only): [BL,256]@[256,672] -> XBC
    gemm_kernel<0><<<dim3(11, BL / 64, 1), dim3(256), 0, stream>>>(
        x, in_proj_w + 512, XBC, nullptr, BL, XBCLD, DMODEL, DMODEL, DINPROJ, XBCLD, 0, 0, 0);

    // 3. conv+silu for B/C channels; dt -> DT/DA
    convbc_kernel<<<dim3(BL), dim3(192), 0, stream>>>(XBC, conv_w, conv_b, dt_bias, A_log,
                                                      BCb, DTb, DAb);

    // 4. scan v3 (fused x-channel conv + silu + D_skip), y in-place into XBC cols 0..511
    scan3_kernel<<<dim3(BATCHN * NH / 4), dim3(256), 0, stream>>>(DTb, DAb, XBC, BCb, D_skip,
                                                                  conv_w, conv_b);

    // 5. fused z-GEMV + gate + RMSNorm (in-place: XBC cols 0..511 become G)
    zgate_kernel<<<dim3(BL / 16), dim3(256), 0, stream>>>(x, in_proj_w, XBC, rms_w);

    // 6. out_proj GEMM: [BL,512(stride 672)]@[512,256] -> MO
    gemm_kernel<0><<<dim3(4, BL / 64, 1), dim3(256), 0, stream>>>(
        XBC, out_proj_w, MO, nullptr, BL, DMODEL, DINNER, XBCLD, DMODEL, DMODEL, 0, 0, 0);

    // 7. h1 = LN(MO + x) in place
    lnadd_kernel<<<dim3(BL / 4), dim3(256), 0, stream>>>(MO, x, ln_g, ln_b, MO);

    // 8. FFT forward: per-b GEMM E_FWD[202,200] @ x_b[200,256] -> XF (XBC region now dead)
    gemm_kernel<0><<<dim3(4, 4, BATCHN), dim3(256), 0, stream>>>(
        E_FWD, x, XF, nullptr, NJ, DMODEL, SEQ, SEQ, DMODEL, DMODEL,
        0, (long long)SEQ * DMODEL, (long long)NJ * DMODEL);

    // 9. pointwise complex filter (in place)
    filt_kernel<<<dim3((BATCHN * NF * DMODEL + 255) / 256), dim3(256), 0, stream>>>(XF, filt_w);

    // 10. FFT inverse: per-b GEMM E_INV[200,202] @ XF_b[202,256] -> XI
    gemm_kernel<0><<<dim3(4, 4, BATCHN), dim3(256), 0, stream>>>(
        E_INV, XF, XI, nullptr, SEQ, DMODEL, NJ, NJ, DMODEL, DMODEL,
        0, (long long)NJ * DMODEL, (long long)SEQ * DMODEL);

    // 11. combine: MO = alpha*h1 + beta*LN(XI + x)   (in place on MO)
    combine_kernel<<<dim3(BL / 4), dim3(256), 0, stream>>>(XI, x, MO, filt_ln_g, filt_ln_b,
                                                           alpha, beta);

    // 12/13. FFN in K-quarters: HID_q = GELU(H@W1_q + b1_q); FFO (+)= HID_q @ W2_q
    for (int q = 0; q < 4; q++) {
        gemm_kernel<1><<<dim3(4, BL / 64, 1), dim3(256), 0, stream>>>(
            MO, ffn_w1 + q * 256, HID, ffn_b1 + q * 256, BL, 256, DMODEL, DMODEL, 1024, 256, 0, 0, 0);
        if (q == 0)
            gemm_kernel<0><<<dim3(4, BL / 64, 1), dim3(256), 0, stream>>>(
                HID, ffn_w2 + q * 256 * DMODEL, FFO, ffn_b2, BL, DMODEL, 256, 256, DMODEL, DMODEL, 0, 0, 0);
        else
            gemm_kernel<2><<<dim3(4, BL / 64, 1), dim3(256), 0, stream>>>(
                HID, ffn_w2 + q * 256 * DMODEL, FFO, nullptr, BL, DMODEL, 256, 256, DMODEL, DMODEL, 0, 0, 0);
    }

    // 14. out = LN(FFO + H)
    lnadd_kernel<<<dim3(BL / 4), dim3(256), 0, stream>>>(FFO, MO, ffn_ln_g, ffn_ln_b, out);
}

// Round 4
// 1416.771 us; speedup vs baseline: 3.2968x; 2.3298x over previous
//
#include <hip/hip_runtime.h>
#include <math.h>

#define BATCHN 256
#define SEQ 200
#define DMODEL 256
#define DINNER 512
#define NH 32
#define HD 16
#define DSTATE 64
#define DINPROJ 1184
#define XBCLD 672
#define BL (BATCHN*SEQ)   // 51200
#define NF 101
#define NJ 202
#define NJP 208           // padded (16B-aligned bf16 rows)
#define XBASE 655360      // float offset of XBC region in ws

typedef __attribute__((ext_vector_type(8))) short bf16x8;
typedef __attribute__((ext_vector_type(4))) float f32x4;

__device__ inline unsigned short f2bf(float f) {
    union { float f; unsigned u; } v; v.f = f;
    unsigned r = v.u + 0x7FFFu + ((v.u >> 16) & 1u);
    return (unsigned short)(r >> 16);
}
__device__ inline float bf2f(unsigned short h) {
    union { unsigned u; float f; } v; v.u = ((unsigned)h) << 16;
    return v.f;
}

// ---------------- DFT matrices (bf16 direct) ----------------
// EFbf [202][200]: rows 0..100 = cos(2pi f t/200); 101..201 = -sin  (B^T for fwd)
// EIbf [200][208]: A for inverse; cols 202..207 zero pad
__global__ void init_dft_kernel(unsigned short* __restrict__ EF, unsigned short* __restrict__ EI)
{
    const float ang = 6.28318530717958647692f / 200.0f;
    int idx = blockIdx.x * 256 + threadIdx.x;
    if (idx < NJ * SEQ) {
        int f = idx / SEQ, t = idx - f * SEQ;
        float v;
        if (f <= 100) { int ph = (f * t) % 200; v = cosf(ang * (float)ph); }
        else { int ff = f - 101; int ph = (ff * t) % 200; v = -sinf(ang * (float)ph); }
        EF[idx] = f2bf(v);
    } else if (idx < NJ * SEQ + SEQ * NJP) {
        int j2 = idx - NJ * SEQ;
        int t = j2 / NJP, j = j2 - t * NJP;
        float v;
        if (j == 0) v = 1.0f / 200.0f;
        else if (j == 100) v = ((t & 1) ? -1.0f : 1.0f) / 200.0f;
        else if (j < 100) { int ph = (j * t) % 200; v = 2.0f * cosf(ang * (float)ph) / 200.0f; }
        else if (j >= 202 || j == 101 || j == 201) v = 0.0f;
        else { int f = j - 101; int ph = (f * t) % 200; v = -2.0f * sinf(ang * (float)ph) / 200.0f; }
        EI[j2] = f2bf(v);
    }
}

// ---------------- weight pack: dst[n][k] = bf16(src[k][coloff+n]) ----------------
__global__ void pack_wT_kernel(const float* __restrict__ src, unsigned short* __restrict__ dst,
                               int srcld, int coloff, int N, int K)
{
    int idx = blockIdx.x * 256 + threadIdx.x;
    if (idx >= N * K) return;
    int n = idx / K, k = idx - n * K;
    dst[idx] = f2bf(src[(long long)k * srcld + coloff + n]);
}

// ---------------- x transpose: xT[b][d][t] = bf16(x[b][t][d]) ----------------
__global__ void xT_kernel(const float* __restrict__ X, unsigned short* __restrict__ XT)
{
    __shared__ float tile[32][33];
    int b = blockIdx.z, t0 = blockIdx.x * 32, d0 = blockIdx.y * 32;
    int tx = threadIdx.x & 31, ty = threadIdx.x >> 5;  // ty 0..7
    const float* xb = X + (long long)b * SEQ * DMODEL;
#pragma unroll
    for (int i = 0; i < 4; i++) {
        int t = t0 + ty + i * 8;
        tile[ty + i * 8][tx] = (t < SEQ) ? xb[(long long)t * DMODEL + d0 + tx] : 0.f;
    }
    __syncthreads();
    unsigned short* xtb = XT + (long long)b * DMODEL * SEQ;
#pragma unroll
    for (int i = 0; i < 4; i++) {
        int d = d0 + ty + i * 8;
        int t = t0 + tx;
        if (t < SEQ) xtb[(long long)d * SEQ + t] = f2bf(tile[tx][ty + i * 8]);
    }
}

// ---------------- bf16 MFMA GEMM ----------------
// C[M,N](f32|bf16) = A[M,K](f32|bf16, ld lda) @ BT[N,K](bf16, ld ldbt)^T  (+bias)(+GELU)
// 128x128 tile, BK=32, 4 waves (2x2), 4x4 16x16x32 frags per wave.
template<int ACT, int ABF, int CBF>
__global__ __launch_bounds__(256) void mgemm_kernel(
    const void* __restrict__ Ap, const unsigned short* __restrict__ BTp, void* __restrict__ Cp,
    const float* __restrict__ bias,
    int M, int N, int K, int lda, int ldbt, int ldc,
    long long sA, long long sBT, long long sC)
{
    __shared__ unsigned short As[128 * 40];
    __shared__ unsigned short Bs[128 * 40];
    const float* Af = (const float*)Ap + (ABF ? 0 : (long long)blockIdx.z * sA);
    const unsigned short* Ab = (const unsigned short*)Ap + (ABF ? (long long)blockIdx.z * sA : 0);
    const unsigned short* Bt = BTp + (long long)blockIdx.z * sBT;
    float* Cf = (float*)Cp + (CBF ? 0 : (long long)blockIdx.z * sC);
    unsigned short* Cb = (unsigned short*)Cp + (CBF ? (long long)blockIdx.z * sC : 0);

    int m0 = blockIdx.y * 128, n0 = blockIdx.x * 128;
    int tid = threadIdx.x;
    int srow = tid >> 1, skb = (tid & 1) * 16;
    int w = tid >> 6, l = tid & 63;
    int wr = w >> 1, wc = w & 1;
    int fr = l & 15, fk = l >> 4;

    f32x4 acc[4][4] = {};

    for (int k0 = 0; k0 < K; k0 += 32) {
        bool kedge = (k0 + 32 > K);
        // ---- stage A tile [128][32] ----
        {
            int gm = m0 + srow;
            unsigned short* dst = &As[srow * 40 + skb];
            if (gm < M && !kedge) {
                if (ABF) {
                    const unsigned short* src = Ab + (long long)gm * lda + k0 + skb;
                    ((uint4*)dst)[0] = ((const uint4*)src)[0];
                    ((uint4*)dst)[1] = ((const uint4*)src)[1];
                } else {
                    const float* src = Af + (long long)gm * lda + k0 + skb;
                    float4 f0 = ((const float4*)src)[0];
                    float4 f1 = ((const float4*)src)[1];
                    float4 f2 = ((const float4*)src)[2];
                    float4 f3 = ((const float4*)src)[3];
                    uint4 q0, q1;
                    q0.x = (unsigned)f2bf(f0.x) | ((unsigned)f2bf(f0.y) << 16);
                    q0.y = (unsigned)f2bf(f0.z) | ((unsigned)f2bf(f0.w) << 16);
                    q0.z = (unsigned)f2bf(f1.x) | ((unsigned)f2bf(f1.y) << 16);
                    q0.w = (unsigned)f2bf(f1.z) | ((unsigned)f2bf(f1.w) << 16);
                    q1.x = (unsigned)f2bf(f2.x) | ((unsigned)f2bf(f2.y) << 16);
                    q1.y = (unsigned)f2bf(f2.z) | ((unsigned)f2bf(f2.w) << 16);
                    q1.z = (unsigned)f2bf(f3.x) | ((unsigned)f2bf(f3.y) << 16);
                    q1.w = (unsigned)f2bf(f3.z) | ((unsigned)f2bf(f3.w) << 16);
                    ((uint4*)dst)[0] = q0;
                    ((uint4*)dst)[1] = q1;
                }
            } else {
#pragma unroll
                for (int i = 0; i < 16; i++) {
                    int gk = k0 + skb + i;
                    unsigned short v = 0;
                    if (gm < M && gk < K)
                        v = ABF ? Ab[(long long)gm * lda + gk]
                                : f2bf(Af[(long long)gm * lda + gk]);
                    dst[i] = v;
                }
            }
        }
        // ---- stage BT tile [128][32] ----
        {
            int gn = n0 + srow;
            unsigned short* dst = &Bs[srow * 40 + skb];
            if (gn < N && !kedge) {
                const unsigned short* src = Bt + (long long)gn * ldbt + k0 + skb;
                ((uint4*)dst)[0] = ((const uint4*)src)[0];
                ((uint4*)dst)[1] = ((const uint4*)src)[1];
            } else {
#pragma unroll
                for (int i = 0; i < 16; i++) {
                    int gk = k0 + skb + i;
                    dst[i] = (gn < N && gk < K) ? Bt[(long long)gn * ldbt + gk] : (unsigned short)0;
                }
            }
        }
        __syncthreads();
        bf16x8 a[4], b[4];
#pragma unroll
        for (int i = 0; i < 4; i++) {
            a[i] = *(const bf16x8*)&As[(wr * 64 + i * 16 + fr) * 40 + fk * 8];
            b[i] = *(const bf16x8*)&Bs[(wc * 64 + i * 16 + fr) * 40 + fk * 8];
        }
#pragma unroll
        for (int i = 0; i < 4; i++)
#pragma unroll
            for (int j = 0; j < 4; j++)
                acc[i][j] = __builtin_amdgcn_mfma_f32_16x16x32_bf16(a[i], b[j], acc[i][j], 0, 0, 0);
        __syncthreads();
    }

    // epilogue: C row = (lane>>4)*4 + r, col = lane&15 (m89-verified)
#pragma unroll
    for (int i = 0; i < 4; i++) {
        int gr0 = m0 + wr * 64 + i * 16 + fk * 4;
#pragma unroll
        for (int j = 0; j < 4; j++) {
            int gc = n0 + wc * 64 + j * 16 + fr;
            if (gc >= N) continue;
            float bv = bias ? bias[gc] : 0.f;
#pragma unroll
            for (int r = 0; r < 4; r++) {
                int gr = gr0 + r;
                if (gr >= M) continue;
                float v = acc[i][j][r] + bv;
                if (ACT == 1) v = 0.5f * v * (1.f + erff(v * 0.70710678118654752f));
                long long ci = (long long)gr * ldc + gc;
                if (CBF) Cb[ci] = f2bf(v);
                else Cf[ci] = v;
            }
        }
    }
}

// ---------------- conv+silu for B/C channels, dt/dA ----------------
__global__ void convbc_kernel(const float* __restrict__ XBC, const float* __restrict__ conv_w,
                              const float* __restrict__ conv_b, const float* __restrict__ dt_bias,
                              const float* __restrict__ A_log,
                              float* __restrict__ BCb, float* __restrict__ DTb, float* __restrict__ DAb)
{
    int row = blockIdx.x;
    int b = row / SEQ, l = row - b * SEQ;
    int tid = threadIdx.x;
    if (tid < 128) {
        int ch = 512 + tid;
        float acc = conv_b[ch];
#pragma unroll
        for (int k = 0; k < 4; k++) {
            int lt = l + k - 3;
            if (lt >= 0)
                acc = fmaf(conv_w[ch * 4 + k], XBC[(long long)(b * SEQ + lt) * XBCLD + ch], acc);
        }
        BCb[(long long)row * 128 + tid] = acc / (1.f + expf(-acc));
    } else if (tid < 160) {
        int h = tid - 128;
        float draw = XBC[(long long)row * XBCLD + 640 + h] + dt_bias[h];
        float dtv = (draw > 20.f) ? draw : log1pf(expf(draw));
        DTb[(long long)row * NH + h] = dtv;
        DAb[(long long)row * NH + h] = expf(-expf(A_log[h]) * dtv);
    }
}

// ---------------- selective scan v3 (unchanged) ----------------
__global__ __launch_bounds__(256) void scan3_kernel(
    const float* __restrict__ DTb, const float* __restrict__ DAb,
    float* __restrict__ XBC, const float* __restrict__ BCb,
    const float* __restrict__ Dsk,
    const float* __restrict__ conv_w, const float* __restrict__ conv_b)
{
    int wid = blockIdx.x * 4 + (threadIdx.x >> 6);
    int lane = threadIdx.x & 63;
    int b = wid >> 5, h = wid & 31;
    int p = lane & 15;
    int g = lane >> 4;
    int ch = h * HD + p;
    float cw0 = conv_w[ch * 4 + 0], cw1 = conv_w[ch * 4 + 1];
    float cw2 = conv_w[ch * 4 + 2], cw3 = conv_w[ch * 4 + 3];
    float cb = conv_b[ch];
    float ds = Dsk[h];
    float wA = 0.f, wB = 0.f, wC = 0.f;
    float st[16];
#pragma unroll
    for (int r = 0; r < 16; r++) st[r] = 0.f;
    long long rowbase = (long long)b * SEQ;
    for (int t = 0; t < SEQ; t++) {
        long long row = rowbase + t;
        float da = DAb[row * NH + h];
        float dtv = DTb[row * NH + h];
        float raw = XBC[row * XBCLD + h * HD + p];
        const float4* bq = (const float4*)(BCb + row * 128 + g * 16);
        const float4* cq = (const float4*)(BCb + row * 128 + 64 + g * 16);
        float4 b0 = bq[0], b1 = bq[1], b2 = bq[2], b3 = bq[3];
        float4 c0 = cq[0], c1 = cq[1], c2 = cq[2], c3 = cq[3];
        float cvv = cb + cw0 * wA + cw1 * wB + cw2 * wC + cw3 * raw;
        float xhv = cvv / (1.f + expf(-cvv));
        wA = wB; wB = wC; wC = raw;
        float xv = dtv * xhv;
        float part = 0.f;
        st[0]  = fmaf(da, st[0],  xv * b0.x); part = fmaf(st[0],  c0.x, part);
        st[1]  = fmaf(da, st[1],  xv * b0.y); part = fmaf(st[1],  c0.y, part);
        st[2]  = fmaf(da, st[2],  xv * b0.z); part = fmaf(st[2],  c0.z, part);
        st[3]  = fmaf(da, st[3],  xv * b0.w); part = fmaf(st[3],  c0.w, part);
        st[4]  = fmaf(da, st[4],  xv * b1.x); part = fmaf(st[4],  c1.x, part);
        st[5]  = fmaf(da, st[5],  xv * b1.y); part = fmaf(st[5],  c1.y, part);
        st[6]  = fmaf(da, st[6],  xv * b1.z); part = fmaf(st[6],  c1.z, part);
        st[7]  = fmaf(da, st[7],  xv * b1.w); part = fmaf(st[7],  c1.w, part);
        st[8]  = fmaf(da, st[8],  xv * b2.x); part = fmaf(st[8],  c2.x, part);
        st[9]  = fmaf(da, st[9],  xv * b2.y); part = fmaf(st[9],  c2.y, part);
        st[10] = fmaf(da, st[10], xv * b2.z); part = fmaf(st[10], c2.z, part);
        st[11] = fmaf(da, st[11], xv * b2.w); part = fmaf(st[11], c2.w, part);
        st[12] = fmaf(da, st[12], xv * b3.x); part = fmaf(st[12], c3.x, part);
        st[13] = fmaf(da, st[13], xv * b3.y); part = fmaf(st[13], c3.y, part);
        st[14] = fmaf(da, st[14], xv * b3.z); part = fmaf(st[14], c3.z, part);
        st[15] = fmaf(da, st[15], xv * b3.w); part = fmaf(st[15], c3.w, part);
        part += __shfl_xor(part, 16);
        part += __shfl_xor(part, 32);
        if (lane < HD)
            XBC[row * XBCLD + h * HD + p] = part + ds * xhv;
    }
}

// ---------------- fused z-GEMV + silu gate + RMSNorm -> bf16 G in place ----------------
__global__ __launch_bounds__(256) void zgate_kernel(
    const float* __restrict__ X, const float* __restrict__ Wip,
    float* __restrict__ XBC, const float* __restrict__ rms_w)
{
    __shared__ float xs[16][DMODEL];
    __shared__ float red[16][4];
    int row0 = blockIdx.x * 16;
    int tid = threadIdx.x;
#pragma unroll
    for (int r = 0; r < 16; r++)
        xs[r][tid] = X[(long long)(row0 + r) * DMODEL + tid];
    __syncthreads();
    float z0[16], z1[16];
#pragma unroll
    for (int r = 0; r < 16; r++) { z0[r] = 0.f; z1[r] = 0.f; }
    for (int k = 0; k < DMODEL; k++) {
        float w0 = Wip[(long long)k * DINPROJ + tid];
        float w1 = Wip[(long long)k * DINPROJ + 256 + tid];
#pragma unroll
        for (int r = 0; r < 16; r++) {
            float xv = xs[r][k];
            z0[r] = fmaf(xv, w0, z0[r]);
            z1[r] = fmaf(xv, w1, z1[r]);
        }
    }
    int wv = tid >> 6, lane = tid & 63;
    float g0[16], g1[16];
#pragma unroll
    for (int r = 0; r < 16; r++) {
        long long row = row0 + r;
        float y0 = XBC[row * XBCLD + tid];
        float y1 = XBC[row * XBCLD + 256 + tid];
        float zz0 = z0[r], zz1 = z1[r];
        float a0 = y0 * (zz0 / (1.f + expf(-zz0)));
        float a1 = y1 * (zz1 / (1.f + expf(-zz1)));
        g0[r] = a0; g1[r] = a1;
        float val = fmaf(a0, a0, a1 * a1);
#pragma unroll
        for (int m = 1; m < 64; m <<= 1) val += __shfl_xor(val, m);
        if (lane == 0) red[r][wv] = val;
    }
    __syncthreads();
#pragma unroll
    for (int r = 0; r < 16; r++) {
        long long row = row0 + r;
        float ss = red[r][0] + red[r][1] + red[r][2] + red[r][3];
        float sc = rsqrtf(ss * (1.f / 512.f) + 1e-5f);
        unsigned short* grow = (unsigned short*)&XBC[row * XBCLD];
        grow[tid]       = f2bf(g0[r] * sc * rms_w[tid]);
        grow[256 + tid] = f2bf(g1[r] * sc * rms_w[256 + tid]);
    }
}

// ---------------- LayerNorm(a+b)*g+be (f32,f32) ----------------
__global__ void lnadd_kernel(const float* __restrict__ A, const float* __restrict__ Bb,
                             const float* __restrict__ g, const float* __restrict__ be,
                             float* __restrict__ O)
{
    int row = blockIdx.x * 4 + (threadIdx.x >> 6);
    int lane = threadIdx.x & 63;
    long long base = (long long)row * DMODEL + lane * 4;
    float v[4]; float s1 = 0.f;
#pragma unroll
    for (int i = 0; i < 4; i++) { float a = A[base + i] + Bb[base + i]; v[i] = a; s1 += a; }
#pragma unroll
    for (int m = 1; m < 64; m <<= 1) s1 += __shfl_xor(s1, m);
    float mean = s1 * (1.f / 256.f);
    float s2 = 0.f;
#pragma unroll
    for (int i = 0; i < 4; i++) { float d = v[i] - mean; s2 = fmaf(d, d, s2); }
#pragma unroll
    for (int m = 1; m < 64; m <<= 1) s2 += __shfl_xor(s2, m);
    float r = rsqrtf(s2 * (1.f / 256.f) + 1e-12f);
#pragma unroll
    for (int i = 0; i < 4; i++)
        O[base + i] = (v[i] - mean) * r * g[lane * 4 + i] + be[lane * 4 + i];
}

// ---------------- LayerNorm(bf16 a + f32 b)*g+be -> f32 ----------------
__global__ void lnadd_bf_kernel(const unsigned short* __restrict__ A, const float* __restrict__ Bb,
                                const float* __restrict__ g, const float* __restrict__ be,
                                float* __restrict__ O)
{
    int row = blockIdx.x * 4 + (threadIdx.x >> 6);
    int lane = threadIdx.x & 63;
    long long base = (long long)row * DMODEL + lane * 4;
    float v[4]; float s1 = 0.f;
#pragma unroll
    for (int i = 0; i < 4; i++) { float a = bf2f(A[base + i]) + Bb[base + i]; v[i] = a; s1 += a; }
#pragma unroll
    for (int m = 1; m < 64; m <<= 1) s1 += __shfl_xor(s1, m);
    float mean = s1 * (1.f / 256.f);
    float s2 = 0.f;
#pragma unroll
    for (int i = 0; i < 4; i++) { float d = v[i] - mean; s2 = fmaf(d, d, s2); }
#pragma unroll
    for (int m = 1; m < 64; m <<= 1) s2 += __shfl_xor(s2, m);
    float r = rsqrtf(s2 * (1.f / 256.f) + 1e-12f);
#pragma unroll
    for (int i = 0; i < 4; i++)
        O[base + i] = (v[i] - mean) * r * g[lane * 4 + i] + be[lane * 4 + i];
}

// ---------------- combine: H1 = alpha*H1 + beta*LN(XI + X) ----------------
__global__ void combine_kernel(const float* __restrict__ XI, const float* __restrict__ X,
                               float* __restrict__ H1,
                               const float* __restrict__ fg, const float* __restrict__ fb,
                               const float* __restrict__ al, const float* __restrict__ bt)
{
    int row = blockIdx.x * 4 + (threadIdx.x >> 6);
    int lane = threadIdx.x & 63;
    long long base = (long long)row * DMODEL + lane * 4;
    float v[4]; float s1 = 0.f;
#pragma unroll
    for (int i = 0; i < 4; i++) { float a = XI[base + i] + X[base + i]; v[i] = a; s1 += a; }
#pragma unroll
    for (int m = 1; m < 64; m <<= 1) s1 += __shfl_xor(s1, m);
    float mean = s1 * (1.f / 256.f);
    float s2 = 0.f;
#pragma unroll
    for (int i = 0; i < 4; i++) { float d = v[i] - mean; s2 = fmaf(d, d, s2); }
#pragma unroll
    for (int m = 1; m < 64; m <<= 1) s2 += __shfl_xor(s2, m);
    float r = rsqrtf(s2 * (1.f / 256.f) + 1e-12f);
#pragma unroll
    for (int i = 0; i < 4; i++) {
        float h2 = (v[i] - mean) * r * fg[lane * 4 + i] + fb[lane * 4 + i];
        H1[base + i] = al[lane * 4 + i] * H1[base + i] + bt[lane * 4 + i] * h2;
    }
}

// ---------------- pointwise spectral filter on XFT[b][d][j] bf16 (ld 208) ----------------
__global__ void filt_kernel(unsigned short* __restrict__ XF, const float* __restrict__ W)
{
    long long idx = (long long)blockIdx.x * 256 + threadIdx.x;
    if (idx >= (long long)BATCHN * DMODEL * NF) return;
    int f = (int)(idx % NF);
    int d = (int)((idx / NF) % DMODEL);
    int b = (int)(idx / ((long long)NF * DMODEL));
    long long base = ((long long)b * DMODEL + d) * NJP;
    float re = bf2f(XF[base + f]);
    float im = bf2f(XF[base + 101 + f]);
    float wr = W[((long long)f * DMODEL + d) * 2];
    float wi = W[((long long)f * DMODEL + d) * 2 + 1];
    XF[base + f]       = f2bf(re * wr - im * wi);
    XF[base + 101 + f] = f2bf(re * wi + im * wr);
}

extern "C" void kernel_launch(void* const* d_in, const int* in_sizes, int n_in,
                              void* d_out, int out_size, void* d_ws, size_t ws_size,
                              hipStream_t stream)
{
    const float* x          = (const float*)d_in[0];
    const float* in_proj_w  = (const float*)d_in[1];
    const float* conv_w     = (const float*)d_in[2];
    const float* conv_b     = (const float*)d_in[3];
    const float* dt_bias    = (const float*)d_in[4];
    const float* A_log      = (const float*)d_in[5];
    const float* D_skip     = (const float*)d_in[6];
    const float* rms_w      = (const float*)d_in[7];
    const float* out_proj_w = (const float*)d_in[8];
    const float* ln_g       = (const float*)d_in[9];
    const float* ln_b       = (const float*)d_in[10];
    const float* filt_w     = (const float*)d_in[11];
    const float* filt_ln_g  = (const float*)d_in[12];
    const float* filt_ln_b  = (const float*)d_in[13];
    const float* alpha      = (const float*)d_in[14];
    const float* beta       = (const float*)d_in[15];
    const float* ffn_w1     = (const float*)d_in[16];
    const float* ffn_b1     = (const float*)d_in[17];
    const float* ffn_w2     = (const float*)d_in[18];
    const float* ffn_b2     = (const float*)d_in[19];
    const float* ffn_ln_g   = (const float*)d_in[20];
    const float* ffn_ln_b   = (const float*)d_in[21];
    float* out = (float*)d_out;
    float* ws = (float*)d_ws;

    // ---- workspace layout (float offsets), peak ~232 MB ----
    // [81920 .. XBASE): packed bf16 weights
    unsigned short* WP   = (unsigned short*)(ws + 81920);
    unsigned short* ipwT = WP;                  // 672*256
    unsigned short* opwT = ipwT + 672 * 256;    // 256*512
    unsigned short* w1T  = opwT + 256 * 512;    // 1024*256
    unsigned short* w2T  = w1T + 1024 * 256;    // 256*1024
    unsigned short* EFbf = w2T + 256 * 1024;    // 202*200
    unsigned short* EIbf = EFbf + NJ * SEQ;     // 200*208
    float* XBC = ws + XBASE;                    // BL*672 f32
    float* BCb = XBC + (long long)BL * XBCLD;   // BL*128
    float* DTb = BCb + (long long)BL * 128;     // BL*32
    float* DAb = DTb + (long long)BL * NH;      // BL*32
    float* MO  = DAb + (long long)BL * NH;      // BL*256 (h1/H)
    // region reuse:
    unsigned short* Gbf = (unsigned short*)XBC;             // in-place bf16 G, ld 1344
    unsigned short* xTbf = (unsigned short*)BCb;            // 256*256*200 bf16 (post-scan)
    unsigned short* XFT = (unsigned short*)XBC;             // 256*256*208 bf16 (post-out_proj)
    float* XI  = XBC + 7000000;                              // BL*256 f32
    unsigned short* HID = (unsigned short*)XBC;              // BL*1024 bf16 (post-combine)
    unsigned short* FFO = (unsigned short*)(XBC + 26500000); // BL*256 bf16

    // 1. DFT matrices (bf16) + weight packs
    init_dft_kernel<<<dim3((NJ * SEQ + SEQ * NJP + 255) / 256), dim3(256), 0, stream>>>(EFbf, EIbf);
    pack_wT_kernel<<<dim3((672 * 256 + 255) / 256), dim3(256), 0, stream>>>(in_proj_w, ipwT, DINPROJ, 512, 672, 256);
    pack_wT_kernel<<<dim3((256 * 512 + 255) / 256), dim3(256), 0, stream>>>(out_proj_w, opwT, 256, 0, 256, 512);
    pack_wT_kernel<<<dim3((1024 * 256 + 255) / 256), dim3(256), 0, stream>>>(ffn_w1, w1T, 1024, 0, 1024, 256);
    pack_wT_kernel<<<dim3((256 * 1024 + 255) / 256), dim3(256), 0, stream>>>(ffn_w2, w2T, 256, 0, 256, 1024);

    // 2. in_proj (xBC+dt cols): [BL,256] @ ipwT^T -> XBC f32 (ld 672)
    mgemm_kernel<0,0,0><<<dim3(6, BL / 128, 1), dim3(256), 0, stream>>>(
        x, ipwT, XBC, nullptr, BL, 672, 256, 256, 256, 672, 0, 0, 0);

    // 3. conv+silu B/C; dt -> DT/DA
    convbc_kernel<<<dim3(BL), dim3(192), 0, stream>>>(XBC, conv_w, conv_b, dt_bias, A_log,
                                                      BCb, DTb, DAb);

    // 4. scan (fused x-conv+silu+D_skip), y in place (XBC cols 0..511 f32)
    scan3_kernel<<<dim3(BATCHN * NH / 4), dim3(256), 0, stream>>>(DTb, DAb, XBC, BCb, D_skip,
                                                                  conv_w, conv_b);

    // 4.5 x transpose -> xTbf (BCb region dead after scan)
    xT_kernel<<<dim3(7, 8, BATCHN), dim3(256), 0, stream>>>(x, xTbf);

    // 5. z-GEMV + gate + RMSNorm -> Gbf bf16 in place
    zgate_kernel<<<dim3(BL / 16), dim3(256), 0, stream>>>(x, in_proj_w, XBC, rms_w);

    // 6. out_proj: Gbf[BL,512](ld 1344) @ opwT^T -> MO f32
    mgemm_kernel<0,1,0><<<dim3(2, BL / 128, 1), dim3(256), 0, stream>>>(
        Gbf, opwT, MO, nullptr, BL, 256, 512, 1344, 512, 256, 0, 0, 0);

    // 7. h1 = LN(MO + x) in place
    lnadd_kernel<<<dim3(BL / 4), dim3(256), 0, stream>>>(MO, x, ln_g, ln_b, MO);

    // 8. FFT fwd (transposed): XFT[b] [256,202] = xTbf[b][256,200] @ EFbf^T, bf16 out (ld 208)
    mgemm_kernel<0,1,1><<<dim3(2, 2, BATCHN), dim3(256), 0, stream>>>(
        xTbf, EFbf, XFT, nullptr, 256, NJ, SEQ, SEQ, SEQ, NJP,
        (long long)DMODEL * SEQ, 0, (long long)DMODEL * NJP);

    // 9. spectral filter in place on XFT
    filt_kernel<<<dim3((BATCHN * DMODEL * NF + 255) / 256), dim3(256), 0, stream>>>(XFT, filt_w);

    // 10. FFT inv: XI[b] [200,256] = EIbf[200,202] @ XFT[b]^T, f32 out
    mgemm_kernel<0,1,0><<<dim3(2, 2, BATCHN), dim3(256), 0, stream>>>(
        EIbf, XFT, XI, nullptr, SEQ, DMODEL, NJ, NJP, NJP, DMODEL,
        0, (long long)DMODEL * NJP, (long long)SEQ * DMODEL);

    // 11. combine: MO = alpha*h1 + beta*LN(XI + x)
    combine_kernel<<<dim3(BL / 4), dim3(256), 0, stream>>>(XI, x, MO, filt_ln_g, filt_ln_b,
                                                           alpha, beta);

    // 12. FFN1: MO[BL,256] @ w1T^T + b1, GELU -> HID bf16
    mgemm_kernel<1,0,1><<<dim3(8, BL / 128, 1), dim3(256), 0, stream>>>(
        MO, w1T, HID, ffn_b1, BL, 1024, 256, 256, 256, 1024, 0, 0, 0);

    // 13. FFN2: HID[BL,1024] @ w2T^T + b2 -> FFO bf16
    mgemm_kernel<0,1,1><<<dim3(2, BL / 128, 1), dim3(256), 0, stream>>>(
        HID, w2T, FFO, ffn_b2, BL, 256, 1024, 1024, 1024, 256, 0, 0, 0);

    // 14. out = LN(FFO + MO)
    lnadd_bf_kernel<<<dim3(BL / 4), dim3(256), 0, stream>>>(FFO, MO, ffn_ln_g, ffn_ln_b, out);
}

// Round 5
// 1307.340 us; speedup vs baseline: 3.5728x; 1.0837x over previous
//
#include <hip/hip_runtime.h>
#include <math.h>

#define BATCHN 256
#define SEQ 200
#define DMODEL 256
#define DINNER 512
#define NH 32
#define HD 16
#define DSTATE 64
#define DINPROJ 1184
#define XBCLD 672
#define BL (BATCHN*SEQ)   // 51200
#define NF 101
#define NJ 202
#define NJP 208           // padded (16B-aligned bf16 rows)
#define XBASE 655360      // float offset of XBC region in ws

typedef __attribute__((ext_vector_type(8))) short bf16x8;
typedef __attribute__((ext_vector_type(4))) float f32x4;

__device__ inline unsigned short f2bf(float f) {
    union { float f; unsigned u; } v; v.f = f;
    unsigned r = v.u + 0x7FFFu + ((v.u >> 16) & 1u);
    return (unsigned short)(r >> 16);
}
__device__ inline float bf2f(unsigned short h) {
    union { unsigned u; float f; } v; v.u = ((unsigned)h) << 16;
    return v.f;
}

// ---------------- DFT matrices (bf16 direct) ----------------
__global__ void init_dft_kernel(unsigned short* __restrict__ EF, unsigned short* __restrict__ EI)
{
    const float ang = 6.28318530717958647692f / 200.0f;
    int idx = blockIdx.x * 256 + threadIdx.x;
    if (idx < NJ * SEQ) {
        int f = idx / SEQ, t = idx - f * SEQ;
        float v;
        if (f <= 100) { int ph = (f * t) % 200; v = cosf(ang * (float)ph); }
        else { int ff = f - 101; int ph = (ff * t) % 200; v = -sinf(ang * (float)ph); }
        EF[idx] = f2bf(v);
    } else if (idx < NJ * SEQ + SEQ * NJP) {
        int j2 = idx - NJ * SEQ;
        int t = j2 / NJP, j = j2 - t * NJP;
        float v;
        if (j == 0) v = 1.0f / 200.0f;
        else if (j == 100) v = ((t & 1) ? -1.0f : 1.0f) / 200.0f;
        else if (j < 100) { int ph = (j * t) % 200; v = 2.0f * cosf(ang * (float)ph) / 200.0f; }
        else if (j >= 202 || j == 101 || j == 201) v = 0.0f;
        else { int f = j - 101; int ph = (f * t) % 200; v = -2.0f * sinf(ang * (float)ph) / 200.0f; }
        EI[j2] = f2bf(v);
    }
}

// ---------------- weight pack: dst[n][k] = bf16(src[k][coloff+n]) ----------------
__global__ void pack_wT_kernel(const float* __restrict__ src, unsigned short* __restrict__ dst,
                               int srcld, int coloff, int N, int K)
{
    int idx = blockIdx.x * 256 + threadIdx.x;
    if (idx >= N * K) return;
    int n = idx / K, k = idx - n * K;
    dst[idx] = f2bf(src[(long long)k * srcld + coloff + n]);
}

// ---------------- x transpose: xT[b][d][t] = bf16(x[b][t][d]) ----------------
__global__ void xT_kernel(const float* __restrict__ X, unsigned short* __restrict__ XT)
{
    __shared__ float tile[32][33];
    int b = blockIdx.z, t0 = blockIdx.x * 32, d0 = blockIdx.y * 32;
    int tx = threadIdx.x & 31, ty = threadIdx.x >> 5;  // ty 0..7
    const float* xb = X + (long long)b * SEQ * DMODEL;
#pragma unroll
    for (int i = 0; i < 4; i++) {
        int t = t0 + ty + i * 8;
        tile[ty + i * 8][tx] = (t < SEQ) ? xb[(long long)t * DMODEL + d0 + tx] : 0.f;
    }
    __syncthreads();
    unsigned short* xtb = XT + (long long)b * DMODEL * SEQ;
#pragma unroll
    for (int i = 0; i < 4; i++) {
        int d = d0 + ty + i * 8;
        int t = t0 + tx;
        if (t < SEQ) xtb[(long long)d * SEQ + t] = f2bf(tile[tx][ty + i * 8]);
    }
}

// ---------------- bf16 MFMA GEMM ----------------
template<int ACT, int ABF, int CBF>
__global__ __launch_bounds__(256) void mgemm_kernel(
    const void* __restrict__ Ap, const unsigned short* __restrict__ BTp, void* __restrict__ Cp,
    const float* __restrict__ bias,
    int M, int N, int K, int lda, int ldbt, int ldc,
    long long sA, long long sBT, long long sC)
{
    __shared__ unsigned short As[128 * 40];
    __shared__ unsigned short Bs[128 * 40];
    const float* Af = (const float*)Ap + (ABF ? 0 : (long long)blockIdx.z * sA);
    const unsigned short* Ab = (const unsigned short*)Ap + (ABF ? (long long)blockIdx.z * sA : 0);
    const unsigned short* Bt = BTp + (long long)blockIdx.z * sBT;
    float* Cf = (float*)Cp + (CBF ? 0 : (long long)blockIdx.z * sC);
    unsigned short* Cb = (unsigned short*)Cp + (CBF ? (long long)blockIdx.z * sC : 0);

    int m0 = blockIdx.y * 128, n0 = blockIdx.x * 128;
    int tid = threadIdx.x;
    int srow = tid >> 1, skb = (tid & 1) * 16;
    int w = tid >> 6, l = tid & 63;
    int wr = w >> 1, wc = w & 1;
    int fr = l & 15, fk = l >> 4;

    f32x4 acc[4][4] = {};

    for (int k0 = 0; k0 < K; k0 += 32) {
        bool kedge = (k0 + 32 > K);
        {
            int gm = m0 + srow;
            unsigned short* dst = &As[srow * 40 + skb];
            if (gm < M && !kedge) {
                if (ABF) {
                    const unsigned short* src = Ab + (long long)gm * lda + k0 + skb;
                    ((uint4*)dst)[0] = ((const uint4*)src)[0];
                    ((uint4*)dst)[1] = ((const uint4*)src)[1];
                } else {
                    const float* src = Af + (long long)gm * lda + k0 + skb;
                    float4 f0 = ((const float4*)src)[0];
                    float4 f1 = ((const float4*)src)[1];
                    float4 f2 = ((const float4*)src)[2];
                    float4 f3 = ((const float4*)src)[3];
                    uint4 q0, q1;
                    q0.x = (unsigned)f2bf(f0.x) | ((unsigned)f2bf(f0.y) << 16);
                    q0.y = (unsigned)f2bf(f0.z) | ((unsigned)f2bf(f0.w) << 16);
                    q0.z = (unsigned)f2bf(f1.x) | ((unsigned)f2bf(f1.y) << 16);
                    q0.w = (unsigned)f2bf(f1.z) | ((unsigned)f2bf(f1.w) << 16);
                    q1.x = (unsigned)f2bf(f2.x) | ((unsigned)f2bf(f2.y) << 16);
                    q1.y = (unsigned)f2bf(f2.z) | ((unsigned)f2bf(f2.w) << 16);
                    q1.z = (unsigned)f2bf(f3.x) | ((unsigned)f2bf(f3.y) << 16);
                    q1.w = (unsigned)f2bf(f3.z) | ((unsigned)f2bf(f3.w) << 16);
                    ((uint4*)dst)[0] = q0;
                    ((uint4*)dst)[1] = q1;
                }
            } else {
#pragma unroll
                for (int i = 0; i < 16; i++) {
                    int gk = k0 + skb + i;
                    unsigned short v = 0;
                    if (gm < M && gk < K)
                        v = ABF ? Ab[(long long)gm * lda + gk]
                                : f2bf(Af[(long long)gm * lda + gk]);
                    dst[i] = v;
                }
            }
        }
        {
            int gn = n0 + srow;
            unsigned short* dst = &Bs[srow * 40 + skb];
            if (gn < N && !kedge) {
                const unsigned short* src = Bt + (long long)gn * ldbt + k0 + skb;
                ((uint4*)dst)[0] = ((const uint4*)src)[0];
                ((uint4*)dst)[1] = ((const uint4*)src)[1];
            } else {
#pragma unroll
                for (int i = 0; i < 16; i++) {
                    int gk = k0 + skb + i;
                    dst[i] = (gn < N && gk < K) ? Bt[(long long)gn * ldbt + gk] : (unsigned short)0;
                }
            }
        }
        __syncthreads();
        bf16x8 a[4], b[4];
#pragma unroll
        for (int i = 0; i < 4; i++) {
            a[i] = *(const bf16x8*)&As[(wr * 64 + i * 16 + fr) * 40 + fk * 8];
            b[i] = *(const bf16x8*)&Bs[(wc * 64 + i * 16 + fr) * 40 + fk * 8];
        }
#pragma unroll
        for (int i = 0; i < 4; i++)
#pragma unroll
            for (int j = 0; j < 4; j++)
                acc[i][j] = __builtin_amdgcn_mfma_f32_16x16x32_bf16(a[i], b[j], acc[i][j], 0, 0, 0);
        __syncthreads();
    }

#pragma unroll
    for (int i = 0; i < 4; i++) {
        int gr0 = m0 + wr * 64 + i * 16 + fk * 4;
#pragma unroll
        for (int j = 0; j < 4; j++) {
            int gc = n0 + wc * 64 + j * 16 + fr;
            if (gc >= N) continue;
            float bv = bias ? bias[gc] : 0.f;
#pragma unroll
            for (int r = 0; r < 4; r++) {
                int gr = gr0 + r;
                if (gr >= M) continue;
                float v = acc[i][j][r] + bv;
                if (ACT == 1) v = 0.5f * v * (1.f + erff(v * 0.70710678118654752f));
                long long ci = (long long)gr * ldc + gc;
                if (CBF) Cb[ci] = f2bf(v);
                else Cf[ci] = v;
            }
        }
    }
}

// ---------------- conv+silu for B/C channels, dt/dA ----------------
__global__ void convbc_kernel(const float* __restrict__ XBC, const float* __restrict__ conv_w,
                              const float* __restrict__ conv_b, const float* __restrict__ dt_bias,
                              const float* __restrict__ A_log,
                              float* __restrict__ BCb, float* __restrict__ DTb, float* __restrict__ DAb)
{
    int row = blockIdx.x;
    int b = row / SEQ, l = row - b * SEQ;
    int tid = threadIdx.x;
    if (tid < 128) {
        int ch = 512 + tid;
        float acc = conv_b[ch];
#pragma unroll
        for (int k = 0; k < 4; k++) {
            int lt = l + k - 3;
            if (lt >= 0)
                acc = fmaf(conv_w[ch * 4 + k], XBC[(long long)(b * SEQ + lt) * XBCLD + ch], acc);
        }
        BCb[(long long)row * 128 + tid] = acc * __builtin_amdgcn_rcpf(1.f + __expf(-acc));
    } else if (tid < 160) {
        int h = tid - 128;
        float draw = XBC[(long long)row * XBCLD + 640 + h] + dt_bias[h];
        float dtv = (draw > 20.f) ? draw : log1pf(__expf(draw));
        DTb[(long long)row * NH + h] = dtv;
        DAb[(long long)row * NH + h] = __expf(-__expf(A_log[h]) * dtv);
    }
}

// ---------------- selective scan v4: prefetch + LDS dt/da + fast silu + tree reduce ----------------
struct PF {
    float4 b0, b1, b2, b3, c0, c1, c2, c3;
    float raw;
};

__device__ __forceinline__ void pfload(PF& P, const float* __restrict__ bp,
                                       const float* __restrict__ xp, int t)
{
    const float4* bq = (const float4*)(bp + (long long)t * 128);
    P.b0 = bq[0]; P.b1 = bq[1]; P.b2 = bq[2]; P.b3 = bq[3];
    const float4* cq = (const float4*)(bp + (long long)t * 128 + 64);
    P.c0 = cq[0]; P.c1 = cq[1]; P.c2 = cq[2]; P.c3 = cq[3];
    P.raw = xp[(long long)t * XBCLD];
}

__device__ __forceinline__ void scan_step(
    const PF& P, float* st, float& wA, float& wB, float& wC,
    float dtv, float da,
    float cw0, float cw1, float cw2, float cw3, float cb, float ds,
    int lane, float* __restrict__ yaddr)
{
    float cvv = cb + cw0 * wA + cw1 * wB + cw2 * wC + cw3 * P.raw;
    float xhv = cvv * __builtin_amdgcn_rcpf(1.f + __expf(-cvv));
    wA = wB; wB = wC; wC = P.raw;
    float xv = dtv * xhv;
    float p0, p1, p2, p3;
    st[0]  = fmaf(da, st[0],  xv * P.b0.x); p0 = st[0]  * P.c0.x;
    st[1]  = fmaf(da, st[1],  xv * P.b0.y); p1 = st[1]  * P.c0.y;
    st[2]  = fmaf(da, st[2],  xv * P.b0.z); p2 = st[2]  * P.c0.z;
    st[3]  = fmaf(da, st[3],  xv * P.b0.w); p3 = st[3]  * P.c0.w;
    st[4]  = fmaf(da, st[4],  xv * P.b1.x); p0 = fmaf(st[4],  P.c1.x, p0);
    st[5]  = fmaf(da, st[5],  xv * P.b1.y); p1 = fmaf(st[5],  P.c1.y, p1);
    st[6]  = fmaf(da, st[6],  xv * P.b1.z); p2 = fmaf(st[6],  P.c1.z, p2);
    st[7]  = fmaf(da, st[7],  xv * P.b1.w); p3 = fmaf(st[7],  P.c1.w, p3);
    st[8]  = fmaf(da, st[8],  xv * P.b2.x); p0 = fmaf(st[8],  P.c2.x, p0);
    st[9]  = fmaf(da, st[9],  xv * P.b2.y); p1 = fmaf(st[9],  P.c2.y, p1);
    st[10] = fmaf(da, st[10], xv * P.b2.z); p2 = fmaf(st[10], P.c2.z, p2);
    st[11] = fmaf(da, st[11], xv * P.b2.w); p3 = fmaf(st[11], P.c2.w, p3);
    st[12] = fmaf(da, st[12], xv * P.b3.x); p0 = fmaf(st[12], P.c3.x, p0);
    st[13] = fmaf(da, st[13], xv * P.b3.y); p1 = fmaf(st[13], P.c3.y, p1);
    st[14] = fmaf(da, st[14], xv * P.b3.z); p2 = fmaf(st[14], P.c3.z, p2);
    st[15] = fmaf(da, st[15], xv * P.b3.w); p3 = fmaf(st[15], P.c3.w, p3);
    float part = (p0 + p1) + (p2 + p3);
    part += __shfl_xor(part, 16);
    part += __shfl_xor(part, 32);
    if (lane < HD) *yaddr = part + ds * xhv;
}

__global__ __launch_bounds__(256) void scan4_kernel(
    const float* __restrict__ DTb, const float* __restrict__ DAb,
    float* __restrict__ XBC, const float* __restrict__ BCb,
    const float* __restrict__ Dsk,
    const float* __restrict__ conv_w, const float* __restrict__ conv_b)
{
    __shared__ float sdt[4][SEQ];
    __shared__ float sda[4][SEQ];
    int wv = threadIdx.x >> 6, lane = threadIdx.x & 63;
    int wid = blockIdx.x * 4 + wv;
    int b = wid >> 5, h = wid & 31;
    for (int t = lane; t < SEQ; t += 64) {
        long long row = (long long)b * SEQ + t;
        sdt[wv][t] = DTb[row * NH + h];
        sda[wv][t] = DAb[row * NH + h];
    }
    __syncthreads();
    int p = lane & 15, g = lane >> 4;
    int ch = h * HD + p;
    float cw0 = conv_w[ch * 4 + 0], cw1 = conv_w[ch * 4 + 1];
    float cw2 = conv_w[ch * 4 + 2], cw3 = conv_w[ch * 4 + 3];
    float cb = conv_b[ch];
    float ds = Dsk[h];
    const float* bp = BCb + (long long)b * SEQ * 128 + g * 16;
    const float* xp = XBC + (long long)b * SEQ * XBCLD + h * HD + p;
    float* yp = XBC + (long long)b * SEQ * XBCLD + h * HD + p;
    float st[16];
#pragma unroll
    for (int r = 0; r < 16; r++) st[r] = 0.f;
    float wA = 0.f, wB = 0.f, wC = 0.f;

    PF A0, A1;
    pfload(A0, bp, xp, 0);
    for (int t = 0; t < SEQ; t += 2) {
        pfload(A1, bp, xp, t + 1);
        scan_step(A0, st, wA, wB, wC, sdt[wv][t], sda[wv][t],
                  cw0, cw1, cw2, cw3, cb, ds, lane, yp + (long long)t * XBCLD);
        int t2 = (t + 2 < SEQ) ? (t + 2) : (SEQ - 1);
        pfload(A0, bp, xp, t2);
        scan_step(A1, st, wA, wB, wC, sdt[wv][t + 1], sda[wv][t + 1],
                  cw0, cw1, cw2, cw3, cb, ds, lane, yp + (long long)(t + 1) * XBCLD);
    }
}

// ---------------- fused z-GEMV + silu gate + RMSNorm -> bf16 G in place ----------------
__global__ __launch_bounds__(256) void zgate_kernel(
    const float* __restrict__ X, const float* __restrict__ Wip,
    float* __restrict__ XBC, const float* __restrict__ rms_w)
{
    __shared__ float xs[16][DMODEL];
    __shared__ float red[16][4];
    int row0 = blockIdx.x * 16;
    int tid = threadIdx.x;
#pragma unroll
    for (int r = 0; r < 16; r++)
        xs[r][tid] = X[(long long)(row0 + r) * DMODEL + tid];
    __syncthreads();
    float z0[16], z1[16];
#pragma unroll
    for (int r = 0; r < 16; r++) { z0[r] = 0.f; z1[r] = 0.f; }
    for (int k = 0; k < DMODEL; k++) {
        float w0 = Wip[(long long)k * DINPROJ + tid];
        float w1 = Wip[(long long)k * DINPROJ + 256 + tid];
#pragma unroll
        for (int r = 0; r < 16; r++) {
            float xv = xs[r][k];
            z0[r] = fmaf(xv, w0, z0[r]);
            z1[r] = fmaf(xv, w1, z1[r]);
        }
    }
    int wv = tid >> 6, lane = tid & 63;
    float g0[16], g1[16];
#pragma unroll
    for (int r = 0; r < 16; r++) {
        long long row = row0 + r;
        float y0 = XBC[row * XBCLD + tid];
        float y1 = XBC[row * XBCLD + 256 + tid];
        float zz0 = z0[r], zz1 = z1[r];
        float a0 = y0 * (zz0 * __builtin_amdgcn_rcpf(1.f + __expf(-zz0)));
        float a1 = y1 * (zz1 * __builtin_amdgcn_rcpf(1.f + __expf(-zz1)));
        g0[r] = a0; g1[r] = a1;
        float val = fmaf(a0, a0, a1 * a1);
#pragma unroll
        for (int m = 1; m < 64; m <<= 1) val += __shfl_xor(val, m);
        if (lane == 0) red[r][wv] = val;
    }
    __syncthreads();
#pragma unroll
    for (int r = 0; r < 16; r++) {
        long long row = row0 + r;
        float ss = red[r][0] + red[r][1] + red[r][2] + red[r][3];
        float sc = rsqrtf(ss * (1.f / 512.f) + 1e-5f);
        unsigned short* grow = (unsigned short*)&XBC[row * XBCLD];
        grow[tid]       = f2bf(g0[r] * sc * rms_w[tid]);
        grow[256 + tid] = f2bf(g1[r] * sc * rms_w[256 + tid]);
    }
}

// ---------------- LayerNorm(a+b)*g+be (f32,f32) ----------------
__global__ void lnadd_kernel(const float* __restrict__ A, const float* __restrict__ Bb,
                             const float* __restrict__ g, const float* __restrict__ be,
                             float* __restrict__ O)
{
    int row = blockIdx.x * 4 + (threadIdx.x >> 6);
    int lane = threadIdx.x & 63;
    long long base = (long long)row * DMODEL + lane * 4;
    float v[4]; float s1 = 0.f;
#pragma unroll
    for (int i = 0; i < 4; i++) { float a = A[base + i] + Bb[base + i]; v[i] = a; s1 += a; }
#pragma unroll
    for (int m = 1; m < 64; m <<= 1) s1 += __shfl_xor(s1, m);
    float mean = s1 * (1.f / 256.f);
    float s2 = 0.f;
#pragma unroll
    for (int i = 0; i < 4; i++) { float d = v[i] - mean; s2 = fmaf(d, d, s2); }
#pragma unroll
    for (int m = 1; m < 64; m <<= 1) s2 += __shfl_xor(s2, m);
    float r = rsqrtf(s2 * (1.f / 256.f) + 1e-12f);
#pragma unroll
    for (int i = 0; i < 4; i++)
        O[base + i] = (v[i] - mean) * r * g[lane * 4 + i] + be[lane * 4 + i];
}

// ---------------- LayerNorm(bf16 a + f32 b)*g+be -> f32 ----------------
__global__ void lnadd_bf_kernel(const unsigned short* __restrict__ A, const float* __restrict__ Bb,
                                const float* __restrict__ g, const float* __restrict__ be,
                                float* __restrict__ O)
{
    int row = blockIdx.x * 4 + (threadIdx.x >> 6);
    int lane = threadIdx.x & 63;
    long long base = (long long)row * DMODEL + lane * 4;
    float v[4]; float s1 = 0.f;
#pragma unroll
    for (int i = 0; i < 4; i++) { float a = bf2f(A[base + i]) + Bb[base + i]; v[i] = a; s1 += a; }
#pragma unroll
    for (int m = 1; m < 64; m <<= 1) s1 += __shfl_xor(s1, m);
    float mean = s1 * (1.f / 256.f);
    float s2 = 0.f;
#pragma unroll
    for (int i = 0; i < 4; i++) { float d = v[i] - mean; s2 = fmaf(d, d, s2); }
#pragma unroll
    for (int m = 1; m < 64; m <<= 1) s2 += __shfl_xor(s2, m);
    float r = rsqrtf(s2 * (1.f / 256.f) + 1e-12f);
#pragma unroll
    for (int i = 0; i < 4; i++)
        O[base + i] = (v[i] - mean) * r * g[lane * 4 + i] + be[lane * 4 + i];
}

// ---------------- combine: H1 = alpha*H1 + beta*LN(XI + X) ----------------
__global__ void combine_kernel(const float* __restrict__ XI, const float* __restrict__ X,
                               float* __restrict__ H1,
                               const float* __restrict__ fg, const float* __restrict__ fb,
                               const float* __restrict__ al, const float* __restrict__ bt)
{
    int row = blockIdx.x * 4 + (threadIdx.x >> 6);
    int lane = threadIdx.x & 63;
    long long base = (long long)row * DMODEL + lane * 4;
    float v[4]; float s1 = 0.f;
#pragma unroll
    for (int i = 0; i < 4; i++) { float a = XI[base + i] + X[base + i]; v[i] = a; s1 += a; }
#pragma unroll
    for (int m = 1; m < 64; m <<= 1) s1 += __shfl_xor(s1, m);
    float mean = s1 * (1.f / 256.f);
    float s2 = 0.f;
#pragma unroll
    for (int i = 0; i < 4; i++) { float d = v[i] - mean; s2 = fmaf(d, d, s2); }
#pragma unroll
    for (int m = 1; m < 64; m <<= 1) s2 += __shfl_xor(s2, m);
    float r = rsqrtf(s2 * (1.f / 256.f) + 1e-12f);
#pragma unroll
    for (int i = 0; i < 4; i++) {
        float h2 = (v[i] - mean) * r * fg[lane * 4 + i] + fb[lane * 4 + i];
        H1[base + i] = al[lane * 4 + i] * H1[base + i] + bt[lane * 4 + i] * h2;
    }
}

// ---------------- pointwise spectral filter on XFT[b][d][j] bf16 (ld 208) ----------------
__global__ void filt_kernel(unsigned short* __restrict__ XF, const float* __restrict__ W)
{
    long long idx = (long long)blockIdx.x * 256 + threadIdx.x;
    if (idx >= (long long)BATCHN * DMODEL * NF) return;
    int f = (int)(idx % NF);
    int d = (int)((idx / NF) % DMODEL);
    int b = (int)(idx / ((long long)NF * DMODEL));
    long long base = ((long long)b * DMODEL + d) * NJP;
    float re = bf2f(XF[base + f]);
    float im = bf2f(XF[base + 101 + f]);
    float wr = W[((long long)f * DMODEL + d) * 2];
    float wi = W[((long long)f * DMODEL + d) * 2 + 1];
    XF[base + f]       = f2bf(re * wr - im * wi);
    XF[base + 101 + f] = f2bf(re * wi + im * wr);
}

extern "C" void kernel_launch(void* const* d_in, const int* in_sizes, int n_in,
                              void* d_out, int out_size, void* d_ws, size_t ws_size,
                              hipStream_t stream)
{
    const float* x          = (const float*)d_in[0];
    const float* in_proj_w  = (const float*)d_in[1];
    const float* conv_w     = (const float*)d_in[2];
    const float* conv_b     = (const float*)d_in[3];
    const float* dt_bias    = (const float*)d_in[4];
    const float* A_log      = (const float*)d_in[5];
    const float* D_skip     = (const float*)d_in[6];
    const float* rms_w      = (const float*)d_in[7];
    const float* out_proj_w = (const float*)d_in[8];
    const float* ln_g       = (const float*)d_in[9];
    const float* ln_b       = (const float*)d_in[10];
    const float* filt_w     = (const float*)d_in[11];
    const float* filt_ln_g  = (const float*)d_in[12];
    const float* filt_ln_b  = (const float*)d_in[13];
    const float* alpha      = (const float*)d_in[14];
    const float* beta       = (const float*)d_in[15];
    const float* ffn_w1     = (const float*)d_in[16];
    const float* ffn_b1     = (const float*)d_in[17];
    const float* ffn_w2     = (const float*)d_in[18];
    const float* ffn_b2     = (const float*)d_in[19];
    const float* ffn_ln_g   = (const float*)d_in[20];
    const float* ffn_ln_b   = (const float*)d_in[21];
    float* out = (float*)d_out;
    float* ws = (float*)d_ws;

    unsigned short* WP   = (unsigned short*)(ws + 81920);
    unsigned short* ipwT = WP;                  // 672*256
    unsigned short* opwT = ipwT + 672 * 256;    // 256*512
    unsigned short* w1T  = opwT + 256 * 512;    // 1024*256
    unsigned short* w2T  = w1T + 1024 * 256;    // 256*1024
    unsigned short* EFbf = w2T + 256 * 1024;    // 202*200
    unsigned short* EIbf = EFbf + NJ * SEQ;     // 200*208
    float* XBC = ws + XBASE;                    // BL*672 f32
    float* BCb = XBC + (long long)BL * XBCLD;   // BL*128
    float* DTb = BCb + (long long)BL * 128;     // BL*32
    float* DAb = DTb + (long long)BL * NH;      // BL*32
    float* MO  = DAb + (long long)BL * NH;      // BL*256 (h1/H)
    unsigned short* Gbf = (unsigned short*)XBC;             // in-place bf16 G, ld 1344
    unsigned short* xTbf = (unsigned short*)BCb;            // 256*256*200 bf16 (post-scan)
    unsigned short* XFT = (unsigned short*)XBC;             // 256*256*208 bf16 (post-out_proj)
    float* XI  = XBC + 7000000;                              // BL*256 f32
    unsigned short* HID = (unsigned short*)XBC;              // BL*1024 bf16 (post-combine)
    unsigned short* FFO = (unsigned short*)(XBC + 26500000); // BL*256 bf16

    // 1. DFT matrices (bf16) + weight packs
    init_dft_kernel<<<dim3((NJ * SEQ + SEQ * NJP + 255) / 256), dim3(256), 0, stream>>>(EFbf, EIbf);
    pack_wT_kernel<<<dim3((672 * 256 + 255) / 256), dim3(256), 0, stream>>>(in_proj_w, ipwT, DINPROJ, 512, 672, 256);
    pack_wT_kernel<<<dim3((256 * 512 + 255) / 256), dim3(256), 0, stream>>>(out_proj_w, opwT, 256, 0, 256, 512);
    pack_wT_kernel<<<dim3((1024 * 256 + 255) / 256), dim3(256), 0, stream>>>(ffn_w1, w1T, 1024, 0, 1024, 256);
    pack_wT_kernel<<<dim3((256 * 1024 + 255) / 256), dim3(256), 0, stream>>>(ffn_w2, w2T, 256, 0, 256, 1024);

    // 2. in_proj (xBC+dt cols): [BL,256] @ ipwT^T -> XBC f32 (ld 672)
    mgemm_kernel<0,0,0><<<dim3(6, BL / 128, 1), dim3(256), 0, stream>>>(
        x, ipwT, XBC, nullptr, BL, 672, 256, 256, 256, 672, 0, 0, 0);

    // 3. conv+silu B/C; dt -> DT/DA
    convbc_kernel<<<dim3(BL), dim3(192), 0, stream>>>(XBC, conv_w, conv_b, dt_bias, A_log,
                                                      BCb, DTb, DAb);

    // 4. scan v4 (prefetch + LDS dt/da), y in place (XBC cols 0..511 f32)
    scan4_kernel<<<dim3(BATCHN * NH / 4), dim3(256), 0, stream>>>(DTb, DAb, XBC, BCb, D_skip,
                                                                  conv_w, conv_b);

    // 4.5 x transpose -> xTbf (BCb region dead after scan)
    xT_kernel<<<dim3(7, 8, BATCHN), dim3(256), 0, stream>>>(x, xTbf);

    // 5. z-GEMV + gate + RMSNorm -> Gbf bf16 in place
    zgate_kernel<<<dim3(BL / 16), dim3(256), 0, stream>>>(x, in_proj_w, XBC, rms_w);

    // 6. out_proj: Gbf[BL,512](ld 1344) @ opwT^T -> MO f32
    mgemm_kernel<0,1,0><<<dim3(2, BL / 128, 1), dim3(256), 0, stream>>>(
        Gbf, opwT, MO, nullptr, BL, 256, 512, 1344, 512, 256, 0, 0, 0);

    // 7. h1 = LN(MO + x) in place
    lnadd_kernel<<<dim3(BL / 4), dim3(256), 0, stream>>>(MO, x, ln_g, ln_b, MO);

    // 8. FFT fwd (transposed): XFT[b] [256,202] = xTbf[b][256,200] @ EFbf^T, bf16 out (ld 208)
    mgemm_kernel<0,1,1><<<dim3(2, 2, BATCHN), dim3(256), 0, stream>>>(
        xTbf, EFbf, XFT, nullptr, 256, NJ, SEQ, SEQ, SEQ, NJP,
        (long long)DMODEL * SEQ, 0, (long long)DMODEL * NJP);

    // 9. spectral filter in place on XFT
    filt_kernel<<<dim3((BATCHN * DMODEL * NF + 255) / 256), dim3(256), 0, stream>>>(XFT, filt_w);

    // 10. FFT inv: XI[b] [200,256] = EIbf[200,202] @ XFT[b]^T, f32 out
    mgemm_kernel<0,1,0><<<dim3(2, 2, BATCHN), dim3(256), 0, stream>>>(
        EIbf, XFT, XI, nullptr, SEQ, DMODEL, NJ, NJP, NJP, DMODEL,
        0, (long long)DMODEL * NJP, (long long)SEQ * DMODEL);

    // 11. combine: MO = alpha*h1 + beta*LN(XI + x)
    combine_kernel<<<dim3(BL / 4), dim3(256), 0, stream>>>(XI, x, MO, filt_ln_g, filt_ln_b,
                                                           alpha, beta);

    // 12. FFN1: MO[BL,256] @ w1T^T + b1, GELU -> HID bf16
    mgemm_kernel<1,0,1><<<dim3(8, BL / 128, 1), dim3(256), 0, stream>>>(
        MO, w1T, HID, ffn_b1, BL, 1024, 256, 256, 256, 1024, 0, 0, 0);

    // 13. FFN2: HID[BL,1024] @ w2T^T + b2 -> FFO bf16
    mgemm_kernel<0,1,1><<<dim3(2, BL / 128, 1), dim3(256), 0, stream>>>(
        HID, w2T, FFO, ffn_b2, BL, 256, 1024, 1024, 1024, 256, 0, 0, 0);

    // 14. out = LN(FFO + MO)
    lnadd_bf_kernel<<<dim3(BL / 4), dim3(256), 0, stream>>>(FFO, MO, ffn_ln_g, ffn_ln_b, out);
}

// Round 7
// 1016.512 us; speedup vs baseline: 4.5950x; 1.2861x over previous
//
#include <hip/hip_runtime.h>
#include <math.h>

#define BATCHN 256
#define SEQ 200
#define DMODEL 256
#define DINNER 512
#define NH 32
#define HD 16
#define DSTATE 64
#define DINPROJ 1184
#define XBCLD 672
#define BL (BATCHN*SEQ)   // 51200
#define NF 101
#define NJ 202
#define NJP 208           // padded (16B-aligned bf16 rows)
#define XBASE 655360      // float offset of XBC region in ws
#define TC 25             // scan chunk length (SEQ = 8*25)
#define NCH 8

typedef __attribute__((ext_vector_type(8))) short bf16x8;
typedef __attribute__((ext_vector_type(4))) float f32x4;

__device__ inline unsigned short f2bf(float f) {
    union { float f; unsigned u; } v; v.f = f;
    unsigned r = v.u + 0x7FFFu + ((v.u >> 16) & 1u);
    return (unsigned short)(r >> 16);
}
__device__ inline float bf2f(unsigned short h) {
    union { unsigned u; float f; } v; v.u = ((unsigned)h) << 16;
    return v.f;
}

// ---------------- DFT matrices (bf16 direct) ----------------
__global__ void init_dft_kernel(unsigned short* __restrict__ EF, unsigned short* __restrict__ EI)
{
    const float ang = 6.28318530717958647692f / 200.0f;
    int idx = blockIdx.x * 256 + threadIdx.x;
    if (idx < NJ * SEQ) {
        int f = idx / SEQ, t = idx - f * SEQ;
        float v;
        if (f <= 100) { int ph = (f * t) % 200; v = cosf(ang * (float)ph); }
        else { int ff = f - 101; int ph = (ff * t) % 200; v = -sinf(ang * (float)ph); }
        EF[idx] = f2bf(v);
    } else if (idx < NJ * SEQ + SEQ * NJP) {
        int j2 = idx - NJ * SEQ;
        int t = j2 / NJP, j = j2 - t * NJP;
        float v;
        if (j == 0) v = 1.0f / 200.0f;
        else if (j == 100) v = ((t & 1) ? -1.0f : 1.0f) / 200.0f;
        else if (j < 100) { int ph = (j * t) % 200; v = 2.0f * cosf(ang * (float)ph) / 200.0f; }
        else if (j >= 202 || j == 101 || j == 201) v = 0.0f;
        else { int f = j - 101; int ph = (f * t) % 200; v = -2.0f * sinf(ang * (float)ph) / 200.0f; }
        EI[j2] = f2bf(v);
    }
}

// ---------------- weight pack: dst[n][k] = bf16(src[k][coloff+n]) ----------------
__global__ void pack_wT_kernel(const float* __restrict__ src, unsigned short* __restrict__ dst,
                               int srcld, int coloff, int N, int K)
{
    int idx = blockIdx.x * 256 + threadIdx.x;
    if (idx >= N * K) return;
    int n = idx / K, k = idx - n * K;
    dst[idx] = f2bf(src[(long long)k * srcld + coloff + n]);
}

// ---------------- x transpose: xT[b][d][t] = bf16(x[b][t][d]) ----------------
__global__ void xT_kernel(const float* __restrict__ X, unsigned short* __restrict__ XT)
{
    __shared__ float tile[32][33];
    int b = blockIdx.z, t0 = blockIdx.x * 32, d0 = blockIdx.y * 32;
    int tx = threadIdx.x & 31, ty = threadIdx.x >> 5;  // ty 0..7
    const float* xb = X + (long long)b * SEQ * DMODEL;
#pragma unroll
    for (int i = 0; i < 4; i++) {
        int t = t0 + ty + i * 8;
        tile[ty + i * 8][tx] = (t < SEQ) ? xb[(long long)t * DMODEL + d0 + tx] : 0.f;
    }
    __syncthreads();
    unsigned short* xtb = XT + (long long)b * DMODEL * SEQ;
#pragma unroll
    for (int i = 0; i < 4; i++) {
        int d = d0 + ty + i * 8;
        int t = t0 + tx;
        if (t < SEQ) xtb[(long long)d * SEQ + t] = f2bf(tile[tx][ty + i * 8]);
    }
}

// ---------------- bf16 MFMA GEMM ----------------
template<int ACT, int ABF, int CBF>
__global__ __launch_bounds__(256) void mgemm_kernel(
    const void* __restrict__ Ap, const unsigned short* __restrict__ BTp, void* __restrict__ Cp,
    const float* __restrict__ bias,
    int M, int N, int K, int lda, int ldbt, int ldc,
    long long sA, long long sBT, long long sC)
{
    __shared__ unsigned short As[128 * 40];
    __shared__ unsigned short Bs[128 * 40];
    const float* Af = (const float*)Ap + (ABF ? 0 : (long long)blockIdx.z * sA);
    const unsigned short* Ab = (const unsigned short*)Ap + (ABF ? (long long)blockIdx.z * sA : 0);
    const unsigned short* Bt = BTp + (long long)blockIdx.z * sBT;
    float* Cf = (float*)Cp + (CBF ? 0 : (long long)blockIdx.z * sC);
    unsigned short* Cb = (unsigned short*)Cp + (CBF ? (long long)blockIdx.z * sC : 0);

    int m0 = blockIdx.y * 128, n0 = blockIdx.x * 128;
    int tid = threadIdx.x;
    int srow = tid >> 1, skb = (tid & 1) * 16;
    int w = tid >> 6, l = tid & 63;
    int wr = w >> 1, wc = w & 1;
    int fr = l & 15, fk = l >> 4;

    f32x4 acc[4][4] = {};

    for (int k0 = 0; k0 < K; k0 += 32) {
        bool kedge = (k0 + 32 > K);
        {
            int gm = m0 + srow;
            unsigned short* dst = &As[srow * 40 + skb];
            if (gm < M && !kedge) {
                if (ABF) {
                    const unsigned short* src = Ab + (long long)gm * lda + k0 + skb;
                    ((uint4*)dst)[0] = ((const uint4*)src)[0];
                    ((uint4*)dst)[1] = ((const uint4*)src)[1];
                } else {
                    const float* src = Af + (long long)gm * lda + k0 + skb;
                    float4 f0 = ((const float4*)src)[0];
                    float4 f1 = ((const float4*)src)[1];
                    float4 f2 = ((const float4*)src)[2];
                    float4 f3 = ((const float4*)src)[3];
                    uint4 q0, q1;
                    q0.x = (unsigned)f2bf(f0.x) | ((unsigned)f2bf(f0.y) << 16);
                    q0.y = (unsigned)f2bf(f0.z) | ((unsigned)f2bf(f0.w) << 16);
                    q0.z = (unsigned)f2bf(f1.x) | ((unsigned)f2bf(f1.y) << 16);
                    q0.w = (unsigned)f2bf(f1.z) | ((unsigned)f2bf(f1.w) << 16);
                    q1.x = (unsigned)f2bf(f2.x) | ((unsigned)f2bf(f2.y) << 16);
                    q1.y = (unsigned)f2bf(f2.z) | ((unsigned)f2bf(f2.w) << 16);
                    q1.z = (unsigned)f2bf(f3.x) | ((unsigned)f2bf(f3.y) << 16);
                    q1.w = (unsigned)f2bf(f3.z) | ((unsigned)f2bf(f3.w) << 16);
                    ((uint4*)dst)[0] = q0;
                    ((uint4*)dst)[1] = q1;
                }
            } else {
#pragma unroll
                for (int i = 0; i < 16; i++) {
                    int gk = k0 + skb + i;
                    unsigned short v = 0;
                    if (gm < M && gk < K)
                        v = ABF ? Ab[(long long)gm * lda + gk]
                                : f2bf(Af[(long long)gm * lda + gk]);
                    dst[i] = v;
                }
            }
        }
        {
            int gn = n0 + srow;
            unsigned short* dst = &Bs[srow * 40 + skb];
            if (gn < N && !kedge) {
                const unsigned short* src = Bt + (long long)gn * ldbt + k0 + skb;
                ((uint4*)dst)[0] = ((const uint4*)src)[0];
                ((uint4*)dst)[1] = ((const uint4*)src)[1];
            } else {
#pragma unroll
                for (int i = 0; i < 16; i++) {
                    int gk = k0 + skb + i;
                    dst[i] = (gn < N && gk < K) ? Bt[(long long)gn * ldbt + gk] : (unsigned short)0;
                }
            }
        }
        __syncthreads();
        bf16x8 a[4], b[4];
#pragma unroll
        for (int i = 0; i < 4; i++) {
            a[i] = *(const bf16x8*)&As[(wr * 64 + i * 16 + fr) * 40 + fk * 8];
            b[i] = *(const bf16x8*)&Bs[(wc * 64 + i * 16 + fr) * 40 + fk * 8];
        }
#pragma unroll
        for (int i = 0; i < 4; i++)
#pragma unroll
            for (int j = 0; j < 4; j++)
                acc[i][j] = __builtin_amdgcn_mfma_f32_16x16x32_bf16(a[i], b[j], acc[i][j], 0, 0, 0);
        __syncthreads();
    }

#pragma unroll
    for (int i = 0; i < 4; i++) {
        int gr0 = m0 + wr * 64 + i * 16 + fk * 4;
#pragma unroll
        for (int j = 0; j < 4; j++) {
            int gc = n0 + wc * 64 + j * 16 + fr;
            if (gc >= N) continue;
            float bv = bias ? bias[gc] : 0.f;
#pragma unroll
            for (int r = 0; r < 4; r++) {
                int gr = gr0 + r;
                if (gr >= M) continue;
                float v = acc[i][j][r] + bv;
                if (ACT == 1) v = 0.5f * v * (1.f + erff(v * 0.70710678118654752f));
                long long ci = (long long)gr * ldc + gc;
                if (CBF) Cb[ci] = f2bf(v);
                else Cf[ci] = v;
            }
        }
    }
}

// ---------------- conv+silu for B/C channels, dt/dA ----------------
__global__ void convbc_kernel(const float* __restrict__ XBC, const float* __restrict__ conv_w,
                              const float* __restrict__ conv_b, const float* __restrict__ dt_bias,
                              const float* __restrict__ A_log,
                              float* __restrict__ BCb, float* __restrict__ DTb, float* __restrict__ DAb)
{
    int row = blockIdx.x;
    int b = row / SEQ, l = row - b * SEQ;
    int tid = threadIdx.x;
    if (tid < 128) {
        int ch = 512 + tid;
        float acc = conv_b[ch];
#pragma unroll
        for (int k = 0; k < 4; k++) {
            int lt = l + k - 3;
            if (lt >= 0)
                acc = fmaf(conv_w[ch * 4 + k], XBC[(long long)(b * SEQ + lt) * XBCLD + ch], acc);
        }
        BCb[(long long)row * 128 + tid] = acc * __builtin_amdgcn_rcpf(1.f + __expf(-acc));
    } else if (tid < 160) {
        int h = tid - 128;
        float draw = XBC[(long long)row * XBCLD + 640 + h] + dt_bias[h];
        float dtv = (draw > 20.f) ? draw : log1pf(__expf(draw));
        DTb[(long long)row * NH + h] = dtv;
        DAb[(long long)row * NH + h] = __expf(-__expf(A_log[h]) * dtv);
    }
}

// ---------------- selective scan v5: LDS chunk staging, 2 heads/wave ----------------
__device__ __forceinline__ void sstep(
    float raw, float dtv, float da,
    const float4& qb0, const float4& qb1, const float4& qb2, const float4& qb3,
    const float4& qc0, const float4& qc1, const float4& qc2, const float4& qc3,
    float cw0, float cw1, float cw2, float cw3, float cb, float ds,
    float* st, float& w0, float& w1, float& w2,
    int lane, float* __restrict__ yaddr)
{
    float cvv = cb + cw0 * w0 + cw1 * w1 + cw2 * w2 + cw3 * raw;
    float xhv = cvv * __builtin_amdgcn_rcpf(1.f + __expf(-cvv));
    w0 = w1; w1 = w2; w2 = raw;
    float xv = dtv * xhv;
    float p0, p1, p2, p3;
    st[0]  = fmaf(da, st[0],  xv * qb0.x); p0 = st[0]  * qc0.x;
    st[1]  = fmaf(da, st[1],  xv * qb0.y); p1 = st[1]  * qc0.y;
    st[2]  = fmaf(da, st[2],  xv * qb0.z); p2 = st[2]  * qc0.z;
    st[3]  = fmaf(da, st[3],  xv * qb0.w); p3 = st[3]  * qc0.w;
    st[4]  = fmaf(da, st[4],  xv * qb1.x); p0 = fmaf(st[4],  qc1.x, p0);
    st[5]  = fmaf(da, st[5],  xv * qb1.y); p1 = fmaf(st[5],  qc1.y, p1);
    st[6]  = fmaf(da, st[6],  xv * qb1.z); p2 = fmaf(st[6],  qc1.z, p2);
    st[7]  = fmaf(da, st[7],  xv * qb1.w); p3 = fmaf(st[7],  qc1.w, p3);
    st[8]  = fmaf(da, st[8],  xv * qb2.x); p0 = fmaf(st[8],  qc2.x, p0);
    st[9]  = fmaf(da, st[9],  xv * qb2.y); p1 = fmaf(st[9],  qc2.y, p1);
    st[10] = fmaf(da, st[10], xv * qb2.z); p2 = fmaf(st[10], qc2.z, p2);
    st[11] = fmaf(da, st[11], xv * qb2.w); p3 = fmaf(st[11], qc2.w, p3);
    st[12] = fmaf(da, st[12], xv * qb3.x); p0 = fmaf(st[12], qc3.x, p0);
    st[13] = fmaf(da, st[13], xv * qb3.y); p1 = fmaf(st[13], qc3.y, p1);
    st[14] = fmaf(da, st[14], xv * qb3.z); p2 = fmaf(st[14], qc3.z, p2);
    st[15] = fmaf(da, st[15], xv * qb3.w); p3 = fmaf(st[15], qc3.w, p3);
    float part = (p0 + p1) + (p2 + p3);
    part += __shfl_xor(part, 16);
    part += __shfl_xor(part, 32);
    if (lane < HD) *yaddr = part + ds * xhv;
}

// block = 4 waves, one batch b, 8 heads (hq..hq+7); wave wv: heads hq+wv, hq+4+wv.
__global__ __launch_bounds__(256) void scan5_kernel(
    const float* __restrict__ DTb, const float* __restrict__ DAb,
    float* __restrict__ XBC, const float* __restrict__ BCb,
    const float* __restrict__ Dsk,
    const float* __restrict__ conv_w, const float* __restrict__ conv_b)
{
    __shared__ float sbc[2][TC][128];
    __shared__ float sx[2][TC][128];
    __shared__ float sdt[SEQ][8];
    __shared__ float sda[SEQ][8];
    int tid = threadIdx.x;
    int wv = tid >> 6, lane = tid & 63;
    int bid = blockIdx.x;
    int b = bid >> 2, hq = (bid & 3) * 8;
    long long rowb = (long long)b * SEQ;

    // stage dt/da for whole seq, 8 heads
    for (int i = tid; i < SEQ * 8; i += 256) {
        int t = i >> 3, j = i & 7;
        sdt[t][j] = DTb[(rowb + t) * NH + hq + j];
        sda[t][j] = DAb[(rowb + t) * NH + hq + j];
    }
    // stage chunk 0 (B/C and x)
    for (int i = tid; i < TC * 32; i += 256) {
        int r = i >> 5, c = i & 31;
        ((float4*)&sbc[0][r][0])[c] = ((const float4*)(BCb + (rowb + r) * 128))[c];
        ((float4*)&sx[0][r][0])[c] = ((const float4*)(XBC + (rowb + r) * XBCLD + hq * 16))[c];
    }
    __syncthreads();

    int p = lane & 15, g = lane >> 4;
    int hA = hq + wv, hB = hq + 4 + wv;
    int chA = hA * HD + p, chB = hB * HD + p;
    float cwA0 = conv_w[chA * 4 + 0], cwA1 = conv_w[chA * 4 + 1];
    float cwA2 = conv_w[chA * 4 + 2], cwA3 = conv_w[chA * 4 + 3];
    float cbA = conv_b[chA];
    float cwB0 = conv_w[chB * 4 + 0], cwB1 = conv_w[chB * 4 + 1];
    float cwB2 = conv_w[chB * 4 + 2], cwB3 = conv_w[chB * 4 + 3];
    float cbB = conv_b[chB];
    float dsA = Dsk[hA], dsB = Dsk[hB];
    int xcA = wv * 16 + p, xcB = (4 + wv) * 16 + p;
    float* ypA = XBC + (rowb) * XBCLD + hA * HD + p;
    float* ypB = XBC + (rowb) * XBCLD + hB * HD + p;
    float stA[16], stB[16];
#pragma unroll
    for (int r = 0; r < 16; r++) { stA[r] = 0.f; stB[r] = 0.f; }
    float wA0 = 0.f, wA1 = 0.f, wA2 = 0.f;
    float wB0 = 0.f, wB1 = 0.f, wB2 = 0.f;

    for (int c = 0; c < NCH; c++) {
        int cur = c & 1;
        if (c + 1 < NCH) {
            int nb = cur ^ 1;
            long long tb = rowb + (c + 1) * TC;
            for (int i = tid; i < TC * 32; i += 256) {
                int r = i >> 5, cc = i & 31;
                ((float4*)&sbc[nb][r][0])[cc] = ((const float4*)(BCb + (tb + r) * 128))[cc];
                ((float4*)&sx[nb][r][0])[cc] = ((const float4*)(XBC + (tb + r) * XBCLD + hq * 16))[cc];
            }
        }
        int tbase = c * TC;
        for (int t = 0; t < TC; t++) {
            int gt = tbase + t;
            const float4* qb = (const float4*)&sbc[cur][t][g * 16];
            const float4* qc = (const float4*)&sbc[cur][t][64 + g * 16];
            float4 qb0 = qb[0], qb1 = qb[1], qb2 = qb[2], qb3 = qb[3];
            float4 qc0 = qc[0], qc1 = qc[1], qc2 = qc[2], qc3 = qc[3];
            float rawA = sx[cur][t][xcA];
            float rawB = sx[cur][t][xcB];
            sstep(rawA, sdt[gt][wv], sda[gt][wv], qb0, qb1, qb2, qb3, qc0, qc1, qc2, qc3,
                  cwA0, cwA1, cwA2, cwA3, cbA, dsA, stA, wA0, wA1, wA2,
                  lane, ypA + (long long)gt * XBCLD);
            sstep(rawB, sdt[gt][4 + wv], sda[gt][4 + wv], qb0, qb1, qb2, qb3, qc0, qc1, qc2, qc3,
                  cwB0, cwB1, cwB2, cwB3, cbB, dsB, stB, wB0, wB1, wB2,
                  lane, ypB + (long long)gt * XBCLD);
        }
        __syncthreads();
    }
}

// ---------------- gate: G = rmsnorm(y * silu(z)) * w  (bf16 out, in-place over y) ----------------
__global__ __launch_bounds__(256) void gate_kernel(
    float* __restrict__ XBC, const unsigned short* __restrict__ Zbf,
    const float* __restrict__ rms_w)
{
    int row = blockIdx.x * 4 + (threadIdx.x >> 6);
    int lane = threadIdx.x & 63;
    float* yrow = XBC + (long long)row * XBCLD + lane * 8;
    const unsigned short* zrow = Zbf + (long long)row * 512 + lane * 8;
    float4 y0 = ((const float4*)yrow)[0];
    float4 y1 = ((const float4*)yrow)[1];
    uint4 zq = ((const uint4*)zrow)[0];
    float yv[8] = { y0.x, y0.y, y0.z, y0.w, y1.x, y1.y, y1.z, y1.w };
    float zv[8];
    zv[0] = bf2f((unsigned short)(zq.x & 0xFFFF)); zv[1] = bf2f((unsigned short)(zq.x >> 16));
    zv[2] = bf2f((unsigned short)(zq.y & 0xFFFF)); zv[3] = bf2f((unsigned short)(zq.y >> 16));
    zv[4] = bf2f((unsigned short)(zq.z & 0xFFFF)); zv[5] = bf2f((unsigned short)(zq.z >> 16));
    zv[6] = bf2f((unsigned short)(zq.w & 0xFFFF)); zv[7] = bf2f((unsigned short)(zq.w >> 16));
    float a[8]; float ss = 0.f;
#pragma unroll
    for (int i = 0; i < 8; i++) {
        float z = zv[i];
        a[i] = yv[i] * (z * __builtin_amdgcn_rcpf(1.f + __expf(-z)));
        ss = fmaf(a[i], a[i], ss);
    }
#pragma unroll
    for (int m = 1; m < 64; m <<= 1) ss += __shfl_xor(ss, m);
    float sc = rsqrtf(ss * (1.f / 512.f) + 1e-5f);
    const float* rw = rms_w + lane * 8;
    float4 r0 = ((const float4*)rw)[0];
    float4 r1 = ((const float4*)rw)[1];
    float rv[8] = { r0.x, r0.y, r0.z, r0.w, r1.x, r1.y, r1.z, r1.w };
    uint4 o;
    o.x = (unsigned)f2bf(a[0] * sc * rv[0]) | ((unsigned)f2bf(a[1] * sc * rv[1]) << 16);
    o.y = (unsigned)f2bf(a[2] * sc * rv[2]) | ((unsigned)f2bf(a[3] * sc * rv[3]) << 16);
    o.z = (unsigned)f2bf(a[4] * sc * rv[4]) | ((unsigned)f2bf(a[5] * sc * rv[5]) << 16);
    o.w = (unsigned)f2bf(a[6] * sc * rv[6]) | ((unsigned)f2bf(a[7] * sc * rv[7]) << 16);
    unsigned short* grow = (unsigned short*)(XBC + (long long)row * XBCLD);
    ((uint4*)grow)[lane] = o;
}

// ---------------- LayerNorm(a+b)*g+be (f32,f32) ----------------
__global__ void lnadd_kernel(const float* __restrict__ A, const float* __restrict__ Bb,
                             const float* __restrict__ g, const float* __restrict__ be,
                             float* __restrict__ O)
{
    int row = blockIdx.x * 4 + (threadIdx.x >> 6);
    int lane = threadIdx.x & 63;
    long long base = (long long)row * DMODEL + lane * 4;
    float v[4]; float s1 = 0.f;
#pragma unroll
    for (int i = 0; i < 4; i++) { float a = A[base + i] + Bb[base + i]; v[i] = a; s1 += a; }
#pragma unroll
    for (int m = 1; m < 64; m <<= 1) s1 += __shfl_xor(s1, m);
    float mean = s1 * (1.f / 256.f);
    float s2 = 0.f;
#pragma unroll
    for (int i = 0; i < 4; i++) { float d = v[i] - mean; s2 = fmaf(d, d, s2); }
#pragma unroll
    for (int m = 1; m < 64; m <<= 1) s2 += __shfl_xor(s2, m);
    float r = rsqrtf(s2 * (1.f / 256.f) + 1e-12f);
#pragma unroll
    for (int i = 0; i < 4; i++)
        O[base + i] = (v[i] - mean) * r * g[lane * 4 + i] + be[lane * 4 + i];
}

// ---------------- LayerNorm(bf16 a + f32 b)*g+be -> f32 ----------------
__global__ void lnadd_bf_kernel(const unsigned short* __restrict__ A, const float* __restrict__ Bb,
                                const float* __restrict__ g, const float* __restrict__ be,
                                float* __restrict__ O)
{
    int row = blockIdx.x * 4 + (threadIdx.x >> 6);
    int lane = threadIdx.x & 63;
    long long base = (long long)row * DMODEL + lane * 4;
    float v[4]; float s1 = 0.f;
#pragma unroll
    for (int i = 0; i < 4; i++) { float a = bf2f(A[base + i]) + Bb[base + i]; v[i] = a; s1 += a; }
#pragma unroll
    for (int m = 1; m < 64; m <<= 1) s1 += __shfl_xor(s1, m);
    float mean = s1 * (1.f / 256.f);
    float s2 = 0.f;
#pragma unroll
    for (int i = 0; i < 4; i++) { float d = v[i] - mean; s2 = fmaf(d, d, s2); }
#pragma unroll
    for (int m = 1; m < 64; m <<= 1) s2 += __shfl_xor(s2, m);
    float r = rsqrtf(s2 * (1.f / 256.f) + 1e-12f);
#pragma unroll
    for (int i = 0; i < 4; i++)
        O[base + i] = (v[i] - mean) * r * g[lane * 4 + i] + be[lane * 4 + i];
}

// ---------------- combine: H1 = alpha*H1 + beta*LN(XI + X) ----------------
__global__ void combine_kernel(const float* __restrict__ XI, const float* __restrict__ X,
                               float* __restrict__ H1,
                               const float* __restrict__ fg, const float* __restrict__ fb,
                               const float* __restrict__ al, const float* __restrict__ bt)
{
    int row = blockIdx.x * 4 + (threadIdx.x >> 6);
    int lane = threadIdx.x & 63;
    long long base = (long long)row * DMODEL + lane * 4;
    float v[4]; float s1 = 0.f;
#pragma unroll
    for (int i = 0; i < 4; i++) { float a = XI[base + i] + X[base + i]; v[i] = a; s1 += a; }
#pragma unroll
    for (int m = 1; m < 64; m <<= 1) s1 += __shfl_xor(s1, m);
    float mean = s1 * (1.f / 256.f);
    float s2 = 0.f;
#pragma unroll
    for (int i = 0; i < 4; i++) { float d = v[i] - mean; s2 = fmaf(d, d, s2); }
#pragma unroll
    for (int m = 1; m < 64; m <<= 1) s2 += __shfl_xor(s2, m);
    float r = rsqrtf(s2 * (1.f / 256.f) + 1e-12f);
#pragma unroll
    for (int i = 0; i < 4; i++) {
        float h2 = (v[i] - mean) * r * fg[lane * 4 + i] + fb[lane * 4 + i];
        H1[base + i] = al[lane * 4 + i] * H1[base + i] + bt[lane * 4 + i] * h2;
    }
}

// ---------------- pointwise spectral filter on XFT[b][d][j] bf16 (ld 208) ----------------
__global__ void filt_kernel(unsigned short* __restrict__ XF, const float* __restrict__ W)
{
    long long idx = (long long)blockIdx.x * 256 + threadIdx.x;
    if (idx >= (long long)BATCHN * DMODEL * NF) return;
    int f = (int)(idx % NF);
    int d = (int)((idx / NF) % DMODEL);
    int b = (int)(idx / ((long long)NF * DMODEL));
    long long base = ((long long)b * DMODEL + d) * NJP;
    float re = bf2f(XF[base + f]);
    float im = bf2f(XF[base + 101 + f]);
    float wr = W[((long long)f * DMODEL + d) * 2];
    float wi = W[((long long)f * DMODEL + d) * 2 + 1];
    XF[base + f]       = f2bf(re * wr - im * wi);
    XF[base + 101 + f] = f2bf(re * wi + im * wr);
}

extern "C" void kernel_launch(void* const* d_in, const int* in_sizes, int n_in,
                              void* d_out, int out_size, void* d_ws, size_t ws_size,
                              hipStream_t stream)
{
    const float* x          = (const float*)d_in[0];
    const float* in_proj_w  = (const float*)d_in[1];
    const float* conv_w     = (const float*)d_in[2];
    const float* conv_b     = (const float*)d_in[3];
    const float* dt_bias    = (const float*)d_in[4];
    const float* A_log      = (const float*)d_in[5];
    const float* D_skip     = (const float*)d_in[6];
    const float* rms_w      = (const float*)d_in[7];
    const float* out_proj_w = (const float*)d_in[8];
    const float* ln_g       = (const float*)d_in[9];
    const float* ln_b       = (const float*)d_in[10];
    const float* filt_w     = (const float*)d_in[11];
    const float* filt_ln_g  = (const float*)d_in[12];
    const float* filt_ln_b  = (const float*)d_in[13];
    const float* alpha      = (const float*)d_in[14];
    const float* beta       = (const float*)d_in[15];
    const float* ffn_w1     = (const float*)d_in[16];
    const float* ffn_b1     = (const float*)d_in[17];
    const float* ffn_w2     = (const float*)d_in[18];
    const float* ffn_b2     = (const float*)d_in[19];
    const float* ffn_ln_g   = (const float*)d_in[20];
    const float* ffn_ln_b   = (const float*)d_in[21];
    float* out = (float*)d_out;
    float* ws = (float*)d_ws;

    // weights arena [81920 .. XBASE)
    unsigned short* WP   = (unsigned short*)(ws + 81920);
    unsigned short* ipwT = WP;                  // 672*256
    unsigned short* opwT = ipwT + 672 * 256;    // 256*512
    unsigned short* w1T  = opwT + 256 * 512;    // 1024*256
    unsigned short* w2T  = w1T + 1024 * 256;    // 256*1024
    unsigned short* zwT  = w2T + 256 * 1024;    // 512*256
    unsigned short* EFbf = zwT + 512 * 256;     // 202*200
    unsigned short* EIbf = EFbf + NJ * SEQ;     // 200*208
    float* XBC = ws + XBASE;                    // BL*672 f32 arena
    float* BCb = XBC + (long long)BL * XBCLD;   // BL*128
    float* DTb = BCb + (long long)BL * 128;     // BL*32
    float* DAb = DTb + (long long)BL * NH;      // BL*32
    float* MO  = DAb + (long long)BL * NH;      // BL*256 (h1/H)
    // Zbf ALIASES MO: Zbf lifetime = [zproj .. gate], MO first written at out_proj (after gate).
    unsigned short* Zbf = (unsigned short*)MO;  // BL*512 bf16 == BL*256 f32
    // XBC arena reuse:
    unsigned short* Gbf = (unsigned short*)XBC;             // bf16 G in place, ld 1344
    unsigned short* xTbf = (unsigned short*)BCb;            // 256*256*200 bf16 (post-scan)
    unsigned short* XFT = (unsigned short*)XBC;             // 256*256*208 bf16 (post-out_proj)
    float* XI  = XBC + 7000000;                              // BL*256 f32
    unsigned short* HID = (unsigned short*)XBC;              // BL*1024 bf16 (post-combine)
    unsigned short* FFO = (unsigned short*)(XBC + 26500000); // BL*256 bf16

    // 1. DFT matrices (bf16) + weight packs
    init_dft_kernel<<<dim3((NJ * SEQ + SEQ * NJP + 255) / 256), dim3(256), 0, stream>>>(EFbf, EIbf);
    pack_wT_kernel<<<dim3((672 * 256 + 255) / 256), dim3(256), 0, stream>>>(in_proj_w, ipwT, DINPROJ, 512, 672, 256);
    pack_wT_kernel<<<dim3((512 * 256 + 255) / 256), dim3(256), 0, stream>>>(in_proj_w, zwT, DINPROJ, 0, 512, 256);
    pack_wT_kernel<<<dim3((256 * 512 + 255) / 256), dim3(256), 0, stream>>>(out_proj_w, opwT, 256, 0, 256, 512);
    pack_wT_kernel<<<dim3((1024 * 256 + 255) / 256), dim3(256), 0, stream>>>(ffn_w1, w1T, 1024, 0, 1024, 256);
    pack_wT_kernel<<<dim3((256 * 1024 + 255) / 256), dim3(256), 0, stream>>>(ffn_w2, w2T, 256, 0, 256, 1024);

    // 2. in_proj (xBC+dt cols): [BL,256] @ ipwT^T -> XBC f32 (ld 672)
    mgemm_kernel<0,0,0><<<dim3(6, BL / 128, 1), dim3(256), 0, stream>>>(
        x, ipwT, XBC, nullptr, BL, 672, 256, 256, 256, 672, 0, 0, 0);

    // 2b. z projection: [BL,256] @ zwT^T -> Zbf bf16 (aliases MO)
    mgemm_kernel<0,0,1><<<dim3(4, BL / 128, 1), dim3(256), 0, stream>>>(
        x, zwT, Zbf, nullptr, BL, 512, 256, 256, 256, 512, 0, 0, 0);

    // 3. conv+silu B/C; dt -> DT/DA
    convbc_kernel<<<dim3(BL), dim3(192), 0, stream>>>(XBC, conv_w, conv_b, dt_bias, A_log,
                                                      BCb, DTb, DAb);

    // 4. scan v5 (LDS chunk staging, 2 heads/wave), y in place f32
    scan5_kernel<<<dim3(BATCHN * 4), dim3(256), 0, stream>>>(DTb, DAb, XBC, BCb, D_skip,
                                                             conv_w, conv_b);

    // 4.5 x transpose -> xTbf (BCb region dead after scan)
    xT_kernel<<<dim3(7, 8, BATCHN), dim3(256), 0, stream>>>(x, xTbf);

    // 5. gate: G = rmsnorm(y*silu(z))*w -> Gbf bf16 in place
    gate_kernel<<<dim3(BL / 4), dim3(256), 0, stream>>>(XBC, Zbf, rms_w);

    // 6. out_proj: Gbf[BL,512](ld 1344) @ opwT^T -> MO f32 (Zbf dead now)
    mgemm_kernel<0,1,0><<<dim3(2, BL / 128, 1), dim3(256), 0, stream>>>(
        Gbf, opwT, MO, nullptr, BL, 256, 512, 1344, 512, 256, 0, 0, 0);

    // 7. h1 = LN(MO + x) in place
    lnadd_kernel<<<dim3(BL / 4), dim3(256), 0, stream>>>(MO, x, ln_g, ln_b, MO);

    // 8. FFT fwd (transposed): XFT[b] [256,202] = xTbf[b][256,200] @ EFbf^T, bf16 out (ld 208)
    mgemm_kernel<0,1,1><<<dim3(2, 2, BATCHN), dim3(256), 0, stream>>>(
        xTbf, EFbf, XFT, nullptr, 256, NJ, SEQ, SEQ, SEQ, NJP,
        (long long)DMODEL * SEQ, 0, (long long)DMODEL * NJP);

    // 9. spectral filter in place on XFT
    filt_kernel<<<dim3((BATCHN * DMODEL * NF + 255) / 256), dim3(256), 0, stream>>>(XFT, filt_w);

    // 10. FFT inv: XI[b] [200,256] = EIbf[200,202] @ XFT[b]^T, f32 out
    mgemm_kernel<0,1,0><<<dim3(2, 2, BATCHN), dim3(256), 0, stream>>>(
        EIbf, XFT, XI, nullptr, SEQ, DMODEL, NJ, NJP, NJP, DMODEL,
        0, (long long)DMODEL * NJP, (long long)SEQ * DMODEL);

    // 11. combine: MO = alpha*h1 + beta*LN(XI + x)
    combine_kernel<<<dim3(BL / 4), dim3(256), 0, stream>>>(XI, x, MO, filt_ln_g, filt_ln_b,
                                                           alpha, beta);

    // 12. FFN1: MO[BL,256] @ w1T^T + b1, GELU -> HID bf16
    mgemm_kernel<1,0,1><<<dim3(8, BL / 128, 1), dim3(256), 0, stream>>>(
        MO, w1T, HID, ffn_b1, BL, 1024, 256, 256, 256, 1024, 0, 0, 0);

    // 13. FFN2: HID[BL,1024] @ w2T^T + b2 -> FFO bf16
    mgemm_kernel<0,1,1><<<dim3(2, BL / 128, 1), dim3(256), 0, stream>>>(
        HID, w2T, FFO, ffn_b2, BL, 256, 1024, 1024, 1024, 256, 0, 0, 0);

    // 14. out = LN(FFO + MO)
    lnadd_bf_kernel<<<dim3(BL / 4), dim3(256), 0, stream>>>(FFO, MO, ffn_ln_g, ffn_ln_b, out);
}

// Round 8
// 970.498 us; speedup vs baseline: 4.8128x; 1.0474x over previous
//
#include <hip/hip_runtime.h>
#include <math.h>

#define BATCHN 256
#define SEQ 200
#define DMODEL 256
#define DINNER 512
#define NH 32
#define HD 16
#define DSTATE 64
#define DINPROJ 1184
#define XBCLD 672
#define BL (BATCHN*SEQ)   // 51200
#define NF 101
#define NJ 202
#define NJP 208
#define XBASE 655360
#define TC 25
#define NCH 8

typedef __attribute__((ext_vector_type(8))) short bf16x8;
typedef __attribute__((ext_vector_type(4))) float f32x4;

__device__ inline unsigned short f2bf(float f) {
    union { float f; unsigned u; } v; v.f = f;
    unsigned r = v.u + 0x7FFFu + ((v.u >> 16) & 1u);
    return (unsigned short)(r >> 16);
}
__device__ inline float bf2f(unsigned short h) {
    union { unsigned u; float f; } v; v.u = ((unsigned)h) << 16;
    return v.f;
}

#define GLOAD16(src, dst) __builtin_amdgcn_global_load_lds( \
    (const __attribute__((address_space(1))) void*)(src),   \
    (__attribute__((address_space(3))) void*)(dst), 16, 0, 0)

// ---------------- DFT matrices (bf16 direct) ----------------
__global__ void init_dft_kernel(unsigned short* __restrict__ EF, unsigned short* __restrict__ EI)
{
    const float ang = 6.28318530717958647692f / 200.0f;
    int idx = blockIdx.x * 256 + threadIdx.x;
    if (idx < NJ * SEQ) {
        int f = idx / SEQ, t = idx - f * SEQ;
        float v;
        if (f <= 100) { int ph = (f * t) % 200; v = cosf(ang * (float)ph); }
        else { int ff = f - 101; int ph = (ff * t) % 200; v = -sinf(ang * (float)ph); }
        EF[idx] = f2bf(v);
    } else if (idx < NJ * SEQ + SEQ * NJP) {
        int j2 = idx - NJ * SEQ;
        int t = j2 / NJP, j = j2 - t * NJP;
        float v;
        if (j == 0) v = 1.0f / 200.0f;
        else if (j == 100) v = ((t & 1) ? -1.0f : 1.0f) / 200.0f;
        else if (j < 100) { int ph = (j * t) % 200; v = 2.0f * cosf(ang * (float)ph) / 200.0f; }
        else if (j >= 202 || j == 101 || j == 201) v = 0.0f;
        else { int f = j - 101; int ph = (f * t) % 200; v = -2.0f * sinf(ang * (float)ph) / 200.0f; }
        EI[j2] = f2bf(v);
    }
}

// ---------------- weight pack: dst[n][k] = bf16(src[k][coloff+n]) ----------------
__global__ void pack_wT_kernel(const float* __restrict__ src, unsigned short* __restrict__ dst,
                               int srcld, int coloff, int N, int K)
{
    int idx = blockIdx.x * 256 + threadIdx.x;
    if (idx >= N * K) return;
    int n = idx / K, k = idx - n * K;
    dst[idx] = f2bf(src[(long long)k * srcld + coloff + n]);
}

// ---------------- f32 -> bf16 bulk convert (n multiple of 2048) ----------------
__global__ void f2bf_kernel(const float* __restrict__ X, unsigned short* __restrict__ O)
{
    long long i = ((long long)blockIdx.x * 256 + threadIdx.x) * 8;
    float4 a = ((const float4*)(X + i))[0];
    float4 b = ((const float4*)(X + i))[1];
    uint4 o;
    o.x = (unsigned)f2bf(a.x) | ((unsigned)f2bf(a.y) << 16);
    o.y = (unsigned)f2bf(a.z) | ((unsigned)f2bf(a.w) << 16);
    o.z = (unsigned)f2bf(b.x) | ((unsigned)f2bf(b.y) << 16);
    o.w = (unsigned)f2bf(b.z) | ((unsigned)f2bf(b.w) << 16);
    *(uint4*)(O + i) = o;
}

// ---------------- x transpose: xT[b][d][t] = bf16(x[b][t][d]) ----------------
__global__ void xT_kernel(const float* __restrict__ X, unsigned short* __restrict__ XT)
{
    __shared__ float tile[32][33];
    int b = blockIdx.z, t0 = blockIdx.x * 32, d0 = blockIdx.y * 32;
    int tx = threadIdx.x & 31, ty = threadIdx.x >> 5;
    const float* xb = X + (long long)b * SEQ * DMODEL;
#pragma unroll
    for (int i = 0; i < 4; i++) {
        int t = t0 + ty + i * 8;
        tile[ty + i * 8][tx] = (t < SEQ) ? xb[(long long)t * DMODEL + d0 + tx] : 0.f;
    }
    __syncthreads();
    unsigned short* xtb = XT + (long long)b * DMODEL * SEQ;
#pragma unroll
    for (int i = 0; i < 4; i++) {
        int d = d0 + ty + i * 8;
        int t = t0 + tx;
        if (t < SEQ) xtb[(long long)d * SEQ + t] = f2bf(tile[tx][ty + i * 8]);
    }
}

// ---------------- bf16 MFMA GEMM v2: global_load_lds, linear LDS ----------------
// C[M,N] = A[M,K](bf16) @ BT[N,K](bf16)^T (+bias)(+GELU). 128x128, BK=32, 4 waves.
template<int ACT, int CBF>
__global__ __launch_bounds__(256) void mgemm_kernel(
    const unsigned short* __restrict__ Ab, const unsigned short* __restrict__ BTp,
    void* __restrict__ Cp, const float* __restrict__ bias,
    int M, int N, int K, int lda, int ldbt, int ldc,
    long long sA, long long sBT, long long sC)
{
    __shared__ unsigned short As[128 * 32];
    __shared__ unsigned short Bs[128 * 32];
    const unsigned short* Aa = Ab + (long long)blockIdx.z * sA;
    const unsigned short* Bt = BTp + (long long)blockIdx.z * sBT;
    float* Cf = (float*)Cp + (CBF ? 0 : (long long)blockIdx.z * sC);
    unsigned short* Cb = (unsigned short*)Cp + (CBF ? (long long)blockIdx.z * sC : 0);

    int m0 = blockIdx.y * 128, n0 = blockIdx.x * 128;
    int tid = threadIdx.x;
    int srow = tid >> 1, skb = (tid & 1) * 16;
    int w = tid >> 6, l = tid & 63;
    int wr = w >> 1, wc = w & 1;
    int fr = l & 15, fk = l >> 4;
    int glr = (w << 4) + (l >> 2);     // row within 64-row half (lds dest order)
    int glc = (l & 3) << 3;            // col element
    bool fullM = (m0 + 128 <= M);
    bool fullN = (n0 + 128 <= N);

    f32x4 acc[4][4] = {};

    for (int k0 = 0; k0 < K; k0 += 32) {
        bool kedge = (k0 + 32 > K);
        if (fullM && !kedge) {
            GLOAD16(Aa + (long long)(m0 + glr) * lda + k0 + glc,      &As[w << 9]);
            GLOAD16(Aa + (long long)(m0 + 64 + glr) * lda + k0 + glc, &As[2048 + (w << 9)]);
        } else {
            int gm = m0 + srow;
            unsigned short* dst = &As[srow * 32 + skb];
#pragma unroll
            for (int i = 0; i < 16; i++) {
                int gk = k0 + skb + i;
                dst[i] = (gm < M && gk < K) ? Aa[(long long)gm * lda + gk] : (unsigned short)0;
            }
        }
        if (fullN && !kedge) {
            GLOAD16(Bt + (long long)(n0 + glr) * ldbt + k0 + glc,      &Bs[w << 9]);
            GLOAD16(Bt + (long long)(n0 + 64 + glr) * ldbt + k0 + glc, &Bs[2048 + (w << 9)]);
        } else {
            int gn = n0 + srow;
            unsigned short* dst = &Bs[srow * 32 + skb];
#pragma unroll
            for (int i = 0; i < 16; i++) {
                int gk = k0 + skb + i;
                dst[i] = (gn < N && gk < K) ? Bt[(long long)gn * ldbt + gk] : (unsigned short)0;
            }
        }
        __syncthreads();
        bf16x8 a[4], b[4];
#pragma unroll
        for (int i = 0; i < 4; i++) {
            a[i] = *(const bf16x8*)&As[(wr * 64 + i * 16 + fr) * 32 + fk * 8];
            b[i] = *(const bf16x8*)&Bs[(wc * 64 + i * 16 + fr) * 32 + fk * 8];
        }
#pragma unroll
        for (int i = 0; i < 4; i++)
#pragma unroll
            for (int j = 0; j < 4; j++)
                acc[i][j] = __builtin_amdgcn_mfma_f32_16x16x32_bf16(a[i], b[j], acc[i][j], 0, 0, 0);
        __syncthreads();
    }

#pragma unroll
    for (int i = 0; i < 4; i++) {
        int gr0 = m0 + wr * 64 + i * 16 + fk * 4;
#pragma unroll
        for (int j = 0; j < 4; j++) {
            int gc = n0 + wc * 64 + j * 16 + fr;
            if (gc >= N) continue;
            float bv = bias ? bias[gc] : 0.f;
#pragma unroll
            for (int r = 0; r < 4; r++) {
                int gr = gr0 + r;
                if (gr >= M) continue;
                float v = acc[i][j][r] + bv;
                if (ACT == 1) v = 0.5f * v * (1.f + erff(v * 0.70710678118654752f));
                long long ci = (long long)gr * ldc + gc;
                if (CBF) Cb[ci] = f2bf(v);
                else Cf[ci] = v;
            }
        }
    }
}

// ---------------- conv+silu for B/C channels, dt/dA ----------------
__global__ void convbc_kernel(const float* __restrict__ XBC, const float* __restrict__ conv_w,
                              const float* __restrict__ conv_b, const float* __restrict__ dt_bias,
                              const float* __restrict__ A_log,
                              float* __restrict__ BCb, float* __restrict__ DTb, float* __restrict__ DAb)
{
    int row = blockIdx.x;
    int b = row / SEQ, l = row - b * SEQ;
    int tid = threadIdx.x;
    if (tid < 128) {
        int ch = 512 + tid;
        float acc = conv_b[ch];
#pragma unroll
        for (int k = 0; k < 4; k++) {
            int lt = l + k - 3;
            if (lt >= 0)
                acc = fmaf(conv_w[ch * 4 + k], XBC[(long long)(b * SEQ + lt) * XBCLD + ch], acc);
        }
        BCb[(long long)row * 128 + tid] = acc * __builtin_amdgcn_rcpf(1.f + __expf(-acc));
    } else if (tid < 160) {
        int h = tid - 128;
        float draw = XBC[(long long)row * XBCLD + 640 + h] + dt_bias[h];
        float dtv = (draw > 20.f) ? draw : log1pf(__expf(draw));
        DTb[(long long)row * NH + h] = dtv;
        DAb[(long long)row * NH + h] = __expf(-__expf(A_log[h]) * dtv);
    }
}

// ---------------- selective scan v6: LDS chunk staging (bf16 x), 2 heads/wave ----------------
__device__ __forceinline__ void sstep(
    float raw, float dtv, float da,
    const float4& qb0, const float4& qb1, const float4& qb2, const float4& qb3,
    const float4& qc0, const float4& qc1, const float4& qc2, const float4& qc3,
    float cw0, float cw1, float cw2, float cw3, float cb, float ds,
    float* st, float& w0, float& w1, float& w2,
    int lane, float* __restrict__ yaddr)
{
    float cvv = cb + cw0 * w0 + cw1 * w1 + cw2 * w2 + cw3 * raw;
    float xhv = cvv * __builtin_amdgcn_rcpf(1.f + __expf(-cvv));
    w0 = w1; w1 = w2; w2 = raw;
    float xv = dtv * xhv;
    float p0, p1, p2, p3;
    st[0]  = fmaf(da, st[0],  xv * qb0.x); p0 = st[0]  * qc0.x;
    st[1]  = fmaf(da, st[1],  xv * qb0.y); p1 = st[1]  * qc0.y;
    st[2]  = fmaf(da, st[2],  xv * qb0.z); p2 = st[2]  * qc0.z;
    st[3]  = fmaf(da, st[3],  xv * qb0.w); p3 = st[3]  * qc0.w;
    st[4]  = fmaf(da, st[4],  xv * qb1.x); p0 = fmaf(st[4],  qc1.x, p0);
    st[5]  = fmaf(da, st[5],  xv * qb1.y); p1 = fmaf(st[5],  qc1.y, p1);
    st[6]  = fmaf(da, st[6],  xv * qb1.z); p2 = fmaf(st[6],  qc1.z, p2);
    st[7]  = fmaf(da, st[7],  xv * qb1.w); p3 = fmaf(st[7],  qc1.w, p3);
    st[8]  = fmaf(da, st[8],  xv * qb2.x); p0 = fmaf(st[8],  qc2.x, p0);
    st[9]  = fmaf(da, st[9],  xv * qb2.y); p1 = fmaf(st[9],  qc2.y, p1);
    st[10] = fmaf(da, st[10], xv * qb2.z); p2 = fmaf(st[10], qc2.z, p2);
    st[11] = fmaf(da, st[11], xv * qb2.w); p3 = fmaf(st[11], qc2.w, p3);
    st[12] = fmaf(da, st[12], xv * qb3.x); p0 = fmaf(st[12], qc3.x, p0);
    st[13] = fmaf(da, st[13], xv * qb3.y); p1 = fmaf(st[13], qc3.y, p1);
    st[14] = fmaf(da, st[14], xv * qb3.z); p2 = fmaf(st[14], qc3.z, p2);
    st[15] = fmaf(da, st[15], xv * qb3.w); p3 = fmaf(st[15], qc3.w, p3);
    float part = (p0 + p1) + (p2 + p3);
    part += __shfl_xor(part, 16);
    part += __shfl_xor(part, 32);
    if (lane < HD) *yaddr = part + ds * xhv;
}

__global__ __launch_bounds__(256) void scan6_kernel(
    const float* __restrict__ DTb, const float* __restrict__ DAb,
    float* __restrict__ XBC, const float* __restrict__ BCb,
    const float* __restrict__ Dsk,
    const float* __restrict__ conv_w, const float* __restrict__ conv_b)
{
    __shared__ float sbc[2][TC][128];
    __shared__ unsigned short sx[2][TC][128];
    __shared__ float sdt[SEQ][8];
    __shared__ float sda[SEQ][8];
    int tid = threadIdx.x;
    int wv = tid >> 6, lane = tid & 63;
    int bid = blockIdx.x;
    int b = bid >> 2, hq = (bid & 3) * 8;
    long long rowb = (long long)b * SEQ;

    for (int i = tid; i < SEQ * 8; i += 256) {
        int t = i >> 3, j = i & 7;
        sdt[t][j] = DTb[(rowb + t) * NH + hq + j];
        sda[t][j] = DAb[(rowb + t) * NH + hq + j];
    }
    for (int i = tid; i < TC * 32; i += 256) {
        int r = i >> 5, c = i & 31;
        ((float4*)&sbc[0][r][0])[c] = ((const float4*)(BCb + (rowb + r) * 128))[c];
    }
    for (int i = tid; i < TC * 64; i += 256) {
        int r = i >> 6, c2 = i & 63;
        float2 v = *(const float2*)(XBC + (rowb + r) * XBCLD + hq * 16 + (c2 << 1));
        *(unsigned*)&sx[0][r][c2 << 1] = (unsigned)f2bf(v.x) | ((unsigned)f2bf(v.y) << 16);
    }
    __syncthreads();

    int p = lane & 15, g = lane >> 4;
    int hA = hq + wv, hB = hq + 4 + wv;
    int chA = hA * HD + p, chB = hB * HD + p;
    float cwA0 = conv_w[chA * 4 + 0], cwA1 = conv_w[chA * 4 + 1];
    float cwA2 = conv_w[chA * 4 + 2], cwA3 = conv_w[chA * 4 + 3];
    float cbA = conv_b[chA];
    float cwB0 = conv_w[chB * 4 + 0], cwB1 = conv_w[chB * 4 + 1];
    float cwB2 = conv_w[chB * 4 + 2], cwB3 = conv_w[chB * 4 + 3];
    float cbB = conv_b[chB];
    float dsA = Dsk[hA], dsB = Dsk[hB];
    int xcA = wv * 16 + p, xcB = (4 + wv) * 16 + p;
    float* ypA = XBC + rowb * XBCLD + hA * HD + p;
    float* ypB = XBC + rowb * XBCLD + hB * HD + p;
    float stA[16], stB[16];
#pragma unroll
    for (int r = 0; r < 16; r++) { stA[r] = 0.f; stB[r] = 0.f; }
    float wA0 = 0.f, wA1 = 0.f, wA2 = 0.f;
    float wB0 = 0.f, wB1 = 0.f, wB2 = 0.f;

    for (int c = 0; c < NCH; c++) {
        int cur = c & 1;
        if (c + 1 < NCH) {
            int nb = cur ^ 1;
            long long tb = rowb + (c + 1) * TC;
            for (int i = tid; i < TC * 32; i += 256) {
                int r = i >> 5, cc = i & 31;
                ((float4*)&sbc[nb][r][0])[cc] = ((const float4*)(BCb + (tb + r) * 128))[cc];
            }
            for (int i = tid; i < TC * 64; i += 256) {
                int r = i >> 6, c2 = i & 63;
                float2 v = *(const float2*)(XBC + (tb + r) * XBCLD + hq * 16 + (c2 << 1));
                *(unsigned*)&sx[nb][r][c2 << 1] = (unsigned)f2bf(v.x) | ((unsigned)f2bf(v.y) << 16);
            }
        }
        int tbase = c * TC;
        for (int t = 0; t < TC; t++) {
            int gt = tbase + t;
            const float4* qb = (const float4*)&sbc[cur][t][g * 16];
            const float4* qc = (const float4*)&sbc[cur][t][64 + g * 16];
            float4 qb0 = qb[0], qb1 = qb[1], qb2 = qb[2], qb3 = qb[3];
            float4 qc0 = qc[0], qc1 = qc[1], qc2 = qc[2], qc3 = qc[3];
            float rawA = bf2f(sx[cur][t][xcA]);
            float rawB = bf2f(sx[cur][t][xcB]);
            sstep(rawA, sdt[gt][wv], sda[gt][wv], qb0, qb1, qb2, qb3, qc0, qc1, qc2, qc3,
                  cwA0, cwA1, cwA2, cwA3, cbA, dsA, stA, wA0, wA1, wA2,
                  lane, ypA + (long long)gt * XBCLD);
            sstep(rawB, sdt[gt][4 + wv], sda[gt][4 + wv], qb0, qb1, qb2, qb3, qc0, qc1, qc2, qc3,
                  cwB0, cwB1, cwB2, cwB3, cbB, dsB, stB, wB0, wB1, wB2,
                  lane, ypB + (long long)gt * XBCLD);
        }
        __syncthreads();
    }
}

// ---------------- gate: G = rmsnorm(y * silu(z)) * w  (bf16 out, in-place) ----------------
__global__ __launch_bounds__(256) void gate_kernel(
    float* __restrict__ XBC, const unsigned short* __restrict__ Zbf,
    const float* __restrict__ rms_w)
{
    int row = blockIdx.x * 4 + (threadIdx.x >> 6);
    int lane = threadIdx.x & 63;
    float* yrow = XBC + (long long)row * XBCLD + lane * 8;
    const unsigned short* zrow = Zbf + (long long)row * 512 + lane * 8;
    float4 y0 = ((const float4*)yrow)[0];
    float4 y1 = ((const float4*)yrow)[1];
    uint4 zq = ((const uint4*)zrow)[0];
    float yv[8] = { y0.x, y0.y, y0.z, y0.w, y1.x, y1.y, y1.z, y1.w };
    float zv[8];
    zv[0] = bf2f((unsigned short)(zq.x & 0xFFFF)); zv[1] = bf2f((unsigned short)(zq.x >> 16));
    zv[2] = bf2f((unsigned short)(zq.y & 0xFFFF)); zv[3] = bf2f((unsigned short)(zq.y >> 16));
    zv[4] = bf2f((unsigned short)(zq.z & 0xFFFF)); zv[5] = bf2f((unsigned short)(zq.z >> 16));
    zv[6] = bf2f((unsigned short)(zq.w & 0xFFFF)); zv[7] = bf2f((unsigned short)(zq.w >> 16));
    float a[8]; float ss = 0.f;
#pragma unroll
    for (int i = 0; i < 8; i++) {
        float z = zv[i];
        a[i] = yv[i] * (z * __builtin_amdgcn_rcpf(1.f + __expf(-z)));
        ss = fmaf(a[i], a[i], ss);
    }
#pragma unroll
    for (int m = 1; m < 64; m <<= 1) ss += __shfl_xor(ss, m);
    float sc = rsqrtf(ss * (1.f / 512.f) + 1e-5f);
    const float* rw = rms_w + lane * 8;
    float4 r0 = ((const float4*)rw)[0];
    float4 r1 = ((const float4*)rw)[1];
    float rv[8] = { r0.x, r0.y, r0.z, r0.w, r1.x, r1.y, r1.z, r1.w };
    uint4 o;
    o.x = (unsigned)f2bf(a[0] * sc * rv[0]) | ((unsigned)f2bf(a[1] * sc * rv[1]) << 16);
    o.y = (unsigned)f2bf(a[2] * sc * rv[2]) | ((unsigned)f2bf(a[3] * sc * rv[3]) << 16);
    o.z = (unsigned)f2bf(a[4] * sc * rv[4]) | ((unsigned)f2bf(a[5] * sc * rv[5]) << 16);
    o.w = (unsigned)f2bf(a[6] * sc * rv[6]) | ((unsigned)f2bf(a[7] * sc * rv[7]) << 16);
    unsigned short* grow = (unsigned short*)(XBC + (long long)row * XBCLD);
    ((uint4*)grow)[lane] = o;
}

// ---------------- LayerNorm(a+b)*g+be (f32,f32) ----------------
__global__ void lnadd_kernel(const float* __restrict__ A, const float* __restrict__ Bb,
                             const float* __restrict__ g, const float* __restrict__ be,
                             float* __restrict__ O)
{
    int row = blockIdx.x * 4 + (threadIdx.x >> 6);
    int lane = threadIdx.x & 63;
    long long base = (long long)row * DMODEL + lane * 4;
    float v[4]; float s1 = 0.f;
#pragma unroll
    for (int i = 0; i < 4; i++) { float a = A[base + i] + Bb[base + i]; v[i] = a; s1 += a; }
#pragma unroll
    for (int m = 1; m < 64; m <<= 1) s1 += __shfl_xor(s1, m);
    float mean = s1 * (1.f / 256.f);
    float s2 = 0.f;
#pragma unroll
    for (int i = 0; i < 4; i++) { float d = v[i] - mean; s2 = fmaf(d, d, s2); }
#pragma unroll
    for (int m = 1; m < 64; m <<= 1) s2 += __shfl_xor(s2, m);
    float r = rsqrtf(s2 * (1.f / 256.f) + 1e-12f);
#pragma unroll
    for (int i = 0; i < 4; i++)
        O[base + i] = (v[i] - mean) * r * g[lane * 4 + i] + be[lane * 4 + i];
}

// ---------------- LayerNorm(bf16 a + f32 b)*g+be -> f32 ----------------
__global__ void lnadd_bf_kernel(const unsigned short* __restrict__ A, const float* __restrict__ Bb,
                                const float* __restrict__ g, const float* __restrict__ be,
                                float* __restrict__ O)
{
    int row = blockIdx.x * 4 + (threadIdx.x >> 6);
    int lane = threadIdx.x & 63;
    long long base = (long long)row * DMODEL + lane * 4;
    float v[4]; float s1 = 0.f;
#pragma unroll
    for (int i = 0; i < 4; i++) { float a = bf2f(A[base + i]) + Bb[base + i]; v[i] = a; s1 += a; }
#pragma unroll
    for (int m = 1; m < 64; m <<= 1) s1 += __shfl_xor(s1, m);
    float mean = s1 * (1.f / 256.f);
    float s2 = 0.f;
#pragma unroll
    for (int i = 0; i < 4; i++) { float d = v[i] - mean; s2 = fmaf(d, d, s2); }
#pragma unroll
    for (int m = 1; m < 64; m <<= 1) s2 += __shfl_xor(s2, m);
    float r = rsqrtf(s2 * (1.f / 256.f) + 1e-12f);
#pragma unroll
    for (int i = 0; i < 4; i++)
        O[base + i] = (v[i] - mean) * r * g[lane * 4 + i] + be[lane * 4 + i];
}

// ---------------- combine: H1 = alpha*H1 + beta*LN(XI + X); also write bf16 copy ----------------
__global__ void combine_kernel(const float* __restrict__ XI, const float* __restrict__ X,
                               float* __restrict__ H1, unsigned short* __restrict__ HB,
                               const float* __restrict__ fg, const float* __restrict__ fb,
                               const float* __restrict__ al, const float* __restrict__ bt)
{
    int row = blockIdx.x * 4 + (threadIdx.x >> 6);
    int lane = threadIdx.x & 63;
    long long base = (long long)row * DMODEL + lane * 4;
    float v[4]; float s1 = 0.f;
#pragma unroll
    for (int i = 0; i < 4; i++) { float a = XI[base + i] + X[base + i]; v[i] = a; s1 += a; }
#pragma unroll
    for (int m = 1; m < 64; m <<= 1) s1 += __shfl_xor(s1, m);
    float mean = s1 * (1.f / 256.f);
    float s2 = 0.f;
#pragma unroll
    for (int i = 0; i < 4; i++) { float d = v[i] - mean; s2 = fmaf(d, d, s2); }
#pragma unroll
    for (int m = 1; m < 64; m <<= 1) s2 += __shfl_xor(s2, m);
    float r = rsqrtf(s2 * (1.f / 256.f) + 1e-12f);
#pragma unroll
    for (int i = 0; i < 4; i++) {
        float h2 = (v[i] - mean) * r * fg[lane * 4 + i] + fb[lane * 4 + i];
        float h = al[lane * 4 + i] * H1[base + i] + bt[lane * 4 + i] * h2;
        H1[base + i] = h;
        HB[base + i] = f2bf(h);
    }
}

// ---------------- pointwise spectral filter on XFT[b][d][j] bf16 (ld 208) ----------------
__global__ void filt_kernel(unsigned short* __restrict__ XF, const float* __restrict__ W)
{
    long long idx = (long long)blockIdx.x * 256 + threadIdx.x;
    if (idx >= (long long)BATCHN * DMODEL * NF) return;
    int f = (int)(idx % NF);
    int d = (int)((idx / NF) % DMODEL);
    int b = (int)(idx / ((long long)NF * DMODEL));
    long long base = ((long long)b * DMODEL + d) * NJP;
    float re = bf2f(XF[base + f]);
    float im = bf2f(XF[base + 101 + f]);
    float wr = W[((long long)f * DMODEL + d) * 2];
    float wi = W[((long long)f * DMODEL + d) * 2 + 1];
    XF[base + f]       = f2bf(re * wr - im * wi);
    XF[base + 101 + f] = f2bf(re * wi + im * wr);
}

extern "C" void kernel_launch(void* const* d_in, const int* in_sizes, int n_in,
                              void* d_out, int out_size, void* d_ws, size_t ws_size,
                              hipStream_t stream)
{
    const float* x          = (const float*)d_in[0];
    const float* in_proj_w  = (const float*)d_in[1];
    const float* conv_w     = (const float*)d_in[2];
    const float* conv_b     = (const float*)d_in[3];
    const float* dt_bias    = (const float*)d_in[4];
    const float* A_log      = (const float*)d_in[5];
    const float* D_skip     = (const float*)d_in[6];
    const float* rms_w      = (const float*)d_in[7];
    const float* out_proj_w = (const float*)d_in[8];
    const float* ln_g       = (const float*)d_in[9];
    const float* ln_b       = (const float*)d_in[10];
    const float* filt_w     = (const float*)d_in[11];
    const float* filt_ln_g  = (const float*)d_in[12];
    const float* filt_ln_b  = (const float*)d_in[13];
    const float* alpha      = (const float*)d_in[14];
    const float* beta       = (const float*)d_in[15];
    const float* ffn_w1     = (const float*)d_in[16];
    const float* ffn_b1     = (const float*)d_in[17];
    const float* ffn_w2     = (const float*)d_in[18];
    const float* ffn_b2     = (const float*)d_in[19];
    const float* ffn_ln_g   = (const float*)d_in[20];
    const float* ffn_ln_b   = (const float*)d_in[21];
    float* out = (float*)d_out;
    float* ws = (float*)d_ws;

    // weights arena [81920 .. XBASE)
    unsigned short* WP   = (unsigned short*)(ws + 81920);
    unsigned short* ipwT = WP;                  // 672*256
    unsigned short* opwT = ipwT + 672 * 256;    // 256*512
    unsigned short* w1T  = opwT + 256 * 512;    // 1024*256
    unsigned short* w2T  = w1T + 1024 * 256;    // 256*1024
    unsigned short* zwT  = w2T + 256 * 1024;    // 512*256
    unsigned short* EFbf = zwT + 512 * 256;     // 202*200
    unsigned short* EIbf = EFbf + NJ * SEQ;     // 200*208
    float* XBC = ws + XBASE;                    // BL*672 f32 arena
    float* BCb = XBC + (long long)BL * XBCLD;   // BL*128
    float* DTb = BCb + (long long)BL * 128;     // BL*32
    float* DAb = DTb + (long long)BL * NH;      // BL*32
    float* MO  = DAb + (long long)BL * NH;      // BL*256 (h1/H)
    unsigned short* Zbf = (unsigned short*)MO;  // BL*512 bf16, lifetime [zproj..gate]
    // BCb region reuse (BL*128 f32 == BL*256 bf16):
    unsigned short* xbf  = (unsigned short*)BCb; // bf16 x, lifetime [f2bf..zproj]
    unsigned short* xTbf = (unsigned short*)BCb; // post-scan, lifetime [xT..FFT fwd]
    unsigned short* MObf = (unsigned short*)BCb; // post-FFT, lifetime [combine..FFN1]
    // XBC arena reuse:
    unsigned short* Gbf = (unsigned short*)XBC;              // bf16 G in place, ld 1344
    unsigned short* XFT = (unsigned short*)XBC;              // 256*256*208 bf16
    float* XI  = XBC + 7000000;                              // BL*256 f32
    unsigned short* HID = (unsigned short*)XBC;              // BL*1024 bf16
    unsigned short* FFO = (unsigned short*)(XBC + 26500000); // BL*256 bf16

    // 1. DFT matrices + weight packs + x->bf16
    init_dft_kernel<<<dim3((NJ * SEQ + SEQ * NJP + 255) / 256), dim3(256), 0, stream>>>(EFbf, EIbf);
    pack_wT_kernel<<<dim3((672 * 256 + 255) / 256), dim3(256), 0, stream>>>(in_proj_w, ipwT, DINPROJ, 512, 672, 256);
    pack_wT_kernel<<<dim3((512 * 256 + 255) / 256), dim3(256), 0, stream>>>(in_proj_w, zwT, DINPROJ, 0, 512, 256);
    pack_wT_kernel<<<dim3((256 * 512 + 255) / 256), dim3(256), 0, stream>>>(out_proj_w, opwT, 256, 0, 256, 512);
    pack_wT_kernel<<<dim3((1024 * 256 + 255) / 256), dim3(256), 0, stream>>>(ffn_w1, w1T, 1024, 0, 1024, 256);
    pack_wT_kernel<<<dim3((256 * 1024 + 255) / 256), dim3(256), 0, stream>>>(ffn_w2, w2T, 256, 0, 256, 1024);
    f2bf_kernel<<<dim3(BL * DMODEL / 2048), dim3(256), 0, stream>>>(x, xbf);

    // 2. in_proj (xBC+dt cols): xbf[BL,256] @ ipwT^T -> XBC f32 (ld 672)
    mgemm_kernel<0,0><<<dim3(6, BL / 128, 1), dim3(256), 0, stream>>>(
        xbf, ipwT, XBC, nullptr, BL, 672, 256, 256, 256, 672, 0, 0, 0);

    // 2b. z projection: xbf @ zwT^T -> Zbf bf16 (aliases MO)
    mgemm_kernel<0,1><<<dim3(4, BL / 128, 1), dim3(256), 0, stream>>>(
        xbf, zwT, Zbf, nullptr, BL, 512, 256, 256, 256, 512, 0, 0, 0);

    // 3. conv+silu B/C; dt -> DT/DA (clobbers xbf region: xbf dead)
    convbc_kernel<<<dim3(BL), dim3(192), 0, stream>>>(XBC, conv_w, conv_b, dt_bias, A_log,
                                                      BCb, DTb, DAb);

    // 4. scan v6 (bf16 x staging, 3 blocks/CU), y in place f32
    scan6_kernel<<<dim3(BATCHN * 4), dim3(256), 0, stream>>>(DTb, DAb, XBC, BCb, D_skip,
                                                             conv_w, conv_b);

    // 4.5 x transpose -> xTbf (BCb dead after scan)
    xT_kernel<<<dim3(7, 8, BATCHN), dim3(256), 0, stream>>>(x, xTbf);

    // 5. gate -> Gbf bf16 in place
    gate_kernel<<<dim3(BL / 4), dim3(256), 0, stream>>>(XBC, Zbf, rms_w);

    // 6. out_proj: Gbf[BL,512](ld 1344) @ opwT^T -> MO f32 (Zbf dead)
    mgemm_kernel<0,0><<<dim3(2, BL / 128, 1), dim3(256), 0, stream>>>(
        Gbf, opwT, MO, nullptr, BL, 256, 512, 1344, 512, 256, 0, 0, 0);

    // 7. h1 = LN(MO + x) in place
    lnadd_kernel<<<dim3(BL / 4), dim3(256), 0, stream>>>(MO, x, ln_g, ln_b, MO);

    // 8. FFT fwd: XFT[b][256,202] = xTbf[b][256,200] @ EFbf^T, bf16 out (ld 208)
    mgemm_kernel<0,1><<<dim3(2, 2, BATCHN), dim3(256), 0, stream>>>(
        xTbf, EFbf, XFT, nullptr, 256, NJ, SEQ, SEQ, SEQ, NJP,
        (long long)DMODEL * SEQ, 0, (long long)DMODEL * NJP);

    // 9. spectral filter in place
    filt_kernel<<<dim3((BATCHN * DMODEL * NF + 255) / 256), dim3(256), 0, stream>>>(XFT, filt_w);

    // 10. FFT inv: XI[b][200,256] = EIbf[200,202] @ XFT[b]^T, f32 out
    mgemm_kernel<0,0><<<dim3(2, 2, BATCHN), dim3(256), 0, stream>>>(
        EIbf, XFT, XI, nullptr, SEQ, DMODEL, NJ, NJP, NJP, DMODEL,
        0, (long long)DMODEL * NJP, (long long)SEQ * DMODEL);

    // 11. combine: MO = alpha*h1 + beta*LN(XI + x); MObf = bf16(MO) (xTbf dead)
    combine_kernel<<<dim3(BL / 4), dim3(256), 0, stream>>>(XI, x, MO, MObf,
                                                           filt_ln_g, filt_ln_b, alpha, beta);

    // 12. FFN1: MObf[BL,256] @ w1T^T + b1, GELU -> HID bf16
    mgemm_kernel<1,1><<<dim3(8, BL / 128, 1), dim3(256), 0, stream>>>(
        MObf, w1T, HID, ffn_b1, BL, 1024, 256, 256, 256, 1024, 0, 0, 0);

    // 13. FFN2: HID[BL,1024] @ w2T^T + b2 -> FFO bf16
    mgemm_kernel<0,1><<<dim3(2, BL / 128, 1), dim3(256), 0, stream>>>(
        HID, w2T, FFO, ffn_b2, BL, 256, 1024, 1024, 1024, 256, 0, 0, 0);

    // 14. out = LN(FFO + MO)
    lnadd_bf_kernel<<<dim3(BL / 4), dim3(256), 0, stream>>>(FFO, MO, ffn_ln_g, ffn_ln_b, out);
}

// Round 9
// 859.917 us; speedup vs baseline: 5.4317x; 1.1286x over previous
//
#include <hip/hip_runtime.h>
#include <math.h>

#define BATCHN 256
#define SEQ 200
#define DMODEL 256
#define DINNER 512
#define NH 32
#define HD 16
#define DSTATE 64
#define DINPROJ 1184
#define XBCLD 672
#define BL (BATCHN*SEQ)   // 51200
#define NF 101
#define NJ 202
#define XBASE 655360
#define TC 20
#define NCH 10
#define XIOFF 8500000     // f32 offset of XI within XBC arena

typedef __attribute__((ext_vector_type(8))) short bf16x8;
typedef __attribute__((ext_vector_type(4))) float f32x4;

__device__ inline unsigned short f2bf(float f) {
    union { float f; unsigned u; } v; v.f = f;
    unsigned r = v.u + 0x7FFFu + ((v.u >> 16) & 1u);
    return (unsigned short)(r >> 16);
}
__device__ inline float bf2f(unsigned short h) {
    union { unsigned u; float f; } v; v.u = ((unsigned)h) << 16;
    return v.f;
}

#define GLOAD16(src, dst) __builtin_amdgcn_global_load_lds( \
    (const __attribute__((address_space(1))) void*)(src),   \
    (__attribute__((address_space(3))) void*)(dst), 16, 0, 0)

// ---------------- DFT matrices (bf16, padded to 256) ----------------
// EF [256][200]: rows 0..100 cos, 101..201 -sin, 202..255 zero  (B^T for fwd)
// EI [256][256]: row t, col j; rows>=200 zero, cols>=202 zero
__global__ void init_dft_kernel(unsigned short* __restrict__ EF, unsigned short* __restrict__ EI)
{
    const float ang = 6.28318530717958647692f / 200.0f;
    int idx = blockIdx.x * 256 + threadIdx.x;
    if (idx < 256 * SEQ) {
        int f = idx / SEQ, t = idx - f * SEQ;
        float v;
        if (f <= 100) { int ph = (f * t) % 200; v = cosf(ang * (float)ph); }
        else if (f <= 201) { int ff = f - 101; int ph = (ff * t) % 200; v = -sinf(ang * (float)ph); }
        else v = 0.f;
        EF[idx] = f2bf(v);
    } else if (idx < 256 * SEQ + 256 * 256) {
        int j2 = idx - 256 * SEQ;
        int t = j2 >> 8, j = j2 & 255;
        float v;
        if (t >= 200) v = 0.f;
        else if (j == 0) v = 1.0f / 200.0f;
        else if (j == 100) v = ((t & 1) ? -1.0f : 1.0f) / 200.0f;
        else if (j < 100) { int ph = (j * t) % 200; v = 2.0f * cosf(ang * (float)ph) / 200.0f; }
        else if (j >= 202 || j == 101 || j == 201) v = 0.0f;
        else { int f = j - 101; int ph = (f * t) % 200; v = -2.0f * sinf(ang * (float)ph) / 200.0f; }
        EI[j2] = f2bf(v);
    }
}

// ---------------- weight pack: dst[n][k] = bf16(src[k][coloff+n]) ----------------
__global__ void pack_wT_kernel(const float* __restrict__ src, unsigned short* __restrict__ dst,
                               int srcld, int coloff, int N, int K)
{
    int idx = blockIdx.x * 256 + threadIdx.x;
    if (idx >= N * K) return;
    int n = idx / K, k = idx - n * K;
    dst[idx] = f2bf(src[(long long)k * srcld + coloff + n]);
}

// ---------------- f32 -> bf16 bulk convert (n multiple of 2048) ----------------
__global__ void f2bf_kernel(const float* __restrict__ X, unsigned short* __restrict__ O)
{
    long long i = ((long long)blockIdx.x * 256 + threadIdx.x) * 8;
    float4 a = ((const float4*)(X + i))[0];
    float4 b = ((const float4*)(X + i))[1];
    uint4 o;
    o.x = (unsigned)f2bf(a.x) | ((unsigned)f2bf(a.y) << 16);
    o.y = (unsigned)f2bf(a.z) | ((unsigned)f2bf(a.w) << 16);
    o.z = (unsigned)f2bf(b.x) | ((unsigned)f2bf(b.y) << 16);
    o.w = (unsigned)f2bf(b.z) | ((unsigned)f2bf(b.w) << 16);
    *(uint4*)(O + i) = o;
}

// ---------------- x transpose: xT[b][d][t] = bf16(x[b][t][d]) ----------------
__global__ void xT_kernel(const float* __restrict__ X, unsigned short* __restrict__ XT)
{
    __shared__ float tile[32][33];
    int b = blockIdx.z, t0 = blockIdx.x * 32, d0 = blockIdx.y * 32;
    int tx = threadIdx.x & 31, ty = threadIdx.x >> 5;
    const float* xb = X + (long long)b * SEQ * DMODEL;
#pragma unroll
    for (int i = 0; i < 4; i++) {
        int t = t0 + ty + i * 8;
        tile[ty + i * 8][tx] = (t < SEQ) ? xb[(long long)t * DMODEL + d0 + tx] : 0.f;
    }
    __syncthreads();
    unsigned short* xtb = XT + (long long)b * DMODEL * SEQ;
#pragma unroll
    for (int i = 0; i < 4; i++) {
        int d = d0 + ty + i * 8;
        int t = t0 + tx;
        if (t < SEQ) xtb[(long long)d * SEQ + t] = f2bf(tile[tx][ty + i * 8]);
    }
}

// ---------------- bf16 MFMA GEMM: global_load_lds, linear LDS ----------------
template<int ACT, int CBF>
__global__ __launch_bounds__(256) void mgemm_kernel(
    const unsigned short* __restrict__ Ab, const unsigned short* __restrict__ BTp,
    void* __restrict__ Cp, const float* __restrict__ bias,
    int M, int N, int K, int lda, int ldbt, int ldc,
    long long sA, long long sBT, long long sC)
{
    __shared__ unsigned short As[128 * 32];
    __shared__ unsigned short Bs[128 * 32];
    const unsigned short* Aa = Ab + (long long)blockIdx.z * sA;
    const unsigned short* Bt = BTp + (long long)blockIdx.z * sBT;
    float* Cf = (float*)Cp + (CBF ? 0 : (long long)blockIdx.z * sC);
    unsigned short* Cb = (unsigned short*)Cp + (CBF ? (long long)blockIdx.z * sC : 0);

    int m0 = blockIdx.y * 128, n0 = blockIdx.x * 128;
    int tid = threadIdx.x;
    int srow = tid >> 1, skb = (tid & 1) * 16;
    int w = tid >> 6, l = tid & 63;
    int wr = w >> 1, wc = w & 1;
    int fr = l & 15, fk = l >> 4;
    int glr = (w << 4) + (l >> 2);
    int glc = (l & 3) << 3;
    bool fullM = (m0 + 128 <= M);
    bool fullN = (n0 + 128 <= N);

    f32x4 acc[4][4] = {};

    for (int k0 = 0; k0 < K; k0 += 32) {
        bool kedge = (k0 + 32 > K);
        if (fullM && !kedge) {
            GLOAD16(Aa + (long long)(m0 + glr) * lda + k0 + glc,      &As[w << 9]);
            GLOAD16(Aa + (long long)(m0 + 64 + glr) * lda + k0 + glc, &As[2048 + (w << 9)]);
        } else {
            int gm = m0 + srow;
            unsigned short* dst = &As[srow * 32 + skb];
#pragma unroll
            for (int i = 0; i < 16; i++) {
                int gk = k0 + skb + i;
                dst[i] = (gm < M && gk < K) ? Aa[(long long)gm * lda + gk] : (unsigned short)0;
            }
        }
        if (fullN && !kedge) {
            GLOAD16(Bt + (long long)(n0 + glr) * ldbt + k0 + glc,      &Bs[w << 9]);
            GLOAD16(Bt + (long long)(n0 + 64 + glr) * ldbt + k0 + glc, &Bs[2048 + (w << 9)]);
        } else {
            int gn = n0 + srow;
            unsigned short* dst = &Bs[srow * 32 + skb];
#pragma unroll
            for (int i = 0; i < 16; i++) {
                int gk = k0 + skb + i;
                dst[i] = (gn < N && gk < K) ? Bt[(long long)gn * ldbt + gk] : (unsigned short)0;
            }
        }
        __syncthreads();
        bf16x8 a[4], b[4];
#pragma unroll
        for (int i = 0; i < 4; i++) {
            a[i] = *(const bf16x8*)&As[(wr * 64 + i * 16 + fr) * 32 + fk * 8];
            b[i] = *(const bf16x8*)&Bs[(wc * 64 + i * 16 + fr) * 32 + fk * 8];
        }
#pragma unroll
        for (int i = 0; i < 4; i++)
#pragma unroll
            for (int j = 0; j < 4; j++)
                acc[i][j] = __builtin_amdgcn_mfma_f32_16x16x32_bf16(a[i], b[j], acc[i][j], 0, 0, 0);
        __syncthreads();
    }

#pragma unroll
    for (int i = 0; i < 4; i++) {
        int gr0 = m0 + wr * 64 + i * 16 + fk * 4;
#pragma unroll
        for (int j = 0; j < 4; j++) {
            int gc = n0 + wc * 64 + j * 16 + fr;
            if (gc >= N) continue;
            float bv = bias ? bias[gc] : 0.f;
#pragma unroll
            for (int r = 0; r < 4; r++) {
                int gr = gr0 + r;
                if (gr >= M) continue;
                float v = acc[i][j][r] + bv;
                if (ACT == 1) v = 0.5f * v * (1.f + erff(v * 0.70710678118654752f));
                long long ci = (long long)gr * ldc + gc;
                if (CBF) Cb[ci] = f2bf(v);
                else Cf[ci] = v;
            }
        }
    }
}

// ---------------- conv+silu for B/C channels, dt/dA ----------------
__global__ void convbc_kernel(const float* __restrict__ XBC, const float* __restrict__ conv_w,
                              const float* __restrict__ conv_b, const float* __restrict__ dt_bias,
                              const float* __restrict__ A_log,
                              float* __restrict__ BCb, float* __restrict__ DTb, float* __restrict__ DAb)
{
    int row = blockIdx.x;
    int b = row / SEQ, l = row - b * SEQ;
    int tid = threadIdx.x;
    if (tid < 128) {
        int ch = 512 + tid;
        float acc = conv_b[ch];
#pragma unroll
        for (int k = 0; k < 4; k++) {
            int lt = l + k - 3;
            if (lt >= 0)
                acc = fmaf(conv_w[ch * 4 + k], XBC[(long long)(b * SEQ + lt) * XBCLD + ch], acc);
        }
        BCb[(long long)row * 128 + tid] = acc * __builtin_amdgcn_rcpf(1.f + __expf(-acc));
    } else if (tid < 160) {
        int h = tid - 128;
        float draw = XBC[(long long)row * XBCLD + 640 + h] + dt_bias[h];
        float dtv = (draw > 20.f) ? draw : log1pf(__expf(draw));
        DTb[(long long)row * NH + h] = dtv;
        DAb[(long long)row * NH + h] = __expf(-__expf(A_log[h]) * dtv);
    }
}

// ---------------- selective scan v7: TC=20, chunked dt/da, 4 blocks/CU ----------------
__device__ __forceinline__ void sstep(
    float raw, float dtv, float da,
    const float4& qb0, const float4& qb1, const float4& qb2, const float4& qb3,
    const float4& qc0, const float4& qc1, const float4& qc2, const float4& qc3,
    float cw0, float cw1, float cw2, float cw3, float cb, float ds,
    float* st, float& w0, float& w1, float& w2,
    int lane, float* __restrict__ yaddr)
{
    float cvv = cb + cw0 * w0 + cw1 * w1 + cw2 * w2 + cw3 * raw;
    float xhv = cvv * __builtin_amdgcn_rcpf(1.f + __expf(-cvv));
    w0 = w1; w1 = w2; w2 = raw;
    float xv = dtv * xhv;
    float p0, p1, p2, p3;
    st[0]  = fmaf(da, st[0],  xv * qb0.x); p0 = st[0]  * qc0.x;
    st[1]  = fmaf(da, st[1],  xv * qb0.y); p1 = st[1]  * qc0.y;
    st[2]  = fmaf(da, st[2],  xv * qb0.z); p2 = st[2]  * qc0.z;
    st[3]  = fmaf(da, st[3],  xv * qb0.w); p3 = st[3]  * qc0.w;
    st[4]  = fmaf(da, st[4],  xv * qb1.x); p0 = fmaf(st[4],  qc1.x, p0);
    st[5]  = fmaf(da, st[5],  xv * qb1.y); p1 = fmaf(st[5],  qc1.y, p1);
    st[6]  = fmaf(da, st[6],  xv * qb1.z); p2 = fmaf(st[6],  qc1.z, p2);
    st[7]  = fmaf(da, st[7],  xv * qb1.w); p3 = fmaf(st[7],  qc1.w, p3);
    st[8]  = fmaf(da, st[8],  xv * qb2.x); p0 = fmaf(st[8],  qc2.x, p0);
    st[9]  = fmaf(da, st[9],  xv * qb2.y); p1 = fmaf(st[9],  qc2.y, p1);
    st[10] = fmaf(da, st[10], xv * qb2.z); p2 = fmaf(st[10], qc2.z, p2);
    st[11] = fmaf(da, st[11], xv * qb2.w); p3 = fmaf(st[11], qc2.w, p3);
    st[12] = fmaf(da, st[12], xv * qb3.x); p0 = fmaf(st[12], qc3.x, p0);
    st[13] = fmaf(da, st[13], xv * qb3.y); p1 = fmaf(st[13], qc3.y, p1);
    st[14] = fmaf(da, st[14], xv * qb3.z); p2 = fmaf(st[14], qc3.z, p2);
    st[15] = fmaf(da, st[15], xv * qb3.w); p3 = fmaf(st[15], qc3.w, p3);
    float part = (p0 + p1) + (p2 + p3);
    part += __shfl_xor(part, 16);
    part += __shfl_xor(part, 32);
    if (lane < HD) *yaddr = part + ds * xhv;
}

__global__ __launch_bounds__(256) void scan7_kernel(
    const float* __restrict__ DTb, const float* __restrict__ DAb,
    float* __restrict__ XBC, const float* __restrict__ BCb,
    const float* __restrict__ Dsk,
    const float* __restrict__ conv_w, const float* __restrict__ conv_b)
{
    __shared__ float sbc[2][TC][128];
    __shared__ unsigned short sx[2][TC][128];
    __shared__ float sdt[2][TC][8];
    __shared__ float sda[2][TC][8];
    int tid = threadIdx.x;
    int wv = tid >> 6, lane = tid & 63;
    int bid = blockIdx.x;
    int b = bid >> 2, hq = (bid & 3) * 8;
    long long rowb = (long long)b * SEQ;

    // stage chunk 0
    for (int i = tid; i < TC * 32; i += 256) {
        int r = i >> 5, c = i & 31;
        ((float4*)&sbc[0][r][0])[c] = ((const float4*)(BCb + (rowb + r) * 128))[c];
    }
    for (int i = tid; i < TC * 64; i += 256) {
        int r = i >> 6, c2 = i & 63;
        float2 v = *(const float2*)(XBC + (rowb + r) * XBCLD + hq * 16 + (c2 << 1));
        *(unsigned*)&sx[0][r][c2 << 1] = (unsigned)f2bf(v.x) | ((unsigned)f2bf(v.y) << 16);
    }
    for (int i = tid; i < TC * 8; i += 256) {
        int t = i >> 3, j = i & 7;
        sdt[0][t][j] = DTb[(rowb + t) * NH + hq + j];
        sda[0][t][j] = DAb[(rowb + t) * NH + hq + j];
    }
    __syncthreads();

    int p = lane & 15, g = lane >> 4;
    int hA = hq + wv, hB = hq + 4 + wv;
    int chA = hA * HD + p, chB = hB * HD + p;
    float cwA0 = conv_w[chA * 4 + 0], cwA1 = conv_w[chA * 4 + 1];
    float cwA2 = conv_w[chA * 4 + 2], cwA3 = conv_w[chA * 4 + 3];
    float cbA = conv_b[chA];
    float cwB0 = conv_w[chB * 4 + 0], cwB1 = conv_w[chB * 4 + 1];
    float cwB2 = conv_w[chB * 4 + 2], cwB3 = conv_w[chB * 4 + 3];
    float cbB = conv_b[chB];
    float dsA = Dsk[hA], dsB = Dsk[hB];
    int xcA = wv * 16 + p, xcB = (4 + wv) * 16 + p;
    float* ypA = XBC + rowb * XBCLD + hA * HD + p;
    float* ypB = XBC + rowb * XBCLD + hB * HD + p;
    float stA[16], stB[16];
#pragma unroll
    for (int r = 0; r < 16; r++) { stA[r] = 0.f; stB[r] = 0.f; }
    float wA0 = 0.f, wA1 = 0.f, wA2 = 0.f;
    float wB0 = 0.f, wB1 = 0.f, wB2 = 0.f;

    for (int c = 0; c < NCH; c++) {
        int cur = c & 1;
        if (c + 1 < NCH) {
            int nb = cur ^ 1;
            long long tb = rowb + (c + 1) * TC;
            for (int i = tid; i < TC * 32; i += 256) {
                int r = i >> 5, cc = i & 31;
                ((float4*)&sbc[nb][r][0])[cc] = ((const float4*)(BCb + (tb + r) * 128))[cc];
            }
            for (int i = tid; i < TC * 64; i += 256) {
                int r = i >> 6, c2 = i & 63;
                float2 v = *(const float2*)(XBC + (tb + r) * XBCLD + hq * 16 + (c2 << 1));
                *(unsigned*)&sx[nb][r][c2 << 1] = (unsigned)f2bf(v.x) | ((unsigned)f2bf(v.y) << 16);
            }
            for (int i = tid; i < TC * 8; i += 256) {
                int t = i >> 3, j = i & 7;
                sdt[nb][t][j] = DTb[(tb + t) * NH + hq + j];
                sda[nb][t][j] = DAb[(tb + t) * NH + hq + j];
            }
        }
        int tbase = c * TC;
        for (int t = 0; t < TC; t++) {
            int gt = tbase + t;
            const float4* qb = (const float4*)&sbc[cur][t][g * 16];
            const float4* qc = (const float4*)&sbc[cur][t][64 + g * 16];
            float4 qb0 = qb[0], qb1 = qb[1], qb2 = qb[2], qb3 = qb[3];
            float4 qc0 = qc[0], qc1 = qc[1], qc2 = qc[2], qc3 = qc[3];
            float rawA = bf2f(sx[cur][t][xcA]);
            float rawB = bf2f(sx[cur][t][xcB]);
            sstep(rawA, sdt[cur][t][wv], sda[cur][t][wv], qb0, qb1, qb2, qb3, qc0, qc1, qc2, qc3,
                  cwA0, cwA1, cwA2, cwA3, cbA, dsA, stA, wA0, wA1, wA2,
                  lane, ypA + (long long)gt * XBCLD);
            sstep(rawB, sdt[cur][t][4 + wv], sda[cur][t][4 + wv], qb0, qb1, qb2, qb3, qc0, qc1, qc2, qc3,
                  cwB0, cwB1, cwB2, cwB3, cbB, dsB, stB, wB0, wB1, wB2,
                  lane, ypB + (long long)gt * XBCLD);
        }
        __syncthreads();
    }
}

// ---------------- gate: G = rmsnorm(y * silu(z)) * w  (bf16 out, in-place) ----------------
__global__ __launch_bounds__(256) void gate_kernel(
    float* __restrict__ XBC, const unsigned short* __restrict__ Zbf,
    const float* __restrict__ rms_w)
{
    int row = blockIdx.x * 4 + (threadIdx.x >> 6);
    int lane = threadIdx.x & 63;
    float* yrow = XBC + (long long)row * XBCLD + lane * 8;
    const unsigned short* zrow = Zbf + (long long)row * 512 + lane * 8;
    float4 y0 = ((const float4*)yrow)[0];
    float4 y1 = ((const float4*)yrow)[1];
    uint4 zq = ((const uint4*)zrow)[0];
    float yv[8] = { y0.x, y0.y, y0.z, y0.w, y1.x, y1.y, y1.z, y1.w };
    float zv[8];
    zv[0] = bf2f((unsigned short)(zq.x & 0xFFFF)); zv[1] = bf2f((unsigned short)(zq.x >> 16));
    zv[2] = bf2f((unsigned short)(zq.y & 0xFFFF)); zv[3] = bf2f((unsigned short)(zq.y >> 16));
    zv[4] = bf2f((unsigned short)(zq.z & 0xFFFF)); zv[5] = bf2f((unsigned short)(zq.z >> 16));
    zv[6] = bf2f((unsigned short)(zq.w & 0xFFFF)); zv[7] = bf2f((unsigned short)(zq.w >> 16));
    float a[8]; float ss = 0.f;
#pragma unroll
    for (int i = 0; i < 8; i++) {
        float z = zv[i];
        a[i] = yv[i] * (z * __builtin_amdgcn_rcpf(1.f + __expf(-z)));
        ss = fmaf(a[i], a[i], ss);
    }
#pragma unroll
    for (int m = 1; m < 64; m <<= 1) ss += __shfl_xor(ss, m);
    float sc = rsqrtf(ss * (1.f / 512.f) + 1e-5f);
    const float* rw = rms_w + lane * 8;
    float4 r0 = ((const float4*)rw)[0];
    float4 r1 = ((const float4*)rw)[1];
    float rv[8] = { r0.x, r0.y, r0.z, r0.w, r1.x, r1.y, r1.z, r1.w };
    uint4 o;
    o.x = (unsigned)f2bf(a[0] * sc * rv[0]) | ((unsigned)f2bf(a[1] * sc * rv[1]) << 16);
    o.y = (unsigned)f2bf(a[2] * sc * rv[2]) | ((unsigned)f2bf(a[3] * sc * rv[3]) << 16);
    o.z = (unsigned)f2bf(a[4] * sc * rv[4]) | ((unsigned)f2bf(a[5] * sc * rv[5]) << 16);
    o.w = (unsigned)f2bf(a[6] * sc * rv[6]) | ((unsigned)f2bf(a[7] * sc * rv[7]) << 16);
    unsigned short* grow = (unsigned short*)(XBC + (long long)row * XBCLD);
    ((uint4*)grow)[lane] = o;
}

// ---------------- LayerNorm(bf16 a + f32 b)*g+be -> f32 ----------------
__global__ void lnadd_bf_kernel(const unsigned short* __restrict__ A, const float* __restrict__ Bb,
                                const float* __restrict__ g, const float* __restrict__ be,
                                float* __restrict__ O)
{
    int row = blockIdx.x * 4 + (threadIdx.x >> 6);
    int lane = threadIdx.x & 63;
    long long base = (long long)row * DMODEL + lane * 4;
    float v[4]; float s1 = 0.f;
#pragma unroll
    for (int i = 0; i < 4; i++) { float a = bf2f(A[base + i]) + Bb[base + i]; v[i] = a; s1 += a; }
#pragma unroll
    for (int m = 1; m < 64; m <<= 1) s1 += __shfl_xor(s1, m);
    float mean = s1 * (1.f / 256.f);
    float s2 = 0.f;
#pragma unroll
    for (int i = 0; i < 4; i++) { float d = v[i] - mean; s2 = fmaf(d, d, s2); }
#pragma unroll
    for (int m = 1; m < 64; m <<= 1) s2 += __shfl_xor(s2, m);
    float r = rsqrtf(s2 * (1.f / 256.f) + 1e-12f);
#pragma unroll
    for (int i = 0; i < 4; i++)
        O[base + i] = (v[i] - mean) * r * g[lane * 4 + i] + be[lane * 4 + i];
}

// ---------------- fused: MO = alpha*LN(MO+x) + beta*LN(XI+x); MObf = bf16(MO) ----------------
// XI has per-batch row stride 256 (65536 f32/batch), rows 0..199 valid.
__global__ void combine2_kernel(const float* __restrict__ XI, const float* __restrict__ X,
                                float* __restrict__ MO, unsigned short* __restrict__ HB,
                                const float* __restrict__ lg, const float* __restrict__ lb,
                                const float* __restrict__ fg, const float* __restrict__ fb,
                                const float* __restrict__ al, const float* __restrict__ bt)
{
    int row = blockIdx.x * 4 + (threadIdx.x >> 6);
    int lane = threadIdx.x & 63;
    long long base = (long long)row * DMODEL + lane * 4;
    int bb = row / SEQ, ll = row - bb * SEQ;
    long long xib = (long long)bb * 65536 + ll * 256 + lane * 4;
    float u[4], v[4]; float su = 0.f, sv = 0.f;
#pragma unroll
    for (int i = 0; i < 4; i++) {
        float xv = X[base + i];
        float a = MO[base + i] + xv;
        float b = XI[xib + i] + xv;
        u[i] = a; v[i] = b; su += a; sv += b;
    }
#pragma unroll
    for (int m = 1; m < 64; m <<= 1) { su += __shfl_xor(su, m); sv += __shfl_xor(sv, m); }
    float mu = su * (1.f / 256.f), mv = sv * (1.f / 256.f);
    float qu = 0.f, qv = 0.f;
#pragma unroll
    for (int i = 0; i < 4; i++) {
        float du = u[i] - mu; qu = fmaf(du, du, qu);
        float dv = v[i] - mv; qv = fmaf(dv, dv, qv);
    }
#pragma unroll
    for (int m = 1; m < 64; m <<= 1) { qu += __shfl_xor(qu, m); qv += __shfl_xor(qv, m); }
    float ru = rsqrtf(qu * (1.f / 256.f) + 1e-12f);
    float rv = rsqrtf(qv * (1.f / 256.f) + 1e-12f);
#pragma unroll
    for (int i = 0; i < 4; i++) {
        int d = lane * 4 + i;
        float h1 = (u[i] - mu) * ru * lg[d] + lb[d];
        float h2 = (v[i] - mv) * rv * fg[d] + fb[d];
        float h = al[d] * h1 + bt[d] * h2;
        MO[base + i] = h;
        HB[base + i] = f2bf(h);
    }
}

// ---------------- pointwise spectral filter on XFT[b][d][j] bf16 (ld 256) ----------------
__global__ void filt_kernel(unsigned short* __restrict__ XF, const float* __restrict__ W)
{
    long long idx = (long long)blockIdx.x * 256 + threadIdx.x;
    if (idx >= (long long)BATCHN * DMODEL * NF) return;
    int f = (int)(idx % NF);
    int d = (int)((idx / NF) % DMODEL);
    int b = (int)(idx / ((long long)NF * DMODEL));
    long long base = ((long long)b * DMODEL + d) * 256;
    float re = bf2f(XF[base + f]);
    float im = bf2f(XF[base + 101 + f]);
    float wr = W[((long long)f * DMODEL + d) * 2];
    float wi = W[((long long)f * DMODEL + d) * 2 + 1];
    XF[base + f]       = f2bf(re * wr - im * wi);
    XF[base + 101 + f] = f2bf(re * wi + im * wr);
}

extern "C" void kernel_launch(void* const* d_in, const int* in_sizes, int n_in,
                              void* d_out, int out_size, void* d_ws, size_t ws_size,
                              hipStream_t stream)
{
    const float* x          = (const float*)d_in[0];
    const float* in_proj_w  = (const float*)d_in[1];
    const float* conv_w     = (const float*)d_in[2];
    const float* conv_b     = (const float*)d_in[3];
    const float* dt_bias    = (const float*)d_in[4];
    const float* A_log      = (const float*)d_in[5];
    const float* D_skip     = (const float*)d_in[6];
    const float* rms_w      = (const float*)d_in[7];
    const float* out_proj_w = (const float*)d_in[8];
    const float* ln_g       = (const float*)d_in[9];
    const float* ln_b       = (const float*)d_in[10];
    const float* filt_w     = (const float*)d_in[11];
    const float* filt_ln_g  = (const float*)d_in[12];
    const float* filt_ln_b  = (const float*)d_in[13];
    const float* alpha      = (const float*)d_in[14];
    const float* beta       = (const float*)d_in[15];
    const float* ffn_w1     = (const float*)d_in[16];
    const float* ffn_b1     = (const float*)d_in[17];
    const float* ffn_w2     = (const float*)d_in[18];
    const float* ffn_b2     = (const float*)d_in[19];
    const float* ffn_ln_g   = (const float*)d_in[20];
    const float* ffn_ln_b   = (const float*)d_in[21];
    float* out = (float*)d_out;
    float* ws = (float*)d_ws;

    // weights arena [81920 .. XBASE)
    unsigned short* WP   = (unsigned short*)(ws + 81920);
    unsigned short* ipwT = WP;                  // 672*256
    unsigned short* opwT = ipwT + 672 * 256;    // 256*512
    unsigned short* w1T  = opwT + 256 * 512;    // 1024*256
    unsigned short* w2T  = w1T + 1024 * 256;    // 256*1024
    unsigned short* zwT  = w2T + 256 * 1024;    // 512*256
    unsigned short* EFbf = zwT + 512 * 256;     // 256*200
    unsigned short* EIbf = EFbf + 256 * SEQ;    // 256*256
    float* XBC = ws + XBASE;                    // BL*672 f32 arena
    float* BCb = XBC + (long long)BL * XBCLD;   // BL*128
    float* DTb = BCb + (long long)BL * 128;     // BL*32
    float* DAb = DTb + (long long)BL * NH;      // BL*32
    float* MO  = DAb + (long long)BL * NH;      // BL*256 (h1/H)
    unsigned short* Zbf = (unsigned short*)MO;  // BL*512 bf16, lifetime [zproj..gate]
    // BCb region reuse (BL*128 f32 == BL*256 bf16):
    unsigned short* xbf  = (unsigned short*)BCb; // bf16 x, lifetime [f2bf..zproj]
    unsigned short* xTbf = (unsigned short*)BCb; // lifetime [xT..FFT fwd]
    unsigned short* MObf = (unsigned short*)BCb; // lifetime [combine2..FFN1]
    // XBC arena reuse:
    unsigned short* Gbf = (unsigned short*)XBC;              // bf16 G in place, ld 1344
    unsigned short* XFT = (unsigned short*)XBC;              // 256*256*256 bf16 (8.39M f32)
    float* XI  = XBC + XIOFF;                                // 256*65536 f32
    unsigned short* HID = (unsigned short*)XBC;              // BL*1024 bf16 (post-combine2)
    unsigned short* FFO = (unsigned short*)(XBC + 26500000); // BL*256 bf16

    // 1. DFT matrices + weight packs + x->bf16
    init_dft_kernel<<<dim3((256 * SEQ + 256 * 256 + 255) / 256), dim3(256), 0, stream>>>(EFbf, EIbf);
    pack_wT_kernel<<<dim3((672 * 256 + 255) / 256), dim3(256), 0, stream>>>(in_proj_w, ipwT, DINPROJ, 512, 672, 256);
    pack_wT_kernel<<<dim3((512 * 256 + 255) / 256), dim3(256), 0, stream>>>(in_proj_w, zwT, DINPROJ, 0, 512, 256);
    pack_wT_kernel<<<dim3((256 * 512 + 255) / 256), dim3(256), 0, stream>>>(out_proj_w, opwT, 256, 0, 256, 512);
    pack_wT_kernel<<<dim3((1024 * 256 + 255) / 256), dim3(256), 0, stream>>>(ffn_w1, w1T, 1024, 0, 1024, 256);
    pack_wT_kernel<<<dim3((256 * 1024 + 255) / 256), dim3(256), 0, stream>>>(ffn_w2, w2T, 256, 0, 256, 1024);
    f2bf_kernel<<<dim3(BL * DMODEL / 2048), dim3(256), 0, stream>>>(x, xbf);

    // 2. in_proj (xBC+dt cols): xbf[BL,256] @ ipwT^T -> XBC f32 (ld 672)
    mgemm_kernel<0,0><<<dim3(6, BL / 128, 1), dim3(256), 0, stream>>>(
        xbf, ipwT, XBC, nullptr, BL, 672, 256, 256, 256, 672, 0, 0, 0);

    // 2b. z projection: xbf @ zwT^T -> Zbf bf16 (aliases MO)
    mgemm_kernel<0,1><<<dim3(4, BL / 128, 1), dim3(256), 0, stream>>>(
        xbf, zwT, Zbf, nullptr, BL, 512, 256, 256, 256, 512, 0, 0, 0);

    // 3. conv+silu B/C; dt -> DT/DA (clobbers xbf)
    convbc_kernel<<<dim3(BL), dim3(192), 0, stream>>>(XBC, conv_w, conv_b, dt_bias, A_log,
                                                      BCb, DTb, DAb);

    // 4. scan v7 (TC=20, 4 blocks/CU), y in place f32
    scan7_kernel<<<dim3(BATCHN * 4), dim3(256), 0, stream>>>(DTb, DAb, XBC, BCb, D_skip,
                                                             conv_w, conv_b);

    // 4.5 x transpose -> xTbf (BCb dead after scan)
    xT_kernel<<<dim3(7, 8, BATCHN), dim3(256), 0, stream>>>(x, xTbf);

    // 5. gate -> Gbf bf16 in place
    gate_kernel<<<dim3(BL / 4), dim3(256), 0, stream>>>(XBC, Zbf, rms_w);

    // 6. out_proj: Gbf[BL,512](ld 1344) @ opwT^T -> MO f32 (Zbf dead)
    mgemm_kernel<0,0><<<dim3(2, BL / 128, 1), dim3(256), 0, stream>>>(
        Gbf, opwT, MO, nullptr, BL, 256, 512, 1344, 512, 256, 0, 0, 0);

    // 7. FFT fwd: XFT[b][256 rows][256] = xTbf[b][256,200] @ EFbf[256,200]^T, bf16 (ld 256)
    mgemm_kernel<0,1><<<dim3(2, 2, BATCHN), dim3(256), 0, stream>>>(
        xTbf, EFbf, XFT, nullptr, 256, 256, SEQ, SEQ, SEQ, 256,
        (long long)DMODEL * SEQ, 0, 65536);

    // 8. spectral filter in place
    filt_kernel<<<dim3((BATCHN * DMODEL * NF + 255) / 256), dim3(256), 0, stream>>>(XFT, filt_w);

    // 9. FFT inv: XI[b][256 rows][256] = EIbf[256,256] @ XFT[b]^T, f32 (batch stride 65536)
    mgemm_kernel<0,0><<<dim3(2, 2, BATCHN), dim3(256), 0, stream>>>(
        EIbf, XFT, XI, nullptr, 256, 256, 256, 256, 256, 256,
        0, 65536, 65536);

    // 10. fused combine: MO = alpha*LN(MO+x) + beta*LN(XI+x); MObf (xTbf dead)
    combine2_kernel<<<dim3(BL / 4), dim3(256), 0, stream>>>(XI, x, MO, MObf,
                                                            ln_g, ln_b, filt_ln_g, filt_ln_b,
                                                            alpha, beta);

    // 11. FFN1: MObf[BL,256] @ w1T^T + b1, GELU -> HID bf16 (XI dead)
    mgemm_kernel<1,1><<<dim3(8, BL / 128, 1), dim3(256), 0, stream>>>(
        MObf, w1T, HID, ffn_b1, BL, 1024, 256, 256, 256, 1024, 0, 0, 0);

    // 12. FFN2: HID[BL,1024] @ w2T^T + b2 -> FFO bf16
    mgemm_kernel<0,1><<<dim3(2, BL / 128, 1), dim3(256), 0, stream>>>(
        HID, w2T, FFO, ffn_b2, BL, 256, 1024, 1024, 1024, 256, 0, 0, 0);

    // 13. out = LN(FFO + MO)
    lnadd_bf_kernel<<<dim3(BL / 4), dim3(256), 0, stream>>>(FFO, MO, ffn_ln_g, ffn_ln_b, out);
}